// Round 1
// baseline (3041.837 us; speedup 1.0000x reference)
//
#include <hip/hip_runtime.h>
#include <math.h>

#define S_LEN 2048
#define DMODEL 512
#define NHEAD 8
#define DH 64
#define FDIM 2048

// ---- output layout (floats) ----
// x_t:    [0, 4194304)
// x_ids:  [4194304, 4202496)
// avg:    4202496
// masks:  [4202497, 20979713)
// loss:   20979713

__device__ __forceinline__ float gelu_f(float x) {
    return 0.5f * x * (1.0f + erff(x * 0.70710678118654752440f));
}

// ---------------- copy x -> out, ids -> out, zero scalar slots ----------------
__global__ void copy_init_k(const float* __restrict__ x, const int* __restrict__ x_ids,
                            float* __restrict__ out) {
    size_t i = (size_t)blockIdx.x * blockDim.x + threadIdx.x; // 1,048,576 float4s
    float4* o4 = (float4*)out;
    o4[i] = ((const float4*)x)[i];
    if (i < 2048) {
        int4 id4 = ((const int4*)x_ids)[i];
        o4[1048576 + i] = make_float4((float)id4.x, (float)id4.y, (float)id4.z, (float)id4.w);
    }
    if (i == 0) {
        out[4202496]  = 0.0f;   // avg_chunk_len accum
        out[20979713] = 0.0f;   // chunk_len_loss accum
    }
}

// ---------------- RMSNorm: one block per row (D=512, 256 thr, 2 elem/thr) ----
__global__ __launch_bounds__(256) void rmsnorm_k(const float* __restrict__ x,
                                                 const float* __restrict__ w,
                                                 float* __restrict__ o) {
    __shared__ float red[4];
    const int tid = threadIdx.x;
    const size_t row = blockIdx.x;
    const float* xr = x + row * DMODEL;
    float2 v = *(const float2*)(xr + tid * 2);
    float ss = v.x * v.x + v.y * v.y;
    #pragma unroll
    for (int off = 32; off; off >>= 1) ss += __shfl_down(ss, off);
    if ((tid & 63) == 0) red[tid >> 6] = ss;
    __syncthreads();
    float tot = red[0] + red[1] + red[2] + red[3];
    float rs = 1.0f / sqrtf(tot * (1.0f / 512.0f) + 1e-6f);
    float2 wv = *(const float2*)(w + tid * 2);
    float2 ov;
    ov.x = v.x * rs * wv.x;
    ov.y = v.y * rs * wv.y;
    *(float2*)(o + row * DMODEL + tid * 2) = ov;
}

// ---------------- fp32 GEMM: C[M,N] = A[M,K] @ B[K,N] (+ epilogue) ----------
// EPI: 0 = none, 1 = Cin + acc (residual), 2 = gelu(acc)
// HSPLIT: write as (B,H,S,Dh) head-split layout (N==512, tile == one head)
template<int EPI, bool HSPLIT>
__global__ __launch_bounds__(256) void gemm_k(const float* __restrict__ A,
                                              const float* __restrict__ B,
                                              const float* __restrict__ Cin,
                                              float* __restrict__ C,
                                              int M, int N, int K) {
    __shared__ float As[16][68];  // [kk][i], padded
    __shared__ float Bs[16][64];  // [kk][n]
    const int tid = threadIdx.x;
    const int tx = tid & 15, ty = tid >> 4;
    const int bm = blockIdx.y, bn = blockIdx.x;
    const float* Ab = A + (size_t)bm * 64 * K;
    float acc[4][4] = {};
    const int ar = tid >> 2;          // A-tile row 0..63
    const int ak = (tid & 3) * 4;     // A-tile k   0..12
    const int bk = tid >> 4;          // B-tile k   0..15
    const int bn4 = (tid & 15) * 4;   // B-tile col

    for (int kt = 0; kt < K; kt += 16) {
        float4 a4 = *(const float4*)(Ab + (size_t)ar * K + kt + ak);
        float4 b4 = *(const float4*)(B + (size_t)(kt + bk) * N + bn * 64 + bn4);
        As[ak + 0][ar] = a4.x; As[ak + 1][ar] = a4.y;
        As[ak + 2][ar] = a4.z; As[ak + 3][ar] = a4.w;
        *(float4*)&Bs[bk][bn4] = b4;
        __syncthreads();
        #pragma unroll
        for (int kk = 0; kk < 16; ++kk) {
            float4 av = *(const float4*)&As[kk][ty * 4];
            float4 bv = *(const float4*)&Bs[kk][tx * 4];
            float aa[4] = {av.x, av.y, av.z, av.w};
            float bb[4] = {bv.x, bv.y, bv.z, bv.w};
            #pragma unroll
            for (int r = 0; r < 4; ++r)
                #pragma unroll
                for (int c = 0; c < 4; ++c)
                    acc[r][c] += aa[r] * bb[c];
        }
        __syncthreads();
    }

    #pragma unroll
    for (int r = 0; r < 4; ++r) {
        int m = bm * 64 + ty * 4 + r;
        if (HSPLIT) {
            int b = m >> 11, s = m & 2047;
            size_t off = (((size_t)(b * NHEAD + bn)) * S_LEN + s) * DH + tx * 4;
            *(float4*)(C + off) = make_float4(acc[r][0], acc[r][1], acc[r][2], acc[r][3]);
        } else {
            size_t off = (size_t)m * N + bn * 64 + tx * 4;
            float4 res;
            if (EPI == 1) {
                float4 ci = *(const float4*)(Cin + off);
                res = make_float4(ci.x + acc[r][0], ci.y + acc[r][1],
                                  ci.z + acc[r][2], ci.w + acc[r][3]);
            } else if (EPI == 2) {
                res = make_float4(gelu_f(acc[r][0]), gelu_f(acc[r][1]),
                                  gelu_f(acc[r][2]), gelu_f(acc[r][3]));
            } else {
                res = make_float4(acc[r][0], acc[r][1], acc[r][2], acc[r][3]);
            }
            *(float4*)(C + off) = res;
        }
    }
}

// ---------------- RoPE in-place on (B*H, S, 64) ----------------
__global__ __launch_bounds__(256) void rope_k(float* __restrict__ t) {
    const int tid = threadIdx.x;
    const int lane = tid & 31;            // freq index 0..31
    const size_t row = (size_t)blockIdx.x * 8 + (tid >> 5);
    const int s = (int)(row & (S_LEN - 1));
    float inv = 1.0f / powf(10000.0f, (float)lane * (1.0f / 32.0f));
    float fr = (float)s * inv;
    float sn, cs;
    sincosf(fr, &sn, &cs);
    float* p = t + row * DH;
    float t1 = p[lane], t2 = p[lane + 32];
    p[lane]      = t1 * cs - t2 * sn;
    p[lane + 32] = t1 * sn + t2 * cs;
}

// ---------------- causal flash attention, fp32 ----------------
// grid: (S/64, B*H); 64-row Q tile; K buffer reused for P^T.
__global__ __launch_bounds__(256) void attn_k(const float* __restrict__ Q,
                                              const float* __restrict__ K,
                                              const float* __restrict__ V,
                                              float* __restrict__ O) {
    const int P = 68;
    __shared__ float Qs[64 * P];   // Q^T: [d][i]
    __shared__ float KP[64 * P];   // K^T: [d][j]  -> later P^T: [j][i]
    __shared__ float Vs[64 * P];   // V:   [j][d]
    __shared__ float red[64 * 17];
    __shared__ float mrow[64], lrow[64], arow[64];
    const int tid = threadIdx.x;
    const int tx = tid & 15, ty = tid >> 4;
    const int qt = blockIdx.x, bh = blockIdx.y;
    const float* Qb = Q + ((size_t)bh * S_LEN + qt * 64) * DH;
    #pragma unroll
    for (int rr = 0; rr < 4; ++rr) {
        int row = rr * 16 + ty;
        float4 v4 = *(const float4*)(Qb + row * DH + tx * 4);
        Qs[(tx * 4 + 0) * P + row] = v4.x;
        Qs[(tx * 4 + 1) * P + row] = v4.y;
        Qs[(tx * 4 + 2) * P + row] = v4.z;
        Qs[(tx * 4 + 3) * P + row] = v4.w;
    }
    if (tid < 64) { mrow[tid] = -INFINITY; lrow[tid] = 0.0f; }
    float oacc[4][4] = {};

    for (int kt = 0; kt <= qt; ++kt) {
        __syncthreads();
        const float* Kb = K + ((size_t)bh * S_LEN + kt * 64) * DH;
        const float* Vb = V + ((size_t)bh * S_LEN + kt * 64) * DH;
        #pragma unroll
        for (int rr = 0; rr < 4; ++rr) {
            int row = rr * 16 + ty;
            float4 kv = *(const float4*)(Kb + row * DH + tx * 4);
            KP[(tx * 4 + 0) * P + row] = kv.x;
            KP[(tx * 4 + 1) * P + row] = kv.y;
            KP[(tx * 4 + 2) * P + row] = kv.z;
            KP[(tx * 4 + 3) * P + row] = kv.w;
            *(float4*)&Vs[row * P + tx * 4] = *(const float4*)(Vb + row * DH + tx * 4);
        }
        __syncthreads();
        float s[4][4] = {};
        #pragma unroll 8
        for (int d = 0; d < 64; ++d) {
            float4 qv = *(const float4*)&Qs[d * P + ty * 4];
            float4 kv = *(const float4*)&KP[d * P + tx * 4];
            float qa[4] = {qv.x, qv.y, qv.z, qv.w};
            float ka[4] = {kv.x, kv.y, kv.z, kv.w};
            #pragma unroll
            for (int r = 0; r < 4; ++r)
                #pragma unroll
                for (int c = 0; c < 4; ++c)
                    s[r][c] += qa[r] * ka[c];
        }
        const bool diag = (kt == qt);
        #pragma unroll
        for (int r = 0; r < 4; ++r) {
            float lm = -INFINITY;
            #pragma unroll
            for (int c = 0; c < 4; ++c) {
                float sv = s[r][c] * 0.125f;
                if (diag && (tx * 4 + c) > (ty * 4 + r)) sv = -1e30f;
                s[r][c] = sv;
                lm = fmaxf(lm, sv);
            }
            red[(ty * 4 + r) * 17 + tx] = lm;
        }
        __syncthreads();
        if (tid < 64) {
            float tm = -INFINITY;
            #pragma unroll
            for (int t = 0; t < 16; ++t) tm = fmaxf(tm, red[tid * 17 + t]);
            float mo = mrow[tid];
            float mn = fmaxf(mo, tm);
            arow[tid] = expf(mo - mn);
            mrow[tid] = mn;
        }
        __syncthreads();
        #pragma unroll
        for (int r = 0; r < 4; ++r) {
            float mn = mrow[ty * 4 + r];
            float ls = 0.0f;
            #pragma unroll
            for (int c = 0; c < 4; ++c) {
                float p = expf(s[r][c] - mn);
                KP[(tx * 4 + c) * P + (ty * 4 + r)] = p;   // P^T[j][i]
                ls += p;
            }
            red[(ty * 4 + r) * 17 + tx] = ls;
        }
        __syncthreads();
        if (tid < 64) {
            float ls = 0.0f;
            #pragma unroll
            for (int t = 0; t < 16; ++t) ls += red[tid * 17 + t];
            lrow[tid] = arow[tid] * lrow[tid] + ls;
        }
        #pragma unroll
        for (int r = 0; r < 4; ++r) {
            float al = arow[ty * 4 + r];
            #pragma unroll
            for (int c = 0; c < 4; ++c) oacc[r][c] *= al;
        }
        #pragma unroll 8
        for (int j = 0; j < 64; ++j) {
            float4 pv = *(const float4*)&KP[j * P + ty * 4];
            float4 vv = *(const float4*)&Vs[j * P + tx * 4];
            float pa[4] = {pv.x, pv.y, pv.z, pv.w};
            float va[4] = {vv.x, vv.y, vv.z, vv.w};
            #pragma unroll
            for (int r = 0; r < 4; ++r)
                #pragma unroll
                for (int c = 0; c < 4; ++c)
                    oacc[r][c] += pa[r] * va[c];
        }
    }
    __syncthreads();
    const int b = bh >> 3, hh = bh & 7;
    #pragma unroll
    for (int r = 0; r < 4; ++r) {
        float inv_l = 1.0f / lrow[ty * 4 + r];
        size_t row = (size_t)b * S_LEN + qt * 64 + ty * 4 + r;
        *(float4*)(O + row * DMODEL + hh * DH + tx * 4) =
            make_float4(oacc[r][0] * inv_l, oacc[r][1] * inv_l,
                        oacc[r][2] * inv_l, oacc[r][3] * inv_l);
    }
}

// ---------------- head: logits -> sigmoid -> probs (+loss accum) -----------
__global__ __launch_bounds__(256) void head_k(const float* __restrict__ x,
                                              const float* __restrict__ w,
                                              const float* __restrict__ b,
                                              float* __restrict__ probs,
                                              float* __restrict__ loss_out) {
    const int tid = threadIdx.x;
    const int lane = tid & 63;
    const size_t row = (size_t)blockIdx.x * 4 + (tid >> 6);
    const float* xr = x + row * DMODEL;
    float acc = 0.0f;
    #pragma unroll
    for (int i = 0; i < 8; ++i) acc += xr[lane + i * 64] * w[lane + i * 64];
    #pragma unroll
    for (int off = 32; off; off >>= 1) acc += __shfl_down(acc, off);
    if (lane == 0) {
        float logit = acc + b[0];
        float p = 1.0f / (1.0f + expf(-logit));
        probs[row] = p;
        atomicAdd(loss_out, p * 0.25f);   // mean over B of sum over S
    }
}

// ---------------- chunk id scan: one block per batch -----------------------
__global__ void chunk_k(const float* __restrict__ probs, int* __restrict__ ids,
                        float* __restrict__ avg_out) {
    __shared__ int flagbuf[S_LEN];
    __shared__ int nxt[S_LEN + 1];
    __shared__ int anyf;
    const int b = blockIdx.x;
    const int tid = threadIdx.x;
    const float* pr = probs + (size_t)b * S_LEN;
    if (tid == 0) anyf = 0;
    __syncthreads();
    for (int t = tid; t < S_LEN; t += 256) {
        int f = pr[t] > 0.5f ? 1 : 0;
        flagbuf[t] = f;
        if (f) atomicOr(&anyf, 1);
    }
    __syncthreads();
    if (tid == 0) {
        const int any = anyf;
        const int BIG = S_LEN + 1;  // "S+1" sentinel
        // idx[i] = i if has_end[i] else S+1 ;  has_end[i] = flags[i-1] (i>=1), fallback i==S-1
        auto idxf = [&](int i) -> int {
            bool he = any ? (i >= 1 && flagbuf[i - 1]) : (i == S_LEN - 1);
            return he ? i : BIG;
        };
        int cur = idxf(S_LEN);
        nxt[S_LEN] = cur;
        for (int t = S_LEN - 1; t >= 1; --t) {
            int ix = idxf(t);
            cur = ix < cur ? ix : cur;
            nxt[t] = cur;
        }
        int cur_end = 0, cid = -1;
        for (int t = 0; t < S_LEN; ++t) {
            if (t == cur_end) {
                int cap = t + 16; if (cap > S_LEN) cap = S_LEN;
                int e = nxt[t + 1];
                if (e > cap) e = cap;
                if (e - t < 3) { e = t + 3; if (e > S_LEN) e = S_LEN; }
                cur_end = e;
                cid++;
            }
            ids[(size_t)b * S_LEN + t] = cid;
        }
        atomicAdd(avg_out, 512.0f / (float)(cid + 1));  // mean over B of S/n
    }
}

// ---------------- masks: ids[b,q] == ids[b,k] -------------------------------
__global__ __launch_bounds__(256) void masks_k(const int* __restrict__ ids,
                                               float* __restrict__ mask) {
    const int bq = blockIdx.x;          // 0..8191
    const int b = bq >> 11;
    const int myid = ids[bq];
    const int* idr = ids + (size_t)b * S_LEN;
    float* mr = mask + (size_t)bq * S_LEN;
    for (int k = threadIdx.x; k < S_LEN; k += 256)
        mr[k] = (idr[k] == myid) ? 1.0f : 0.0f;
}

extern "C" void kernel_launch(void* const* d_in, const int* in_sizes, int n_in,
                              void* d_out, int out_size, void* d_ws, size_t ws_size,
                              hipStream_t stream) {
    (void)in_sizes; (void)n_in; (void)out_size; (void)ws_size;
    const float* x      = (const float*)d_in[0];
    const int*   x_ids  = (const int*)d_in[1];
    const float* ln1    = (const float*)d_in[2];
    const float* Wq     = (const float*)d_in[3];
    const float* Wk     = (const float*)d_in[4];
    const float* Wv     = (const float*)d_in[5];
    const float* Wo     = (const float*)d_in[6];
    const float* ln2    = (const float*)d_in[7];
    const float* W1     = (const float*)d_in[8];
    const float* W2     = (const float*)d_in[9];
    const float* head_w = (const float*)d_in[10];
    const float* head_b = (const float*)d_in[11];

    float* out  = (float*)d_out;
    float* wsf  = (float*)d_ws;
    // ws layout (floats): q|k|v (first 12.58M, also low 3/4 of ff) ... ff = 16.78M, h after.
    float* q     = wsf;
    float* k     = wsf + 4194304;
    float* v     = wsf + 8388608;
    float* ff    = wsf;                    // 16,777,216 floats (q,k,v dead by then)
    float* h     = wsf + 16777216;         // 4,194,304 floats (also holds attn out o)
    float* probs = wsf + 20971520;         // 8192
    int*   ids   = (int*)(wsf + 20979712); // 8192
    float* xbuf  = out;                    // running x lives in the x_t output slot

    copy_init_k<<<4096, 256, 0, stream>>>(x, x_ids, out);

    const dim3 gQKV(8, 128);    // N=512
    const dim3 gFF(32, 128);    // N=2048
    for (int l = 0; l < 2; ++l) {
        const float* Wq_l = Wq + (size_t)l * DMODEL * DMODEL;
        const float* Wk_l = Wk + (size_t)l * DMODEL * DMODEL;
        const float* Wv_l = Wv + (size_t)l * DMODEL * DMODEL;
        const float* Wo_l = Wo + (size_t)l * DMODEL * DMODEL;
        const float* W1_l = W1 + (size_t)l * DMODEL * FDIM;
        const float* W2_l = W2 + (size_t)l * FDIM * DMODEL;

        rmsnorm_k<<<8192, 256, 0, stream>>>(xbuf, ln1 + l * DMODEL, h);
        gemm_k<0, true><<<gQKV, 256, 0, stream>>>(h, Wq_l, nullptr, q, 8192, 512, 512);
        gemm_k<0, true><<<gQKV, 256, 0, stream>>>(h, Wk_l, nullptr, k, 8192, 512, 512);
        gemm_k<0, true><<<gQKV, 256, 0, stream>>>(h, Wv_l, nullptr, v, 8192, 512, 512);
        rope_k<<<8192, 256, 0, stream>>>(q);
        rope_k<<<8192, 256, 0, stream>>>(k);
        attn_k<<<dim3(32, 32), 256, 0, stream>>>(q, k, v, h);   // o -> h region
        gemm_k<1, false><<<gQKV, 256, 0, stream>>>(h, Wo_l, xbuf, xbuf, 8192, 512, 512);
        rmsnorm_k<<<8192, 256, 0, stream>>>(xbuf, ln2 + l * DMODEL, h);
        gemm_k<2, false><<<gFF, 256, 0, stream>>>(h, W1_l, nullptr, ff, 8192, 2048, 512);
        gemm_k<1, false><<<gQKV, 256, 0, stream>>>(ff, W2_l, xbuf, xbuf, 8192, 512, 2048);
    }

    head_k<<<2048, 256, 0, stream>>>(xbuf, head_w, head_b, probs, out + 20979713);
    chunk_k<<<4, 256, 0, stream>>>(probs, ids, out + 4202496);
    masks_k<<<8192, 256, 0, stream>>>(ids, out + 4202497);
}

// Round 2
// 2320.808 us; speedup vs baseline: 1.3107x; 1.3107x over previous
//
#include <hip/hip_runtime.h>
#include <math.h>

#define S_LEN 2048
#define DMODEL 512
#define NHEAD 8
#define DH 64
#define FDIM 2048

typedef unsigned short ushort_t;
typedef __attribute__((ext_vector_type(8))) short short8_t;   // 8 bf16 = 4 VGPRs
typedef __attribute__((ext_vector_type(4))) float float4_t;   // MFMA acc

#define MFMA16(a, b, c) __builtin_amdgcn_mfma_f32_16x16x32_bf16(a, b, c, 0, 0, 0)

// ---- output layout (floats) ----
// x_t: [0, 4194304)  x_ids: [4194304, 4202496)  avg: 4202496
// masks: [4202497, 20979713)  loss: 20979713
// masks region doubles as weight-split scratch (dead until masks_k at the end).

__device__ __forceinline__ ushort_t f2bf(float x) {            // RNE fp32->bf16
    unsigned u = __float_as_uint(x);
    return (ushort_t)((u + 0x7fffu + ((u >> 16) & 1u)) >> 16);
}
__device__ __forceinline__ float bf2f(ushort_t h) {
    return __uint_as_float((unsigned)h << 16);
}
__device__ __forceinline__ float gelu_f(float x) {
    return 0.5f * x * (1.0f + erff(x * 0.70710678118654752440f));
}
__device__ __forceinline__ void gl_lds16(const void* g, void* l) {
    __builtin_amdgcn_global_load_lds(
        (const __attribute__((address_space(1))) void*)g,
        (__attribute__((address_space(3))) void*)l, 16, 0, 0);
}

// ---------------- copy x -> out, ids -> out, zero scalar slots --------------
__global__ void copy_init_k(const float* __restrict__ x, const int* __restrict__ x_ids,
                            float* __restrict__ out) {
    size_t i = (size_t)blockIdx.x * blockDim.x + threadIdx.x;
    float4* o4 = (float4*)out;
    o4[i] = ((const float4*)x)[i];
    if (i < 2048) {
        int4 id4 = ((const int4*)x_ids)[i];
        o4[1048576 + i] = make_float4((float)id4.x, (float)id4.y, (float)id4.z, (float)id4.w);
    }
    if (i == 0) { out[4202496] = 0.0f; out[20979713] = 0.0f; }
}

// ---------------- weight transpose + split: T[n][k] = split(W[k][n]) --------
__global__ __launch_bounds__(256) void tsplit_k(const float* __restrict__ W,
                                                ushort_t* __restrict__ Thi,
                                                ushort_t* __restrict__ Tlo,
                                                int K, int N) {
    __shared__ float T[32][33];
    const int tx = threadIdx.x & 31, ty = threadIdx.x >> 5;
    const int n0 = blockIdx.x * 32, k0 = blockIdx.y * 32;
    #pragma unroll
    for (int i = 0; i < 4; ++i)
        T[ty + 8 * i][tx] = W[(size_t)(k0 + ty + 8 * i) * N + n0 + tx];
    __syncthreads();
    #pragma unroll
    for (int i = 0; i < 4; ++i) {
        const int n = ty + 8 * i;
        float x = T[tx][n];
        ushort_t hi = f2bf(x);
        Thi[(size_t)(n0 + n) * K + k0 + tx] = hi;
        Tlo[(size_t)(n0 + n) * K + k0 + tx] = f2bf(x - bf2f(hi));
    }
}

// ---------------- RMSNorm -> hi/lo bf16 split --------------------------------
__global__ __launch_bounds__(256) void rmsnorm_split_k(const float* __restrict__ x,
                                                       const float* __restrict__ w,
                                                       ushort_t* __restrict__ hhi,
                                                       ushort_t* __restrict__ hlo) {
    __shared__ float red[4];
    const int tid = threadIdx.x;
    const size_t row = blockIdx.x;
    const float* xr = x + row * DMODEL;
    float2 v = *(const float2*)(xr + tid * 2);
    float ss = v.x * v.x + v.y * v.y;
    #pragma unroll
    for (int off = 32; off; off >>= 1) ss += __shfl_down(ss, off);
    if ((tid & 63) == 0) red[tid >> 6] = ss;
    __syncthreads();
    float tot = red[0] + red[1] + red[2] + red[3];
    float rs = 1.0f / sqrtf(tot * (1.0f / 512.0f) + 1e-6f);
    float2 wv = *(const float2*)(w + tid * 2);
    float y0 = v.x * rs * wv.x, y1 = v.y * rs * wv.y;
    ushort_t h0 = f2bf(y0), h1 = f2bf(y1);
    ushort_t l0 = f2bf(y0 - bf2f(h0)), l1 = f2bf(y1 - bf2f(h1));
    *(unsigned*)(hhi + row * DMODEL + tid * 2) = ((unsigned)h1 << 16) | h0;
    *(unsigned*)(hlo + row * DMODEL + tid * 2) = ((unsigned)l1 << 16) | l0;
}

// ---------------- bf16x3 split MFMA GEMM ------------------------------------
// A: [M][K] hi/lo bf16 row-major. B: [N][K] hi/lo bf16 (transposed weights).
// 128x128 tile, BK=32, 4 waves, each wave 64x64 (4x4 of 16x16x32 MFMA).
// EPI 0: fp32 q/k/v head-split (N=1536 fused QKV)
// EPI 1: C = Cin + acc (fp32 residual)
// EPI 2: gelu(acc) -> Chi/Clo bf16 split
template<int EPI>
__global__ __launch_bounds__(256) void gemm_s(const ushort_t* __restrict__ Ahi,
                                              const ushort_t* __restrict__ Alo,
                                              const ushort_t* __restrict__ Bhi,
                                              const ushort_t* __restrict__ Blo,
                                              int K, int N,
                                              float* __restrict__ C,
                                              const float* __restrict__ Cin,
                                              float* __restrict__ q,
                                              float* __restrict__ kk,
                                              float* __restrict__ v,
                                              ushort_t* __restrict__ Chi,
                                              ushort_t* __restrict__ Clo) {
    __shared__ ushort_t sAhi[4096], sAlo[4096], sBhi[4096], sBlo[4096];
    const int tid = threadIdx.x;
    const int lane = tid & 63, w = tid >> 6;
    const int wm = w >> 1, wn = w & 1;
    const int bm = blockIdx.y, bn = blockIdx.x;
    const int sm = lane >> 2;          // staging row within 16-row chunk
    const int sk = (lane & 3) * 8;     // staging k offset
    const int fr = lane & 15;          // fragment row/col
    const int fk = (lane >> 4) * 8;    // fragment k base

    float4_t acc[4][4] = {};

    for (int kt = 0; kt < K; kt += 32) {
        #pragma unroll
        for (int j = 0; j < 2; ++j) {
            const int chunk = w * 2 + j;
            const int mr = chunk * 16 + sm;
            const size_t ga = (size_t)(bm * 128 + mr) * K + kt + sk;
            const size_t gb = (size_t)(bn * 128 + mr) * K + kt + sk;
            gl_lds16(Ahi + ga, &sAhi[chunk * 512]);
            gl_lds16(Alo + ga, &sAlo[chunk * 512]);
            gl_lds16(Bhi + gb, &sBhi[chunk * 512]);
            gl_lds16(Blo + gb, &sBlo[chunk * 512]);
        }
        __syncthreads();   // drains vmcnt(0): staged tiles visible
        short8_t ah[4], al[4], bh[4], bl[4];
        #pragma unroll
        for (int t = 0; t < 4; ++t) {
            const int ao = (wm * 64 + t * 16 + fr) * 32 + fk;
            ah[t] = *(const short8_t*)&sAhi[ao];
            al[t] = *(const short8_t*)&sAlo[ao];
            const int bo = (wn * 64 + t * 16 + fr) * 32 + fk;
            bh[t] = *(const short8_t*)&sBhi[bo];
            bl[t] = *(const short8_t*)&sBlo[bo];
        }
        #pragma unroll
        for (int tm = 0; tm < 4; ++tm)
            #pragma unroll
            for (int tn = 0; tn < 4; ++tn) {
                acc[tm][tn] = MFMA16(ah[tm], bh[tn], acc[tm][tn]);
                acc[tm][tn] = MFMA16(al[tm], bh[tn], acc[tm][tn]);
                acc[tm][tn] = MFMA16(ah[tm], bl[tn], acc[tm][tn]);
            }
        __syncthreads();   // all frag reads done before next stage overwrites
    }

    // epilogue: C/D layout col = lane&15, row = (lane>>4)*4 + reg  [m89/m91]
    #pragma unroll
    for (int tm = 0; tm < 4; ++tm) {
        #pragma unroll
        for (int tn = 0; tn < 4; ++tn) {
            const int cb = bn * 128 + wn * 64 + tn * 16;
            #pragma unroll
            for (int r = 0; r < 4; ++r) {
                const int mg = bm * 128 + wm * 64 + tm * 16 + (lane >> 4) * 4 + r;
                const float val = acc[tm][tn][r];
                if (EPI == 0) {
                    const int mat = cb >> 9;
                    float* dst = mat == 0 ? q : (mat == 1 ? kk : v);
                    const int hh = (cb >> 6) & 7;
                    const int dh = (cb & 63) + fr;
                    const int b = mg >> 11, s = mg & 2047;
                    dst[((size_t)(b * NHEAD + hh) * S_LEN + s) * DH + dh] = val;
                } else if (EPI == 1) {
                    const size_t off = (size_t)mg * N + cb + fr;
                    C[off] = Cin[off] + val;
                } else {
                    const size_t off = (size_t)mg * N + cb + fr;
                    const float g = gelu_f(val);
                    const ushort_t hi = f2bf(g);
                    Chi[off] = hi;
                    Clo[off] = f2bf(g - bf2f(hi));
                }
            }
        }
    }
}

// ---------------- RoPE in-place on (B*H, S, 64) ------------------------------
__global__ __launch_bounds__(256) void rope_k(float* __restrict__ t) {
    const int tid = threadIdx.x;
    const int lane = tid & 31;
    const size_t row = (size_t)blockIdx.x * 8 + (tid >> 5);
    const int s = (int)(row & (S_LEN - 1));
    float inv = 1.0f / powf(10000.0f, (float)lane * (1.0f / 32.0f));
    float sn, cs;
    sincosf((float)s * inv, &sn, &cs);
    float* p = t + row * DH;
    float t1 = p[lane], t2 = p[lane + 32];
    p[lane]      = t1 * cs - t2 * sn;
    p[lane + 32] = t1 * sn + t2 * cs;
}

// ---------------- causal flash attention, fp32, bf16-split output -----------
// 52 KB LDS (3 blocks/CU); softmax row state in registers + 16-lane shuffles.
__global__ __launch_bounds__(256) void attn_k(const float* __restrict__ Q,
                                              const float* __restrict__ K,
                                              const float* __restrict__ V,
                                              ushort_t* __restrict__ Ohi,
                                              ushort_t* __restrict__ Olo) {
    const int P = 68;
    __shared__ float Qs[64 * P];   // Q^T [d][i]
    __shared__ float KP[64 * P];   // K^T [d][j] -> P^T [j][i]
    __shared__ float Vs[64 * P];   // V   [j][d]
    const int tid = threadIdx.x;
    const int tx = tid & 15, ty = tid >> 4;
    const int qt = blockIdx.x, bh = blockIdx.y;
    const float* Qb = Q + ((size_t)bh * S_LEN + qt * 64) * DH;
    #pragma unroll
    for (int rr = 0; rr < 4; ++rr) {
        int row = rr * 16 + ty;
        float4 v4 = *(const float4*)(Qb + row * DH + tx * 4);
        Qs[(tx * 4 + 0) * P + row] = v4.x;
        Qs[(tx * 4 + 1) * P + row] = v4.y;
        Qs[(tx * 4 + 2) * P + row] = v4.z;
        Qs[(tx * 4 + 3) * P + row] = v4.w;
    }
    float m_r[4], l_r[4], oacc[4][4] = {};
    #pragma unroll
    for (int r = 0; r < 4; ++r) { m_r[r] = -INFINITY; l_r[r] = 0.0f; }

    for (int kt = 0; kt <= qt; ++kt) {
        __syncthreads();   // prev PV reads of KP/Vs complete
        const float* Kb = K + ((size_t)bh * S_LEN + kt * 64) * DH;
        const float* Vb = V + ((size_t)bh * S_LEN + kt * 64) * DH;
        #pragma unroll
        for (int rr = 0; rr < 4; ++rr) {
            int row = rr * 16 + ty;
            float4 kv = *(const float4*)(Kb + row * DH + tx * 4);
            KP[(tx * 4 + 0) * P + row] = kv.x;
            KP[(tx * 4 + 1) * P + row] = kv.y;
            KP[(tx * 4 + 2) * P + row] = kv.z;
            KP[(tx * 4 + 3) * P + row] = kv.w;
            *(float4*)&Vs[row * P + tx * 4] = *(const float4*)(Vb + row * DH + tx * 4);
        }
        __syncthreads();
        float s[4][4] = {};
        #pragma unroll 8
        for (int d = 0; d < 64; ++d) {
            float4 qv = *(const float4*)&Qs[d * P + ty * 4];
            float4 kv = *(const float4*)&KP[d * P + tx * 4];
            float qa[4] = {qv.x, qv.y, qv.z, qv.w};
            float ka[4] = {kv.x, kv.y, kv.z, kv.w};
            #pragma unroll
            for (int r = 0; r < 4; ++r)
                #pragma unroll
                for (int c = 0; c < 4; ++c)
                    s[r][c] += qa[r] * ka[c];
        }
        const bool diag = (kt == qt);
        float al[4];
        #pragma unroll
        for (int r = 0; r < 4; ++r) {
            float lm = -INFINITY;
            #pragma unroll
            for (int c = 0; c < 4; ++c) {
                float sv = s[r][c] * 0.125f;
                if (diag && (tx * 4 + c) > (ty * 4 + r)) sv = -1e30f;
                s[r][c] = sv;
                lm = fmaxf(lm, sv);
            }
            lm = fmaxf(lm, __shfl_xor(lm, 1));
            lm = fmaxf(lm, __shfl_xor(lm, 2));
            lm = fmaxf(lm, __shfl_xor(lm, 4));
            lm = fmaxf(lm, __shfl_xor(lm, 8));   // row max across 16 sharers
            float mn = fmaxf(m_r[r], lm);
            al[r] = expf(m_r[r] - mn);
            m_r[r] = mn;
        }
        __syncthreads();   // all QK reads of KP done before P^T overwrite
        #pragma unroll
        for (int r = 0; r < 4; ++r) {
            float ls = 0.0f;
            #pragma unroll
            for (int c = 0; c < 4; ++c) {
                float p = expf(s[r][c] - m_r[r]);
                KP[(tx * 4 + c) * P + (ty * 4 + r)] = p;   // P^T[j][i]
                ls += p;
            }
            ls += __shfl_xor(ls, 1);
            ls += __shfl_xor(ls, 2);
            ls += __shfl_xor(ls, 4);
            ls += __shfl_xor(ls, 8);
            l_r[r] = al[r] * l_r[r] + ls;
            #pragma unroll
            for (int c = 0; c < 4; ++c) oacc[r][c] *= al[r];
        }
        __syncthreads();   // P^T fully written
        #pragma unroll 8
        for (int j = 0; j < 64; ++j) {
            float4 pv = *(const float4*)&KP[j * P + ty * 4];
            float4 vv = *(const float4*)&Vs[j * P + tx * 4];
            float pa[4] = {pv.x, pv.y, pv.z, pv.w};
            float va[4] = {vv.x, vv.y, vv.z, vv.w};
            #pragma unroll
            for (int r = 0; r < 4; ++r)
                #pragma unroll
                for (int c = 0; c < 4; ++c)
                    oacc[r][c] += pa[r] * va[c];
        }
    }
    const int b = bh >> 3, hh = bh & 7;
    #pragma unroll
    for (int r = 0; r < 4; ++r) {
        float inv_l = 1.0f / l_r[r];
        size_t off = ((size_t)b * S_LEN + qt * 64 + ty * 4 + r) * DMODEL + hh * DH + tx * 4;
        #pragma unroll
        for (int c = 0; c < 4; ++c) {
            float y = oacc[r][c] * inv_l;
            ushort_t hi = f2bf(y);
            Ohi[off + c] = hi;
            Olo[off + c] = f2bf(y - bf2f(hi));
        }
    }
}

// ---------------- head: logits -> sigmoid -> probs (+loss accum) ------------
__global__ __launch_bounds__(256) void head_k(const float* __restrict__ x,
                                              const float* __restrict__ w,
                                              const float* __restrict__ b,
                                              float* __restrict__ probs,
                                              float* __restrict__ loss_out) {
    const int tid = threadIdx.x;
    const int lane = tid & 63;
    const size_t row = (size_t)blockIdx.x * 4 + (tid >> 6);
    const float* xr = x + row * DMODEL;
    float acc = 0.0f;
    #pragma unroll
    for (int i = 0; i < 8; ++i) acc += xr[lane + i * 64] * w[lane + i * 64];
    #pragma unroll
    for (int off = 32; off; off >>= 1) acc += __shfl_down(acc, off);
    if (lane == 0) {
        float p = 1.0f / (1.0f + expf(-(acc + b[0])));
        probs[row] = p;
        atomicAdd(loss_out, p * 0.25f);
    }
}

// ---------------- chunk id scan: one block per batch -------------------------
__global__ void chunk_k(const float* __restrict__ probs, int* __restrict__ ids,
                        float* __restrict__ avg_out) {
    __shared__ int flagbuf[S_LEN];
    __shared__ int nxt[S_LEN + 1];
    __shared__ int anyf;
    const int b = blockIdx.x;
    const int tid = threadIdx.x;
    const float* pr = probs + (size_t)b * S_LEN;
    if (tid == 0) anyf = 0;
    __syncthreads();
    for (int t = tid; t < S_LEN; t += 256) {
        int f = pr[t] > 0.5f ? 1 : 0;
        flagbuf[t] = f;
        if (f) atomicOr(&anyf, 1);
    }
    __syncthreads();
    if (tid == 0) {
        const int any = anyf;
        const int BIG = S_LEN + 1;
        auto idxf = [&](int i) -> int {
            bool he = any ? (i >= 1 && flagbuf[i - 1]) : (i == S_LEN - 1);
            return he ? i : BIG;
        };
        int cur = idxf(S_LEN);
        nxt[S_LEN] = cur;
        for (int t = S_LEN - 1; t >= 1; --t) {
            int ix = idxf(t);
            cur = ix < cur ? ix : cur;
            nxt[t] = cur;
        }
        int cur_end = 0, cid = -1;
        for (int t = 0; t < S_LEN; ++t) {
            if (t == cur_end) {
                int cap = t + 16; if (cap > S_LEN) cap = S_LEN;
                int e = nxt[t + 1];
                if (e > cap) e = cap;
                if (e - t < 3) { e = t + 3; if (e > S_LEN) e = S_LEN; }
                cur_end = e;
                cid++;
            }
            ids[(size_t)b * S_LEN + t] = cid;
        }
        atomicAdd(avg_out, 512.0f / (float)(cid + 1));
    }
}

// ---------------- masks ------------------------------------------------------
__global__ __launch_bounds__(256) void masks_k(const int* __restrict__ ids,
                                               float* __restrict__ mask) {
    const int bq = blockIdx.x;
    const int b = bq >> 11;
    const int myid = ids[bq];
    const int* idr = ids + (size_t)b * S_LEN;
    float* mr = mask + (size_t)bq * S_LEN;
    for (int k = threadIdx.x; k < S_LEN; k += 256)
        mr[k] = (idr[k] == myid) ? 1.0f : 0.0f;
}

extern "C" void kernel_launch(void* const* d_in, const int* in_sizes, int n_in,
                              void* d_out, int out_size, void* d_ws, size_t ws_size,
                              hipStream_t stream) {
    (void)in_sizes; (void)n_in; (void)out_size; (void)ws_size;
    const float* x      = (const float*)d_in[0];
    const int*   x_ids  = (const int*)d_in[1];
    const float* ln1    = (const float*)d_in[2];
    const float* Wq     = (const float*)d_in[3];
    const float* Wk     = (const float*)d_in[4];
    const float* Wv     = (const float*)d_in[5];
    const float* Wo     = (const float*)d_in[6];
    const float* ln2    = (const float*)d_in[7];
    const float* W1     = (const float*)d_in[8];
    const float* W2     = (const float*)d_in[9];
    const float* head_w = (const float*)d_in[10];
    const float* head_b = (const float*)d_in[11];

    float* out = (float*)d_out;
    float* wsf = (float*)d_ws;
    // ws layout (float offsets), total 20,987,904 floats (~84 MB, same as R1):
    float*    q    = wsf;                              // fp32 q  [0, 4.19M)
    float*    kbuf = wsf + 4194304;                    // fp32 k
    float*    v    = wsf + 8388608;                    // fp32 v
    ushort_t* ohi  = (ushort_t*)(wsf + 12582912);      // o split (4.19M bf16 each)
    ushort_t* olo  = (ushort_t*)(wsf + 14680064);
    ushort_t* ffhi = (ushort_t*)wsf;                   // overlays q..olo after attn
    ushort_t* fflo = (ushort_t*)(wsf + 8388608);
    ushort_t* hhi  = (ushort_t*)(wsf + 16777216);
    ushort_t* hlo  = (ushort_t*)(wsf + 18874368);
    float*    probs = wsf + 20971520;
    int*      ids   = (int*)(wsf + 20979712);
    // weight-split scratch inside out's mask region (dead until masks_k):
    ushort_t* wbuf     = (ushort_t*)(out + 4202512);   // 16B-aligned
    ushort_t* qkvT_hi  = wbuf;                         // [1536][512]
    ushort_t* qkvT_lo  = wbuf + 786432;
    ushort_t* woT_hi   = wbuf + 1572864;               // [512][512]
    ushort_t* woT_lo   = wbuf + 1835008;
    ushort_t* w1T_hi   = wbuf + 2097152;               // [2048][512]
    ushort_t* w1T_lo   = wbuf + 3145728;
    ushort_t* w2T_hi   = wbuf + 4194304;               // [512][2048]
    ushort_t* w2T_lo   = wbuf + 5242880;
    float* xbuf = out;   // running x lives in x_t output slot

    copy_init_k<<<4096, 256, 0, stream>>>(x, x_ids, out);

    for (int l = 0; l < 2; ++l) {
        const float* Wq_l = Wq + (size_t)l * DMODEL * DMODEL;
        const float* Wk_l = Wk + (size_t)l * DMODEL * DMODEL;
        const float* Wv_l = Wv + (size_t)l * DMODEL * DMODEL;
        const float* Wo_l = Wo + (size_t)l * DMODEL * DMODEL;
        const float* W1_l = W1 + (size_t)l * DMODEL * FDIM;
        const float* W2_l = W2 + (size_t)l * FDIM * DMODEL;

        tsplit_k<<<dim3(16, 16), 256, 0, stream>>>(Wq_l, qkvT_hi,            qkvT_lo,            512, 512);
        tsplit_k<<<dim3(16, 16), 256, 0, stream>>>(Wk_l, qkvT_hi + 262144,   qkvT_lo + 262144,   512, 512);
        tsplit_k<<<dim3(16, 16), 256, 0, stream>>>(Wv_l, qkvT_hi + 524288,   qkvT_lo + 524288,   512, 512);
        tsplit_k<<<dim3(16, 16), 256, 0, stream>>>(Wo_l, woT_hi, woT_lo, 512, 512);
        tsplit_k<<<dim3(64, 16), 256, 0, stream>>>(W1_l, w1T_hi, w1T_lo, 512, 2048);
        tsplit_k<<<dim3(16, 64), 256, 0, stream>>>(W2_l, w2T_hi, w2T_lo, 2048, 512);

        rmsnorm_split_k<<<8192, 256, 0, stream>>>(xbuf, ln1 + l * DMODEL, hhi, hlo);
        gemm_s<0><<<dim3(12, 64), 256, 0, stream>>>(hhi, hlo, qkvT_hi, qkvT_lo, 512, 1536,
                                                    nullptr, nullptr, q, kbuf, v, nullptr, nullptr);
        rope_k<<<8192, 256, 0, stream>>>(q);
        rope_k<<<8192, 256, 0, stream>>>(kbuf);
        attn_k<<<dim3(32, 32), 256, 0, stream>>>(q, kbuf, v, ohi, olo);
        gemm_s<1><<<dim3(4, 64), 256, 0, stream>>>(ohi, olo, woT_hi, woT_lo, 512, 512,
                                                   xbuf, xbuf, nullptr, nullptr, nullptr, nullptr, nullptr);
        rmsnorm_split_k<<<8192, 256, 0, stream>>>(xbuf, ln2 + l * DMODEL, hhi, hlo);
        gemm_s<2><<<dim3(16, 64), 256, 0, stream>>>(hhi, hlo, w1T_hi, w1T_lo, 512, 2048,
                                                    nullptr, nullptr, nullptr, nullptr, nullptr, ffhi, fflo);
        gemm_s<1><<<dim3(4, 64), 256, 0, stream>>>(ffhi, fflo, w2T_hi, w2T_lo, 2048, 512,
                                                   xbuf, xbuf, nullptr, nullptr, nullptr, nullptr, nullptr);
    }

    head_k<<<2048, 256, 0, stream>>>(xbuf, head_w, head_b, probs, out + 20979713);
    chunk_k<<<4, 256, 0, stream>>>(probs, ids, out + 4202496);
    masks_k<<<8192, 256, 0, stream>>>(ids, out + 4202497);
}

// Round 3
// 1568.802 us; speedup vs baseline: 1.9390x; 1.4794x over previous
//
#include <hip/hip_runtime.h>
#include <math.h>

#define S_LEN 2048
#define DMODEL 512
#define NHEAD 8
#define DH 64
#define FDIM 2048

typedef unsigned short ushort_t;
typedef __attribute__((ext_vector_type(8))) short short8_t;   // 8 bf16 = 4 VGPRs
typedef __attribute__((ext_vector_type(4))) float float4_t;   // MFMA acc

#define MFMA16(a, b, c) __builtin_amdgcn_mfma_f32_16x16x32_bf16(a, b, c, 0, 0, 0)

// ---- output layout (floats) ----
// x_t: [0, 4194304)  x_ids: [4194304, 4202496)  avg: 4202496
// masks: [4202497, 20979713)  loss: 20979713
// masks region doubles as weight-split scratch (dead until masks_k at the end).

__device__ __forceinline__ ushort_t f2bf(float x) {            // RNE fp32->bf16
    unsigned u = __float_as_uint(x);
    return (ushort_t)((u + 0x7fffu + ((u >> 16) & 1u)) >> 16);
}
__device__ __forceinline__ float bf2f(ushort_t h) {
    return __uint_as_float((unsigned)h << 16);
}
__device__ __forceinline__ float gelu_f(float x) {
    return 0.5f * x * (1.0f + erff(x * 0.70710678118654752440f));
}
__device__ __forceinline__ void gl_lds16(const void* g, void* l) {
    __builtin_amdgcn_global_load_lds(
        (const __attribute__((address_space(1))) void*)g,
        (__attribute__((address_space(3))) void*)l, 16, 0, 0);
}

// stage a 64x64 bf16 tile (row stride rs ushorts) into LDS [kk][64][32] (4096 ushorts).
// 512 16B-chunks; chunk c = (w*2+j)*64 + lane keeps LDS dest = base + lane*16 per instr.
__device__ __forceinline__ void stage_tile(const ushort_t* __restrict__ g, int rs,
                                           ushort_t* __restrict__ s, int w, int lane) {
    #pragma unroll
    for (int j = 0; j < 2; ++j) {
        const int c = (w * 2 + j) * 64 + lane;
        const int kk = c >> 8, row = (c >> 2) & 63, q = c & 3;
        gl_lds16(g + (size_t)row * rs + kk * 32 + q * 8, s + c * 8);
    }
}

// ---------------- copy x -> out, ids -> out, zero scalar slots --------------
__global__ void copy_init_k(const float* __restrict__ x, const int* __restrict__ x_ids,
                            float* __restrict__ out) {
    size_t i = (size_t)blockIdx.x * blockDim.x + threadIdx.x;
    float4* o4 = (float4*)out;
    o4[i] = ((const float4*)x)[i];
    if (i < 2048) {
        int4 id4 = ((const int4*)x_ids)[i];
        o4[1048576 + i] = make_float4((float)id4.x, (float)id4.y, (float)id4.z, (float)id4.w);
    }
    if (i == 0) { out[4202496] = 0.0f; out[20979713] = 0.0f; }
}

// ---------------- weight transpose + split: T[n][k] = split(W[k][n]) --------
__global__ __launch_bounds__(256) void tsplit_k(const float* __restrict__ W,
                                                ushort_t* __restrict__ Thi,
                                                ushort_t* __restrict__ Tlo,
                                                int K, int N) {
    __shared__ float T[32][33];
    const int tx = threadIdx.x & 31, ty = threadIdx.x >> 5;
    const int n0 = blockIdx.x * 32, k0 = blockIdx.y * 32;
    #pragma unroll
    for (int i = 0; i < 4; ++i)
        T[ty + 8 * i][tx] = W[(size_t)(k0 + ty + 8 * i) * N + n0 + tx];
    __syncthreads();
    #pragma unroll
    for (int i = 0; i < 4; ++i) {
        const int n = ty + 8 * i;
        float x = T[tx][n];
        ushort_t hi = f2bf(x);
        Thi[(size_t)(n0 + n) * K + k0 + tx] = hi;
        Tlo[(size_t)(n0 + n) * K + k0 + tx] = f2bf(x - bf2f(hi));
    }
}

// ---------------- RMSNorm -> hi/lo bf16 split --------------------------------
__global__ __launch_bounds__(256) void rmsnorm_split_k(const float* __restrict__ x,
                                                       const float* __restrict__ w,
                                                       ushort_t* __restrict__ hhi,
                                                       ushort_t* __restrict__ hlo) {
    __shared__ float red[4];
    const int tid = threadIdx.x;
    const size_t row = blockIdx.x;
    const float* xr = x + row * DMODEL;
    float2 v = *(const float2*)(xr + tid * 2);
    float ss = v.x * v.x + v.y * v.y;
    #pragma unroll
    for (int off = 32; off; off >>= 1) ss += __shfl_down(ss, off);
    if ((tid & 63) == 0) red[tid >> 6] = ss;
    __syncthreads();
    float tot = red[0] + red[1] + red[2] + red[3];
    float rs = 1.0f / sqrtf(tot * (1.0f / 512.0f) + 1e-6f);
    float2 wv = *(const float2*)(w + tid * 2);
    float y0 = v.x * rs * wv.x, y1 = v.y * rs * wv.y;
    ushort_t h0 = f2bf(y0), h1 = f2bf(y1);
    ushort_t l0 = f2bf(y0 - bf2f(h0)), l1 = f2bf(y1 - bf2f(h1));
    *(unsigned*)(hhi + row * DMODEL + tid * 2) = ((unsigned)h1 << 16) | h0;
    *(unsigned*)(hlo + row * DMODEL + tid * 2) = ((unsigned)l1 << 16) | l0;
}

// ---------------- bf16x3 split MFMA GEMM ------------------------------------
// A: [M][K] hi/lo bf16 row-major. B: [N][K] hi/lo bf16 (transposed weights).
// 128x128 tile, BK=32, 4 waves, each wave 64x64 (4x4 of 16x16x32 MFMA).
// EPI 0: fused QKV epilogue (N=1536): RoPE q/k -> split bf16 [bh][s][64];
//        v -> split bf16 transposed [bh][d][S].
// EPI 1: C = Cin + acc (fp32 residual)
// EPI 2: gelu(acc) -> Chi/Clo bf16 split
template<int EPI>
__global__ __launch_bounds__(256) void gemm_s(const ushort_t* __restrict__ Ahi,
                                              const ushort_t* __restrict__ Alo,
                                              const ushort_t* __restrict__ Bhi,
                                              const ushort_t* __restrict__ Blo,
                                              int K, int N,
                                              float* __restrict__ C,
                                              const float* __restrict__ Cin,
                                              ushort_t* __restrict__ Chi,
                                              ushort_t* __restrict__ Clo,
                                              ushort_t* __restrict__ oqh,
                                              ushort_t* __restrict__ oql,
                                              ushort_t* __restrict__ okh,
                                              ushort_t* __restrict__ okl,
                                              ushort_t* __restrict__ ovh,
                                              ushort_t* __restrict__ ovl) {
    __shared__ ushort_t sAhi[4096], sAlo[4096], sBhi[4096], sBlo[4096];
    const int tid = threadIdx.x;
    const int lane = tid & 63, w = tid >> 6;
    const int wm = w >> 1, wn = w & 1;
    const int bm = blockIdx.y, bn = blockIdx.x;
    const int sm = lane >> 2;          // staging row within 16-row chunk
    const int sk = (lane & 3) * 8;     // staging k offset
    const int fr = lane & 15;          // fragment row/col
    const int fq = lane >> 4;          // fragment quad
    const int fk = fq * 8;             // fragment k base

    float4_t acc[4][4] = {};

    for (int kt = 0; kt < K; kt += 32) {
        #pragma unroll
        for (int j = 0; j < 2; ++j) {
            const int chunk = w * 2 + j;
            const int mr = chunk * 16 + sm;
            const size_t ga = (size_t)(bm * 128 + mr) * K + kt + sk;
            const size_t gb = (size_t)(bn * 128 + mr) * K + kt + sk;
            gl_lds16(Ahi + ga, &sAhi[chunk * 512]);
            gl_lds16(Alo + ga, &sAlo[chunk * 512]);
            gl_lds16(Bhi + gb, &sBhi[chunk * 512]);
            gl_lds16(Blo + gb, &sBlo[chunk * 512]);
        }
        __syncthreads();   // drains vmcnt(0): staged tiles visible
        short8_t ah[4], al[4], bh[4], bl[4];
        #pragma unroll
        for (int t = 0; t < 4; ++t) {
            const int ao = (wm * 64 + t * 16 + fr) * 32 + fk;
            ah[t] = *(const short8_t*)&sAhi[ao];
            al[t] = *(const short8_t*)&sAlo[ao];
            const int bo = (wn * 64 + t * 16 + fr) * 32 + fk;
            bh[t] = *(const short8_t*)&sBhi[bo];
            bl[t] = *(const short8_t*)&sBlo[bo];
        }
        #pragma unroll
        for (int tm = 0; tm < 4; ++tm)
            #pragma unroll
            for (int tn = 0; tn < 4; ++tn) {
                acc[tm][tn] = MFMA16(ah[tm], bh[tn], acc[tm][tn]);
                acc[tm][tn] = MFMA16(al[tm], bh[tn], acc[tm][tn]);
                acc[tm][tn] = MFMA16(ah[tm], bl[tn], acc[tm][tn]);
            }
        __syncthreads();   // all frag reads done before next stage overwrites
    }

    // epilogue: C/D layout col = lane&15, row = (lane>>4)*4 + reg  [m89/m91]
    if (EPI == 0) {
        const int cb = bn * 128 + wn * 64;   // one head (64 cols) per wave-half
        const int mat = cb >> 9;             // 0=q 1=k 2=v
        const int hh = (cb >> 6) & 7;
        // hoist freq: depends only on d1 = tn*16+fr (tn in {0,1})
        float inv0 = powf(10000.0f, -(float)(fr) * (1.0f / 32.0f));
        float inv1 = powf(10000.0f, -(float)(16 + fr) * (1.0f / 32.0f));
        #pragma unroll
        for (int tm = 0; tm < 4; ++tm) {
            #pragma unroll
            for (int r = 0; r < 4; ++r) {
                const int mg = bm * 128 + wm * 64 + tm * 16 + fq * 4 + r;
                const int b = mg >> 11, s = mg & 2047;
                const int bhh = b * NHEAD + hh;
                if (mat < 2) {
                    ushort_t* dhi = (mat == 0) ? oqh : okh;
                    ushort_t* dlo = (mat == 0) ? oql : okl;
                    const size_t base = ((size_t)bhh * S_LEN + s) * DH;
                    #pragma unroll
                    for (int tn = 0; tn < 2; ++tn) {
                        const int d1 = tn * 16 + fr;
                        const float v1 = acc[tm][tn][r], v2 = acc[tm][tn + 2][r];
                        float sn, cs;
                        sincosf((float)s * (tn ? inv1 : inv0), &sn, &cs);
                        const float r1 = v1 * cs - v2 * sn;
                        const float r2 = v1 * sn + v2 * cs;
                        ushort_t h1 = f2bf(r1), h2 = f2bf(r2);
                        dhi[base + d1]      = h1;
                        dlo[base + d1]      = f2bf(r1 - bf2f(h1));
                        dhi[base + d1 + 32] = h2;
                        dlo[base + d1 + 32] = f2bf(r2 - bf2f(h2));
                    }
                } else {
                    #pragma unroll
                    for (int tn = 0; tn < 4; ++tn) {
                        const int d = tn * 16 + fr;
                        const float y = acc[tm][tn][r];
                        const size_t off = ((size_t)bhh * DH + d) * S_LEN + s;
                        ushort_t h = f2bf(y);
                        ovh[off] = h;
                        ovl[off] = f2bf(y - bf2f(h));
                    }
                }
            }
        }
    } else {
        #pragma unroll
        for (int tm = 0; tm < 4; ++tm) {
            #pragma unroll
            for (int tn = 0; tn < 4; ++tn) {
                const int cb = bn * 128 + wn * 64 + tn * 16;
                #pragma unroll
                for (int r = 0; r < 4; ++r) {
                    const int mg = bm * 128 + wm * 64 + tm * 16 + fq * 4 + r;
                    const float val = acc[tm][tn][r];
                    const size_t off = (size_t)mg * N + cb + fr;
                    if (EPI == 1) {
                        C[off] = Cin[off] + val;
                    } else {
                        const float g = gelu_f(val);
                        const ushort_t hi = f2bf(g);
                        Chi[off] = hi;
                        Clo[off] = f2bf(g - bf2f(hi));
                    }
                }
            }
        }
    }
}

// ---------------- MFMA causal flash attention, bf16x3 split ------------------
// grid (S/64, B*H). 64 Q-rows/block, 4 waves each own 16 rows.
// All tiles in [kk][64][32] ushort LDS layout; K/Vt staged per kt via gl_lds16.
__global__ __launch_bounds__(256) void attn_k(const ushort_t* __restrict__ qhi,
                                              const ushort_t* __restrict__ qlo,
                                              const ushort_t* __restrict__ khi,
                                              const ushort_t* __restrict__ klo,
                                              const ushort_t* __restrict__ vthi,
                                              const ushort_t* __restrict__ vtlo,
                                              ushort_t* __restrict__ Ohi,
                                              ushort_t* __restrict__ Olo) {
    __shared__ __align__(16) ushort_t sQh[4096], sQl[4096];
    __shared__ __align__(16) ushort_t sKh[4096], sKl[4096];
    __shared__ __align__(16) ushort_t sVh[4096], sVl[4096];
    __shared__ __align__(16) ushort_t sPh[4096], sPl[4096];
    const int tid = threadIdx.x, lane = tid & 63, w = tid >> 6;
    const int fr = lane & 15, fq = lane >> 4;
    const int qt = blockIdx.x, bh = blockIdx.y;

    const size_t qoff = ((size_t)bh * S_LEN + qt * 64) * DH;
    stage_tile(qhi + qoff, 64, sQh, w, lane);
    stage_tile(qlo + qoff, 64, sQl, w, lane);

    float m_r[4], l_r[4];
    float4_t oacc[4] = {};
    #pragma unroll
    for (int r = 0; r < 4; ++r) { m_r[r] = -INFINITY; l_r[r] = 0.0f; }

    for (int kt = 0; kt <= qt; ++kt) {
        __syncthreads();   // prior frag reads (incl. Q-stage on kt=0) done
        const size_t ko = ((size_t)bh * S_LEN + kt * 64) * DH;
        stage_tile(khi + ko, 64, sKh, w, lane);
        stage_tile(klo + ko, 64, sKl, w, lane);
        const size_t vo = (size_t)bh * DH * S_LEN + kt * 64;
        stage_tile(vthi + vo, S_LEN, sVh, w, lane);
        stage_tile(vtlo + vo, S_LEN, sVl, w, lane);
        __syncthreads();   // vmcnt drained: K/Vt visible

        // ---- QK^T: S[m=16 rows of wave][n=64 j] over k=d=64 ----
        float4_t sacc[4] = {};
        #pragma unroll
        for (int kk = 0; kk < 2; ++kk) {
            const int ab = kk * 2048 + (w * 16 + fr) * 32 + fq * 8;
            short8_t qh = *(const short8_t*)&sQh[ab];
            short8_t ql = *(const short8_t*)&sQl[ab];
            #pragma unroll
            for (int n = 0; n < 4; ++n) {
                const int bb = kk * 2048 + (n * 16 + fr) * 32 + fq * 8;
                short8_t kh = *(const short8_t*)&sKh[bb];
                short8_t kl = *(const short8_t*)&sKl[bb];
                sacc[n] = MFMA16(qh, kh, sacc[n]);
                sacc[n] = MFMA16(ql, kh, sacc[n]);
                sacc[n] = MFMA16(qh, kl, sacc[n]);
            }
        }

        // ---- online softmax (rows fq*4+r of wave tile, cols n*16+fr) ----
        const bool diag = (kt == qt);
        float al[4];
        #pragma unroll
        for (int r = 0; r < 4; ++r) {
            const int rowl = fq * 4 + r;           // row within wave's 16
            float sv[4], mx = -INFINITY;
            #pragma unroll
            for (int n = 0; n < 4; ++n) {
                float x = sacc[n][r] * 0.125f;
                if (diag && (n * 16 + fr) > (w * 16 + rowl)) x = -1e30f;
                sv[n] = x;
                mx = fmaxf(mx, x);
            }
            mx = fmaxf(mx, __shfl_xor(mx, 1));
            mx = fmaxf(mx, __shfl_xor(mx, 2));
            mx = fmaxf(mx, __shfl_xor(mx, 4));
            mx = fmaxf(mx, __shfl_xor(mx, 8));
            const float mn = fmaxf(m_r[r], mx);
            al[r] = expf(m_r[r] - mn);
            m_r[r] = mn;
            float ls = 0.0f;
            #pragma unroll
            for (int n = 0; n < 4; ++n) {
                const float p = expf(sv[n] - mn);
                const int idx = (n >> 1) * 2048 + (w * 16 + rowl) * 32 + (n & 1) * 16 + fr;
                const ushort_t ph = f2bf(p);
                sPh[idx] = ph;
                sPl[idx] = f2bf(p - bf2f(ph));
                ls += p;
            }
            ls += __shfl_xor(ls, 1);
            ls += __shfl_xor(ls, 2);
            ls += __shfl_xor(ls, 4);
            ls += __shfl_xor(ls, 8);
            l_r[r] = al[r] * l_r[r] + ls;
            #pragma unroll
            for (int n = 0; n < 4; ++n) oacc[n][r] *= al[r];
        }
        // P rows are wave-private (wave w writes+reads rows w*16..+15): no barrier.

        // ---- PV: O[m][n=64 d] over k=j=64 ----
        #pragma unroll
        for (int kkj = 0; kkj < 2; ++kkj) {
            const int ab = kkj * 2048 + (w * 16 + fr) * 32 + fq * 8;
            short8_t ph = *(const short8_t*)&sPh[ab];
            short8_t pl = *(const short8_t*)&sPl[ab];
            #pragma unroll
            for (int n = 0; n < 4; ++n) {
                const int bb = kkj * 2048 + (n * 16 + fr) * 32 + fq * 8;
                short8_t vh = *(const short8_t*)&sVh[bb];
                short8_t vl = *(const short8_t*)&sVl[bb];
                oacc[n] = MFMA16(ph, vh, oacc[n]);
                oacc[n] = MFMA16(pl, vh, oacc[n]);
                oacc[n] = MFMA16(ph, vl, oacc[n]);
            }
        }
    }

    // ---- epilogue: O -> [b][s][512] split bf16 ----
    const int b = bh >> 3, hh = bh & 7;
    #pragma unroll
    for (int r = 0; r < 4; ++r) {
        const float inv_l = 1.0f / l_r[r];
        const int s = qt * 64 + w * 16 + fq * 4 + r;
        const size_t base = ((size_t)b * S_LEN + s) * DMODEL + hh * DH;
        #pragma unroll
        for (int n = 0; n < 4; ++n) {
            const float y = oacc[n][r] * inv_l;
            const ushort_t h = f2bf(y);
            Ohi[base + n * 16 + fr] = h;
            Olo[base + n * 16 + fr] = f2bf(y - bf2f(h));
        }
    }
}

// ---------------- head: logits -> sigmoid -> probs (+loss accum) ------------
__global__ __launch_bounds__(256) void head_k(const float* __restrict__ x,
                                              const float* __restrict__ w,
                                              const float* __restrict__ b,
                                              float* __restrict__ probs,
                                              float* __restrict__ loss_out) {
    const int tid = threadIdx.x;
    const int lane = tid & 63;
    const size_t row = (size_t)blockIdx.x * 4 + (tid >> 6);
    const float* xr = x + row * DMODEL;
    float acc = 0.0f;
    #pragma unroll
    for (int i = 0; i < 8; ++i) acc += xr[lane + i * 64] * w[lane + i * 64];
    #pragma unroll
    for (int off = 32; off; off >>= 1) acc += __shfl_down(acc, off);
    if (lane == 0) {
        float p = 1.0f / (1.0f + expf(-(acc + b[0])));
        probs[row] = p;
        atomicAdd(loss_out, p * 0.25f);
    }
}

// ---------------- chunk id scan: one block per batch -------------------------
__global__ void chunk_k(const float* __restrict__ probs, int* __restrict__ ids,
                        float* __restrict__ avg_out) {
    __shared__ int flagbuf[S_LEN];
    __shared__ int nxt[S_LEN + 1];
    __shared__ int anyf;
    const int b = blockIdx.x;
    const int tid = threadIdx.x;
    const float* pr = probs + (size_t)b * S_LEN;
    if (tid == 0) anyf = 0;
    __syncthreads();
    for (int t = tid; t < S_LEN; t += 256) {
        int f = pr[t] > 0.5f ? 1 : 0;
        flagbuf[t] = f;
        if (f) atomicOr(&anyf, 1);
    }
    __syncthreads();
    if (tid == 0) {
        const int any = anyf;
        const int BIG = S_LEN + 1;
        auto idxf = [&](int i) -> int {
            bool he = any ? (i >= 1 && flagbuf[i - 1]) : (i == S_LEN - 1);
            return he ? i : BIG;
        };
        int cur = idxf(S_LEN);
        nxt[S_LEN] = cur;
        for (int t = S_LEN - 1; t >= 1; --t) {
            int ix = idxf(t);
            cur = ix < cur ? ix : cur;
            nxt[t] = cur;
        }
        int cur_end = 0, cid = -1;
        for (int t = 0; t < S_LEN; ++t) {
            if (t == cur_end) {
                int cap = t + 16; if (cap > S_LEN) cap = S_LEN;
                int e = nxt[t + 1];
                if (e > cap) e = cap;
                if (e - t < 3) { e = t + 3; if (e > S_LEN) e = S_LEN; }
                cur_end = e;
                cid++;
            }
            ids[(size_t)b * S_LEN + t] = cid;
        }
        atomicAdd(avg_out, 512.0f / (float)(cid + 1));
    }
}

// ---------------- masks ------------------------------------------------------
__global__ __launch_bounds__(256) void masks_k(const int* __restrict__ ids,
                                               float* __restrict__ mask) {
    const int bq = blockIdx.x;
    const int b = bq >> 11;
    const int myid = ids[bq];
    const int* idr = ids + (size_t)b * S_LEN;
    float* mr = mask + (size_t)bq * S_LEN;
    for (int k = threadIdx.x; k < S_LEN; k += 256)
        mr[k] = (idr[k] == myid) ? 1.0f : 0.0f;
}

extern "C" void kernel_launch(void* const* d_in, const int* in_sizes, int n_in,
                              void* d_out, int out_size, void* d_ws, size_t ws_size,
                              hipStream_t stream) {
    (void)in_sizes; (void)n_in; (void)out_size; (void)ws_size;
    const float* x      = (const float*)d_in[0];
    const int*   x_ids  = (const int*)d_in[1];
    const float* ln1    = (const float*)d_in[2];
    const float* Wq     = (const float*)d_in[3];
    const float* Wk     = (const float*)d_in[4];
    const float* Wv     = (const float*)d_in[5];
    const float* Wo     = (const float*)d_in[6];
    const float* ln2    = (const float*)d_in[7];
    const float* W1     = (const float*)d_in[8];
    const float* W2     = (const float*)d_in[9];
    const float* head_w = (const float*)d_in[10];
    const float* head_b = (const float*)d_in[11];

    float* out = (float*)d_out;
    ushort_t* u = (ushort_t*)d_ws;
    // ws layout (ushort offsets), total 41,975,808 ushorts = 83.95 MB (same as R2):
    ushort_t* qh   = u;                 // [32 bh][2048 s][64 d] roped q hi
    ushort_t* ql   = u + 4194304;
    ushort_t* kh   = u + 8388608;       // roped k
    ushort_t* kl   = u + 12582912;
    ushort_t* vth  = u + 16777216;      // v transposed [32 bh][64 d][2048 s]
    ushort_t* vtl  = u + 20971520;
    ushort_t* ohi  = u + 25165824;      // attn out [8192][512]
    ushort_t* olo  = u + 29360128;
    ushort_t* hhi  = u + 33554432;      // rmsnorm out [8192][512]
    ushort_t* hlo  = u + 37748736;
    ushort_t* ffhi = u;                 // [8192][2048]; overlays q..k (dead after attn)
    ushort_t* fflo = u + 16777216;      // overlays vt..o (dead after Wo gemm)
    float*    probs = (float*)(u + 41943040);
    int*      ids   = (int*)(u + 41943040 + 16384);
    // weight-split scratch inside out's mask region (dead until masks_k):
    ushort_t* wbuf     = (ushort_t*)(out + 4202512);   // 16B-aligned
    ushort_t* qkvT_hi  = wbuf;                         // [1536][512]
    ushort_t* qkvT_lo  = wbuf + 786432;
    ushort_t* woT_hi   = wbuf + 1572864;               // [512][512]
    ushort_t* woT_lo   = wbuf + 1835008;
    ushort_t* w1T_hi   = wbuf + 2097152;               // [2048][512]
    ushort_t* w1T_lo   = wbuf + 3145728;
    ushort_t* w2T_hi   = wbuf + 4194304;               // [512][2048]
    ushort_t* w2T_lo   = wbuf + 5242880;
    float* xbuf = out;   // running x lives in x_t output slot

    copy_init_k<<<4096, 256, 0, stream>>>(x, x_ids, out);

    for (int l = 0; l < 2; ++l) {
        const float* Wq_l = Wq + (size_t)l * DMODEL * DMODEL;
        const float* Wk_l = Wk + (size_t)l * DMODEL * DMODEL;
        const float* Wv_l = Wv + (size_t)l * DMODEL * DMODEL;
        const float* Wo_l = Wo + (size_t)l * DMODEL * DMODEL;
        const float* W1_l = W1 + (size_t)l * DMODEL * FDIM;
        const float* W2_l = W2 + (size_t)l * FDIM * DMODEL;

        tsplit_k<<<dim3(16, 16), 256, 0, stream>>>(Wq_l, qkvT_hi,          qkvT_lo,          512, 512);
        tsplit_k<<<dim3(16, 16), 256, 0, stream>>>(Wk_l, qkvT_hi + 262144, qkvT_lo + 262144, 512, 512);
        tsplit_k<<<dim3(16, 16), 256, 0, stream>>>(Wv_l, qkvT_hi + 524288, qkvT_lo + 524288, 512, 512);
        tsplit_k<<<dim3(16, 16), 256, 0, stream>>>(Wo_l, woT_hi, woT_lo, 512, 512);
        tsplit_k<<<dim3(64, 16), 256, 0, stream>>>(W1_l, w1T_hi, w1T_lo, 512, 2048);
        tsplit_k<<<dim3(16, 64), 256, 0, stream>>>(W2_l, w2T_hi, w2T_lo, 2048, 512);

        rmsnorm_split_k<<<8192, 256, 0, stream>>>(xbuf, ln1 + l * DMODEL, hhi, hlo);
        gemm_s<0><<<dim3(12, 64), 256, 0, stream>>>(hhi, hlo, qkvT_hi, qkvT_lo, 512, 1536,
                                                    nullptr, nullptr, nullptr, nullptr,
                                                    qh, ql, kh, kl, vth, vtl);
        attn_k<<<dim3(32, 32), 256, 0, stream>>>(qh, ql, kh, kl, vth, vtl, ohi, olo);
        gemm_s<1><<<dim3(4, 64), 256, 0, stream>>>(ohi, olo, woT_hi, woT_lo, 512, 512,
                                                   xbuf, xbuf, nullptr, nullptr,
                                                   nullptr, nullptr, nullptr, nullptr, nullptr, nullptr);
        rmsnorm_split_k<<<8192, 256, 0, stream>>>(xbuf, ln2 + l * DMODEL, hhi, hlo);
        gemm_s<2><<<dim3(16, 64), 256, 0, stream>>>(hhi, hlo, w1T_hi, w1T_lo, 512, 2048,
                                                    nullptr, nullptr, ffhi, fflo,
                                                    nullptr, nullptr, nullptr, nullptr, nullptr, nullptr);
        gemm_s<1><<<dim3(4, 64), 256, 0, stream>>>(ffhi, fflo, w2T_hi, w2T_lo, 2048, 512,
                                                   xbuf, xbuf, nullptr, nullptr,
                                                   nullptr, nullptr, nullptr, nullptr, nullptr, nullptr);
    }

    head_k<<<2048, 256, 0, stream>>>(xbuf, head_w, head_b, probs, out + 20979713);
    chunk_k<<<4, 256, 0, stream>>>(probs, ids, out + 4202496);
    masks_k<<<8192, 256, 0, stream>>>(ids, out + 4202497);
}

// Round 4
// 1377.955 us; speedup vs baseline: 2.2075x; 1.1385x over previous
//
#include <hip/hip_runtime.h>
#include <math.h>

#define S_LEN 2048
#define DMODEL 512
#define NHEAD 8
#define DH 64
#define FDIM 2048

typedef unsigned short ushort_t;
typedef __attribute__((ext_vector_type(8))) short short8_t;   // 8 bf16 = 4 VGPRs
typedef __attribute__((ext_vector_type(4))) float float4_t;   // MFMA acc

#define MFMA16(a, b, c) __builtin_amdgcn_mfma_f32_16x16x32_bf16(a, b, c, 0, 0, 0)

// ---- output layout (floats) ----
// x_t: [0, 4194304)  x_ids: [4194304, 4202496)  avg: 4202496
// masks: [4202497, 20979713)  loss: 20979713
// masks region doubles as weight-split + rope-table scratch (dead until masks_k).

__device__ __forceinline__ ushort_t f2bf(float x) {            // RNE fp32->bf16
    unsigned u = __float_as_uint(x);
    return (ushort_t)((u + 0x7fffu + ((u >> 16) & 1u)) >> 16);
}
__device__ __forceinline__ float bf2f(ushort_t h) {
    return __uint_as_float((unsigned)h << 16);
}
__device__ __forceinline__ float gelu_f(float x) {
    return 0.5f * x * (1.0f + erff(x * 0.70710678118654752440f));
}
__device__ __forceinline__ void gl_lds16(const void* g, void* l) {
    __builtin_amdgcn_global_load_lds(
        (const __attribute__((address_space(1))) void*)g,
        (__attribute__((address_space(3))) void*)l, 16, 0, 0);
}

// stage a 64x64 bf16 tile (row stride rs ushorts) into LDS [kk][64][32] (4096 ushorts).
// chunk c = (w*2+j)*64 + lane keeps LDS dest = base + lane*16 per instruction.
__device__ __forceinline__ void stage_tile(const ushort_t* __restrict__ g, int rs,
                                           ushort_t* __restrict__ s, int w, int lane) {
    #pragma unroll
    for (int j = 0; j < 2; ++j) {
        const int c = (w * 2 + j) * 64 + lane;
        const int kk = c >> 8, row = (c >> 2) & 63, q = c & 3;
        gl_lds16(g + (size_t)row * rs + kk * 32 + q * 8, s + c * 8);
    }
}

// ---------------- copy x -> out, ids -> out, zero scalar slots --------------
__global__ void copy_init_k(const float* __restrict__ x, const int* __restrict__ x_ids,
                            float* __restrict__ out) {
    size_t i = (size_t)blockIdx.x * blockDim.x + threadIdx.x;
    float4* o4 = (float4*)out;
    o4[i] = ((const float4*)x)[i];
    if (i < 2048) {
        int4 id4 = ((const int4*)x_ids)[i];
        o4[1048576 + i] = make_float4((float)id4.x, (float)id4.y, (float)id4.z, (float)id4.w);
    }
    if (i == 0) { out[4202496] = 0.0f; out[20979713] = 0.0f; }
}

// ---------------- RoPE cos/sin table: tab[s*32+f] = (cos, sin) --------------
__global__ __launch_bounds__(256) void rope_tab_k(float2* __restrict__ tab) {
    const int i = blockIdx.x * 256 + threadIdx.x;   // 65536
    const int s = i >> 5, f = i & 31;
    float inv = powf(10000.0f, -(float)f * (1.0f / 32.0f));
    float sn, cs;
    sincosf((float)s * inv, &sn, &cs);
    tab[i] = make_float2(cs, sn);
}

// ---------------- weight transpose + split: T[n][k] = split(W[k][n]) --------
__global__ __launch_bounds__(256) void tsplit_k(const float* __restrict__ W,
                                                ushort_t* __restrict__ Thi,
                                                ushort_t* __restrict__ Tlo,
                                                int K, int N) {
    __shared__ float T[32][33];
    const int tx = threadIdx.x & 31, ty = threadIdx.x >> 5;
    const int n0 = blockIdx.x * 32, k0 = blockIdx.y * 32;
    #pragma unroll
    for (int i = 0; i < 4; ++i)
        T[ty + 8 * i][tx] = W[(size_t)(k0 + ty + 8 * i) * N + n0 + tx];
    __syncthreads();
    #pragma unroll
    for (int i = 0; i < 4; ++i) {
        const int n = ty + 8 * i;
        float x = T[tx][n];
        ushort_t hi = f2bf(x);
        Thi[(size_t)(n0 + n) * K + k0 + tx] = hi;
        Tlo[(size_t)(n0 + n) * K + k0 + tx] = f2bf(x - bf2f(hi));
    }
}

// ---------------- RMSNorm -> hi/lo bf16 split --------------------------------
__global__ __launch_bounds__(256) void rmsnorm_split_k(const float* __restrict__ x,
                                                       const float* __restrict__ w,
                                                       ushort_t* __restrict__ hhi,
                                                       ushort_t* __restrict__ hlo) {
    __shared__ float red[4];
    const int tid = threadIdx.x;
    const size_t row = blockIdx.x;
    const float* xr = x + row * DMODEL;
    float2 v = *(const float2*)(xr + tid * 2);
    float ss = v.x * v.x + v.y * v.y;
    #pragma unroll
    for (int off = 32; off; off >>= 1) ss += __shfl_down(ss, off);
    if ((tid & 63) == 0) red[tid >> 6] = ss;
    __syncthreads();
    float tot = red[0] + red[1] + red[2] + red[3];
    float rs = 1.0f / sqrtf(tot * (1.0f / 512.0f) + 1e-6f);
    float2 wv = *(const float2*)(w + tid * 2);
    float y0 = v.x * rs * wv.x, y1 = v.y * rs * wv.y;
    ushort_t h0 = f2bf(y0), h1 = f2bf(y1);
    ushort_t l0 = f2bf(y0 - bf2f(h0)), l1 = f2bf(y1 - bf2f(h1));
    *(unsigned*)(hhi + row * DMODEL + tid * 2) = ((unsigned)h1 << 16) | h0;
    *(unsigned*)(hlo + row * DMODEL + tid * 2) = ((unsigned)l1 << 16) | l0;
}

// ---------------- bf16x3 split MFMA GEMM ------------------------------------
// A: [M][K] hi/lo bf16 row-major. B: [N][K] hi/lo bf16 (transposed weights).
// 128x128 tile, BK=32, 4 waves, each wave 64x64 (4x4 of 16x16x32 MFMA).
// EPI 0: fused QKV epilogue (N=1536): RoPE (table) q/k -> split bf16 [bh][s][64];
//        v -> hi bf16 transposed [bh][d][S].
// EPI 1: C = Cin + acc (fp32 residual)
// EPI 2: gelu(acc) -> Chi/Clo bf16 split
template<int EPI>
__global__ __launch_bounds__(256) void gemm_s(const ushort_t* __restrict__ Ahi,
                                              const ushort_t* __restrict__ Alo,
                                              const ushort_t* __restrict__ Bhi,
                                              const ushort_t* __restrict__ Blo,
                                              int K, int N,
                                              float* __restrict__ C,
                                              const float* __restrict__ Cin,
                                              ushort_t* __restrict__ Chi,
                                              ushort_t* __restrict__ Clo,
                                              ushort_t* __restrict__ oqh,
                                              ushort_t* __restrict__ oql,
                                              ushort_t* __restrict__ okh,
                                              ushort_t* __restrict__ okl,
                                              ushort_t* __restrict__ ovh,
                                              const float2* __restrict__ rtab) {
    __shared__ ushort_t sAhi[4096], sAlo[4096], sBhi[4096], sBlo[4096];
    const int tid = threadIdx.x;
    const int lane = tid & 63, w = tid >> 6;
    const int wm = w >> 1, wn = w & 1;
    const int bm = blockIdx.y, bn = blockIdx.x;
    const int sm = lane >> 2;          // staging row within 16-row chunk
    const int sk = (lane & 3) * 8;     // staging k offset
    const int fr = lane & 15;          // fragment row/col
    const int fq = lane >> 4;          // fragment quad
    const int fk = fq * 8;             // fragment k base

    float4_t acc[4][4] = {};

    for (int kt = 0; kt < K; kt += 32) {
        #pragma unroll
        for (int j = 0; j < 2; ++j) {
            const int chunk = w * 2 + j;
            const int mr = chunk * 16 + sm;
            const size_t ga = (size_t)(bm * 128 + mr) * K + kt + sk;
            const size_t gb = (size_t)(bn * 128 + mr) * K + kt + sk;
            gl_lds16(Ahi + ga, &sAhi[chunk * 512]);
            gl_lds16(Alo + ga, &sAlo[chunk * 512]);
            gl_lds16(Bhi + gb, &sBhi[chunk * 512]);
            gl_lds16(Blo + gb, &sBlo[chunk * 512]);
        }
        __syncthreads();   // drains vmcnt(0): staged tiles visible
        short8_t ah[4], al[4], bh[4], bl[4];
        #pragma unroll
        for (int t = 0; t < 4; ++t) {
            const int ao = (wm * 64 + t * 16 + fr) * 32 + fk;
            ah[t] = *(const short8_t*)&sAhi[ao];
            al[t] = *(const short8_t*)&sAlo[ao];
            const int bo = (wn * 64 + t * 16 + fr) * 32 + fk;
            bh[t] = *(const short8_t*)&sBhi[bo];
            bl[t] = *(const short8_t*)&sBlo[bo];
        }
        #pragma unroll
        for (int tm = 0; tm < 4; ++tm)
            #pragma unroll
            for (int tn = 0; tn < 4; ++tn) {
                acc[tm][tn] = MFMA16(ah[tm], bh[tn], acc[tm][tn]);
                acc[tm][tn] = MFMA16(al[tm], bh[tn], acc[tm][tn]);
                acc[tm][tn] = MFMA16(ah[tm], bl[tn], acc[tm][tn]);
            }
        __syncthreads();   // all frag reads done before next stage overwrites
    }

    // epilogue: C/D layout col = lane&15, row = (lane>>4)*4 + reg  [m89/m91]
    if (EPI == 0) {
        const int cb = bn * 128 + wn * 64;   // one head (64 cols) per wave-half
        const int mat = cb >> 9;             // 0=q 1=k 2=v
        const int hh = (cb >> 6) & 7;
        #pragma unroll
        for (int tm = 0; tm < 4; ++tm) {
            #pragma unroll
            for (int r = 0; r < 4; ++r) {
                const int mg = bm * 128 + wm * 64 + tm * 16 + fq * 4 + r;
                const int b = mg >> 11, s = mg & 2047;
                const int bhh = b * NHEAD + hh;
                if (mat < 2) {
                    ushort_t* dhi = (mat == 0) ? oqh : okh;
                    ushort_t* dlo = (mat == 0) ? oql : okl;
                    const size_t base = ((size_t)bhh * S_LEN + s) * DH;
                    #pragma unroll
                    for (int tn = 0; tn < 2; ++tn) {
                        const int d1 = tn * 16 + fr;
                        const float v1 = acc[tm][tn][r], v2 = acc[tm][tn + 2][r];
                        const float2 t = rtab[s * 32 + d1];
                        const float r1 = v1 * t.x - v2 * t.y;
                        const float r2 = v1 * t.y + v2 * t.x;
                        ushort_t h1 = f2bf(r1), h2 = f2bf(r2);
                        dhi[base + d1]      = h1;
                        dlo[base + d1]      = f2bf(r1 - bf2f(h1));
                        dhi[base + d1 + 32] = h2;
                        dlo[base + d1 + 32] = f2bf(r2 - bf2f(h2));
                    }
                } else {
                    #pragma unroll
                    for (int tn = 0; tn < 4; ++tn) {
                        const int d = tn * 16 + fr;
                        const size_t off = ((size_t)bhh * DH + d) * S_LEN + s;
                        ovh[off] = f2bf(acc[tm][tn][r]);
                    }
                }
            }
        }
    } else {
        #pragma unroll
        for (int tm = 0; tm < 4; ++tm) {
            #pragma unroll
            for (int tn = 0; tn < 4; ++tn) {
                const int cb = bn * 128 + wn * 64 + tn * 16;
                #pragma unroll
                for (int r = 0; r < 4; ++r) {
                    const int mg = bm * 128 + wm * 64 + tm * 16 + fq * 4 + r;
                    const float val = acc[tm][tn][r];
                    const size_t off = (size_t)mg * N + cb + fr;
                    if (EPI == 1) {
                        C[off] = Cin[off] + val;
                    } else {
                        const float g = gelu_f(val);
                        const ushort_t hi = f2bf(g);
                        Chi[off] = hi;
                        Clo[off] = f2bf(g - bf2f(hi));
                    }
                }
            }
        }
    }
}

// ---------------- MFMA causal flash attention --------------------------------
// grid (S/64, B*H), qt reversed (heavy blocks dispatch first). 64 Q-rows/block,
// 4 waves each own 16 rows. Q split frags in registers (wave-private rows).
// QK^T in bf16x3 split (feeds exp); PV in hi-only bf16 (one rounding, ~1e-3).
// LDS: K hi/lo + V hi + P hi = 32 KB.
__global__ __launch_bounds__(256) void attn_k(const ushort_t* __restrict__ qhi,
                                              const ushort_t* __restrict__ qlo,
                                              const ushort_t* __restrict__ khi,
                                              const ushort_t* __restrict__ klo,
                                              const ushort_t* __restrict__ vthi,
                                              ushort_t* __restrict__ Ohi,
                                              ushort_t* __restrict__ Olo) {
    __shared__ __align__(16) ushort_t sKh[4096], sKl[4096];
    __shared__ __align__(16) ushort_t sVh[4096], sPh[4096];
    const int tid = threadIdx.x, lane = tid & 63, w = tid >> 6;
    const int fr = lane & 15, fq = lane >> 4;
    const int qt = 31 - blockIdx.x, bh = blockIdx.y;

    // Q fragments in registers: row qt*64 + w*16 + fr, k-cols kk*32 + fq*8
    short8_t qfh[2], qfl[2];
    {
        const size_t base = ((size_t)bh * S_LEN + qt * 64 + w * 16 + fr) * DH + fq * 8;
        qfh[0] = *(const short8_t*)(qhi + base);
        qfh[1] = *(const short8_t*)(qhi + base + 32);
        qfl[0] = *(const short8_t*)(qlo + base);
        qfl[1] = *(const short8_t*)(qlo + base + 32);
    }

    float m_r[4], l_r[4];
    float4_t oacc[4] = {};
    #pragma unroll
    for (int r = 0; r < 4; ++r) { m_r[r] = -INFINITY; l_r[r] = 0.0f; }

    for (int kt = 0; kt <= qt; ++kt) {
        __syncthreads();   // prior iteration's frag reads done
        const size_t ko = ((size_t)bh * S_LEN + kt * 64) * DH;
        stage_tile(khi + ko, 64, sKh, w, lane);
        stage_tile(klo + ko, 64, sKl, w, lane);
        const size_t vo = (size_t)bh * DH * S_LEN + kt * 64;
        stage_tile(vthi + vo, S_LEN, sVh, w, lane);
        __syncthreads();   // vmcnt drained: K/V visible

        // ---- QK^T: S[wave's 16 rows][64 j] over d=64, split x3 ----
        float4_t sacc[4] = {};
        #pragma unroll
        for (int kk = 0; kk < 2; ++kk) {
            #pragma unroll
            for (int n = 0; n < 4; ++n) {
                const int bb = kk * 2048 + (n * 16 + fr) * 32 + fq * 8;
                short8_t kh = *(const short8_t*)&sKh[bb];
                short8_t kl = *(const short8_t*)&sKl[bb];
                sacc[n] = MFMA16(qfh[kk], kh, sacc[n]);
                sacc[n] = MFMA16(qfl[kk], kh, sacc[n]);
                sacc[n] = MFMA16(qfh[kk], kl, sacc[n]);
            }
        }

        // ---- online softmax (rows fq*4+r, cols n*16+fr) ----
        const bool diag = (kt == qt);
        #pragma unroll
        for (int r = 0; r < 4; ++r) {
            const int rowl = fq * 4 + r;           // row within wave's 16
            float sv[4], mx = -INFINITY;
            #pragma unroll
            for (int n = 0; n < 4; ++n) {
                float x = sacc[n][r] * 0.125f;
                if (diag && (n * 16 + fr) > (w * 16 + rowl)) x = -1e30f;
                sv[n] = x;
                mx = fmaxf(mx, x);
            }
            mx = fmaxf(mx, __shfl_xor(mx, 1));
            mx = fmaxf(mx, __shfl_xor(mx, 2));
            mx = fmaxf(mx, __shfl_xor(mx, 4));
            mx = fmaxf(mx, __shfl_xor(mx, 8));
            const float mn = fmaxf(m_r[r], mx);
            const float al = expf(m_r[r] - mn);
            m_r[r] = mn;
            float ls = 0.0f;
            #pragma unroll
            for (int n = 0; n < 4; ++n) {
                const float p = expf(sv[n] - mn);
                const int idx = (n >> 1) * 2048 + (w * 16 + rowl) * 32 + (n & 1) * 16 + fr;
                sPh[idx] = f2bf(p);
                ls += p;
            }
            ls += __shfl_xor(ls, 1);
            ls += __shfl_xor(ls, 2);
            ls += __shfl_xor(ls, 4);
            ls += __shfl_xor(ls, 8);
            l_r[r] = al * l_r[r] + ls;
            #pragma unroll
            for (int n = 0; n < 4; ++n) oacc[n][r] *= al;
        }
        // P rows are wave-private (wave w writes+reads rows w*16..+15): no barrier.

        // ---- PV: O[16 rows][64 d] over j=64, hi-only ----
        #pragma unroll
        for (int kkj = 0; kkj < 2; ++kkj) {
            short8_t ph = *(const short8_t*)&sPh[kkj * 2048 + (w * 16 + fr) * 32 + fq * 8];
            #pragma unroll
            for (int n = 0; n < 4; ++n) {
                short8_t vh = *(const short8_t*)&sVh[kkj * 2048 + (n * 16 + fr) * 32 + fq * 8];
                oacc[n] = MFMA16(ph, vh, oacc[n]);
            }
        }
    }

    // ---- epilogue: O -> [b][s][512] split bf16 ----
    const int b = bh >> 3, hh = bh & 7;
    #pragma unroll
    for (int r = 0; r < 4; ++r) {
        const float inv_l = 1.0f / l_r[r];
        const int s = qt * 64 + w * 16 + fq * 4 + r;
        const size_t base = ((size_t)b * S_LEN + s) * DMODEL + hh * DH;
        #pragma unroll
        for (int n = 0; n < 4; ++n) {
            const float y = oacc[n][r] * inv_l;
            const ushort_t h = f2bf(y);
            Ohi[base + n * 16 + fr] = h;
            Olo[base + n * 16 + fr] = f2bf(y - bf2f(h));
        }
    }
}

// ---------------- head: logits -> sigmoid -> probs (+loss accum) ------------
__global__ __launch_bounds__(256) void head_k(const float* __restrict__ x,
                                              const float* __restrict__ w,
                                              const float* __restrict__ b,
                                              float* __restrict__ probs,
                                              float* __restrict__ loss_out) {
    const int tid = threadIdx.x;
    const int lane = tid & 63;
    const size_t row = (size_t)blockIdx.x * 4 + (tid >> 6);
    const float* xr = x + row * DMODEL;
    float acc = 0.0f;
    #pragma unroll
    for (int i = 0; i < 8; ++i) acc += xr[lane + i * 64] * w[lane + i * 64];
    #pragma unroll
    for (int off = 32; off; off >>= 1) acc += __shfl_down(acc, off);
    if (lane == 0) {
        float p = 1.0f / (1.0f + expf(-(acc + b[0])));
        probs[row] = p;
        atomicAdd(loss_out, p * 0.25f);
    }
}

// ---------------- chunk id scan: one block per batch -------------------------
__global__ void chunk_k(const float* __restrict__ probs, int* __restrict__ ids,
                        float* __restrict__ avg_out) {
    __shared__ int flagbuf[S_LEN];
    __shared__ int nxt[S_LEN + 1];
    __shared__ int anyf;
    const int b = blockIdx.x;
    const int tid = threadIdx.x;
    const float* pr = probs + (size_t)b * S_LEN;
    if (tid == 0) anyf = 0;
    __syncthreads();
    for (int t = tid; t < S_LEN; t += 256) {
        int f = pr[t] > 0.5f ? 1 : 0;
        flagbuf[t] = f;
        if (f) atomicOr(&anyf, 1);
    }
    __syncthreads();
    if (tid == 0) {
        const int any = anyf;
        const int BIG = S_LEN + 1;
        auto idxf = [&](int i) -> int {
            bool he = any ? (i >= 1 && flagbuf[i - 1]) : (i == S_LEN - 1);
            return he ? i : BIG;
        };
        int cur = idxf(S_LEN);
        nxt[S_LEN] = cur;
        for (int t = S_LEN - 1; t >= 1; --t) {
            int ix = idxf(t);
            cur = ix < cur ? ix : cur;
            nxt[t] = cur;
        }
        int cur_end = 0, cid = -1;
        for (int t = 0; t < S_LEN; ++t) {
            if (t == cur_end) {
                int cap = t + 16; if (cap > S_LEN) cap = S_LEN;
                int e = nxt[t + 1];
                if (e > cap) e = cap;
                if (e - t < 3) { e = t + 3; if (e > S_LEN) e = S_LEN; }
                cur_end = e;
                cid++;
            }
            ids[(size_t)b * S_LEN + t] = cid;
        }
        atomicAdd(avg_out, 512.0f / (float)(cid + 1));
    }
}

// ---------------- masks ------------------------------------------------------
__global__ __launch_bounds__(256) void masks_k(const int* __restrict__ ids,
                                               float* __restrict__ mask) {
    const int bq = blockIdx.x;
    const int b = bq >> 11;
    const int myid = ids[bq];
    const int* idr = ids + (size_t)b * S_LEN;
    float* mr = mask + (size_t)bq * S_LEN;
    for (int k = threadIdx.x; k < S_LEN; k += 256)
        mr[k] = (idr[k] == myid) ? 1.0f : 0.0f;
}

extern "C" void kernel_launch(void* const* d_in, const int* in_sizes, int n_in,
                              void* d_out, int out_size, void* d_ws, size_t ws_size,
                              hipStream_t stream) {
    (void)in_sizes; (void)n_in; (void)out_size; (void)ws_size;
    const float* x      = (const float*)d_in[0];
    const int*   x_ids  = (const int*)d_in[1];
    const float* ln1    = (const float*)d_in[2];
    const float* Wq     = (const float*)d_in[3];
    const float* Wk     = (const float*)d_in[4];
    const float* Wv     = (const float*)d_in[5];
    const float* Wo     = (const float*)d_in[6];
    const float* ln2    = (const float*)d_in[7];
    const float* W1     = (const float*)d_in[8];
    const float* W2     = (const float*)d_in[9];
    const float* head_w = (const float*)d_in[10];
    const float* head_b = (const float*)d_in[11];

    float* out = (float*)d_out;
    ushort_t* u = (ushort_t*)d_ws;
    // ws layout (ushort offsets):
    ushort_t* qh   = u;                 // [32 bh][2048 s][64 d] roped q hi
    ushort_t* ql   = u + 4194304;
    ushort_t* kh   = u + 8388608;       // roped k
    ushort_t* kl   = u + 12582912;
    ushort_t* vth  = u + 16777216;      // v transposed hi [32 bh][64 d][2048 s]
    ushort_t* ohi  = u + 25165824;      // attn out [8192][512]
    ushort_t* olo  = u + 29360128;
    ushort_t* hhi  = u + 33554432;      // rmsnorm out [8192][512]
    ushort_t* hlo  = u + 37748736;
    ushort_t* ffhi = u;                 // [8192][2048]; overlays q..k (dead after attn)
    ushort_t* fflo = u + 16777216;      // overlays vt..o (dead after Wo gemm)
    float*    probs = (float*)(u + 41943040);
    int*      ids   = (int*)(u + 41943040 + 16384);
    // weight-split + rope-table scratch inside out's mask region (dead until masks_k):
    ushort_t* wbuf     = (ushort_t*)(out + 4202512);   // 16B-aligned
    ushort_t* qkvT_hi  = wbuf;                         // [1536][512]
    ushort_t* qkvT_lo  = wbuf + 786432;
    ushort_t* woT_hi   = wbuf + 1572864;               // [512][512]
    ushort_t* woT_lo   = wbuf + 1835008;
    ushort_t* w1T_hi   = wbuf + 2097152;               // [2048][512]
    ushort_t* w1T_lo   = wbuf + 3145728;
    ushort_t* w2T_hi   = wbuf + 4194304;               // [512][2048]
    ushort_t* w2T_lo   = wbuf + 5242880;
    float2*   rope_tab = (float2*)(wbuf + 6291456);    // [2048][32] (cos,sin)
    float* xbuf = out;   // running x lives in x_t output slot

    copy_init_k<<<4096, 256, 0, stream>>>(x, x_ids, out);
    rope_tab_k<<<256, 256, 0, stream>>>(rope_tab);

    for (int l = 0; l < 2; ++l) {
        const float* Wq_l = Wq + (size_t)l * DMODEL * DMODEL;
        const float* Wk_l = Wk + (size_t)l * DMODEL * DMODEL;
        const float* Wv_l = Wv + (size_t)l * DMODEL * DMODEL;
        const float* Wo_l = Wo + (size_t)l * DMODEL * DMODEL;
        const float* W1_l = W1 + (size_t)l * DMODEL * FDIM;
        const float* W2_l = W2 + (size_t)l * FDIM * DMODEL;

        tsplit_k<<<dim3(16, 16), 256, 0, stream>>>(Wq_l, qkvT_hi,          qkvT_lo,          512, 512);
        tsplit_k<<<dim3(16, 16), 256, 0, stream>>>(Wk_l, qkvT_hi + 262144, qkvT_lo + 262144, 512, 512);
        tsplit_k<<<dim3(16, 16), 256, 0, stream>>>(Wv_l, qkvT_hi + 524288, qkvT_lo + 524288, 512, 512);
        tsplit_k<<<dim3(16, 16), 256, 0, stream>>>(Wo_l, woT_hi, woT_lo, 512, 512);
        tsplit_k<<<dim3(64, 16), 256, 0, stream>>>(W1_l, w1T_hi, w1T_lo, 512, 2048);
        tsplit_k<<<dim3(16, 64), 256, 0, stream>>>(W2_l, w2T_hi, w2T_lo, 2048, 512);

        rmsnorm_split_k<<<8192, 256, 0, stream>>>(xbuf, ln1 + l * DMODEL, hhi, hlo);
        gemm_s<0><<<dim3(12, 64), 256, 0, stream>>>(hhi, hlo, qkvT_hi, qkvT_lo, 512, 1536,
                                                    nullptr, nullptr, nullptr, nullptr,
                                                    qh, ql, kh, kl, vth, rope_tab);
        attn_k<<<dim3(32, 32), 256, 0, stream>>>(qh, ql, kh, kl, vth, ohi, olo);
        gemm_s<1><<<dim3(4, 64), 256, 0, stream>>>(ohi, olo, woT_hi, woT_lo, 512, 512,
                                                   xbuf, xbuf, nullptr, nullptr,
                                                   nullptr, nullptr, nullptr, nullptr, nullptr, nullptr);
        rmsnorm_split_k<<<8192, 256, 0, stream>>>(xbuf, ln2 + l * DMODEL, hhi, hlo);
        gemm_s<2><<<dim3(16, 64), 256, 0, stream>>>(hhi, hlo, w1T_hi, w1T_lo, 512, 2048,
                                                    nullptr, nullptr, ffhi, fflo,
                                                    nullptr, nullptr, nullptr, nullptr, nullptr, nullptr);
        gemm_s<1><<<dim3(4, 64), 256, 0, stream>>>(ffhi, fflo, w2T_hi, w2T_lo, 2048, 512,
                                                   xbuf, xbuf, nullptr, nullptr,
                                                   nullptr, nullptr, nullptr, nullptr, nullptr, nullptr);
    }

    head_k<<<2048, 256, 0, stream>>>(xbuf, head_w, head_b, probs, out + 20979713);
    chunk_k<<<4, 256, 0, stream>>>(probs, ids, out + 4202496);
    masks_k<<<8192, 256, 0, stream>>>(ids, out + 4202497);
}

// Round 5
// 1183.338 us; speedup vs baseline: 2.5706x; 1.1645x over previous
//
#include <hip/hip_runtime.h>
#include <math.h>

#define S_LEN 2048
#define DMODEL 512
#define NHEAD 8
#define DH 64
#define FDIM 2048

typedef unsigned short ushort_t;
typedef __attribute__((ext_vector_type(8))) short short8_t;   // 8 bf16 = 4 VGPRs
typedef __attribute__((ext_vector_type(4))) float float4_t;   // MFMA acc

#define MFMA16(a, b, c) __builtin_amdgcn_mfma_f32_16x16x32_bf16(a, b, c, 0, 0, 0)

// ---- output layout (floats) ----
// x_t: [0, 4194304)  x_ids: [4194304, 4202496)  avg: 4202496
// masks: [4202497, 20979713)  loss: 20979713
// masks region doubles as weight-split + rope-table scratch (dead until masks_k).

__device__ __forceinline__ ushort_t f2bf(float x) {            // RNE fp32->bf16
    unsigned u = __float_as_uint(x);
    return (ushort_t)((u + 0x7fffu + ((u >> 16) & 1u)) >> 16);
}
__device__ __forceinline__ float bf2f(ushort_t h) {
    return __uint_as_float((unsigned)h << 16);
}
__device__ __forceinline__ float gelu_f(float x) {
    return 0.5f * x * (1.0f + erff(x * 0.70710678118654752440f));
}
__device__ __forceinline__ void gl_lds16(const void* g, void* l) {
    __builtin_amdgcn_global_load_lds(
        (const __attribute__((address_space(1))) void*)g,
        (__attribute__((address_space(3))) void*)l, 16, 0, 0);
}

// stage a 64x64 bf16 tile (row stride rs ushorts) into LDS [kk][64][32] (4096 ushorts).
__device__ __forceinline__ void stage_tile(const ushort_t* __restrict__ g, int rs,
                                           ushort_t* __restrict__ s, int w, int lane) {
    #pragma unroll
    for (int j = 0; j < 2; ++j) {
        const int c = (w * 2 + j) * 64 + lane;
        const int kk = c >> 8, row = (c >> 2) & 63, q = c & 3;
        gl_lds16(g + (size_t)row * rs + kk * 32 + q * 8, s + c * 8);
    }
}

// ---------------- copy x -> out, ids -> out, zero scalar slots --------------
__global__ void copy_init_k(const float* __restrict__ x, const int* __restrict__ x_ids,
                            float* __restrict__ out) {
    size_t i = (size_t)blockIdx.x * blockDim.x + threadIdx.x;
    float4* o4 = (float4*)out;
    o4[i] = ((const float4*)x)[i];
    if (i < 2048) {
        int4 id4 = ((const int4*)x_ids)[i];
        o4[1048576 + i] = make_float4((float)id4.x, (float)id4.y, (float)id4.z, (float)id4.w);
    }
    if (i == 0) { out[4202496] = 0.0f; out[20979713] = 0.0f; }
}

// ---------------- RoPE cos/sin table: tab[s*32+f] = (cos, sin) --------------
__global__ __launch_bounds__(256) void rope_tab_k(float2* __restrict__ tab) {
    const int i = blockIdx.x * 256 + threadIdx.x;   // 65536
    const int s = i >> 5, f = i & 31;
    float inv = powf(10000.0f, -(float)f * (1.0f / 32.0f));
    float sn, cs;
    sincosf((float)s * inv, &sn, &cs);
    tab[i] = make_float2(cs, sn);
}

// ---------------- weight transpose + split: T[n][k] = split(W[k][n]) --------
__global__ __launch_bounds__(256) void tsplit_k(const float* __restrict__ W,
                                                ushort_t* __restrict__ Thi,
                                                ushort_t* __restrict__ Tlo,
                                                int K, int N) {
    __shared__ float T[32][33];
    const int tx = threadIdx.x & 31, ty = threadIdx.x >> 5;
    const int n0 = blockIdx.x * 32, k0 = blockIdx.y * 32;
    #pragma unroll
    for (int i = 0; i < 4; ++i)
        T[ty + 8 * i][tx] = W[(size_t)(k0 + ty + 8 * i) * N + n0 + tx];
    __syncthreads();
    #pragma unroll
    for (int i = 0; i < 4; ++i) {
        const int n = ty + 8 * i;
        float x = T[tx][n];
        ushort_t hi = f2bf(x);
        Thi[(size_t)(n0 + n) * K + k0 + tx] = hi;
        Tlo[(size_t)(n0 + n) * K + k0 + tx] = f2bf(x - bf2f(hi));
    }
}

// ---------------- RMSNorm -> hi/lo bf16 split --------------------------------
__global__ __launch_bounds__(256) void rmsnorm_split_k(const float* __restrict__ x,
                                                       const float* __restrict__ w,
                                                       ushort_t* __restrict__ hhi,
                                                       ushort_t* __restrict__ hlo) {
    __shared__ float red[4];
    const int tid = threadIdx.x;
    const size_t row = blockIdx.x;
    const float* xr = x + row * DMODEL;
    float2 v = *(const float2*)(xr + tid * 2);
    float ss = v.x * v.x + v.y * v.y;
    #pragma unroll
    for (int off = 32; off; off >>= 1) ss += __shfl_down(ss, off);
    if ((tid & 63) == 0) red[tid >> 6] = ss;
    __syncthreads();
    float tot = red[0] + red[1] + red[2] + red[3];
    float rs = 1.0f / sqrtf(tot * (1.0f / 512.0f) + 1e-6f);
    float2 wv = *(const float2*)(w + tid * 2);
    float y0 = v.x * rs * wv.x, y1 = v.y * rs * wv.y;
    ushort_t h0 = f2bf(y0), h1 = f2bf(y1);
    ushort_t l0 = f2bf(y0 - bf2f(h0)), l1 = f2bf(y1 - bf2f(h1));
    *(unsigned*)(hhi + row * DMODEL + tid * 2) = ((unsigned)h1 << 16) | h0;
    *(unsigned*)(hlo + row * DMODEL + tid * 2) = ((unsigned)l1 << 16) | l0;
}

// ---------------- bf16x3 split MFMA GEMM ------------------------------------
template<int EPI>
__global__ __launch_bounds__(256) void gemm_s(const ushort_t* __restrict__ Ahi,
                                              const ushort_t* __restrict__ Alo,
                                              const ushort_t* __restrict__ Bhi,
                                              const ushort_t* __restrict__ Blo,
                                              int K, int N,
                                              float* __restrict__ C,
                                              const float* __restrict__ Cin,
                                              ushort_t* __restrict__ Chi,
                                              ushort_t* __restrict__ Clo,
                                              ushort_t* __restrict__ oqh,
                                              ushort_t* __restrict__ oql,
                                              ushort_t* __restrict__ okh,
                                              ushort_t* __restrict__ okl,
                                              ushort_t* __restrict__ ovh,
                                              const float2* __restrict__ rtab) {
    __shared__ ushort_t sAhi[4096], sAlo[4096], sBhi[4096], sBlo[4096];
    const int tid = threadIdx.x;
    const int lane = tid & 63, w = tid >> 6;
    const int wm = w >> 1, wn = w & 1;
    const int bm = blockIdx.y, bn = blockIdx.x;
    const int sm = lane >> 2;
    const int sk = (lane & 3) * 8;
    const int fr = lane & 15;
    const int fq = lane >> 4;
    const int fk = fq * 8;

    float4_t acc[4][4] = {};

    for (int kt = 0; kt < K; kt += 32) {
        #pragma unroll
        for (int j = 0; j < 2; ++j) {
            const int chunk = w * 2 + j;
            const int mr = chunk * 16 + sm;
            const size_t ga = (size_t)(bm * 128 + mr) * K + kt + sk;
            const size_t gb = (size_t)(bn * 128 + mr) * K + kt + sk;
            gl_lds16(Ahi + ga, &sAhi[chunk * 512]);
            gl_lds16(Alo + ga, &sAlo[chunk * 512]);
            gl_lds16(Bhi + gb, &sBhi[chunk * 512]);
            gl_lds16(Blo + gb, &sBlo[chunk * 512]);
        }
        __syncthreads();
        short8_t ah[4], al[4], bh[4], bl[4];
        #pragma unroll
        for (int t = 0; t < 4; ++t) {
            const int ao = (wm * 64 + t * 16 + fr) * 32 + fk;
            ah[t] = *(const short8_t*)&sAhi[ao];
            al[t] = *(const short8_t*)&sAlo[ao];
            const int bo = (wn * 64 + t * 16 + fr) * 32 + fk;
            bh[t] = *(const short8_t*)&sBhi[bo];
            bl[t] = *(const short8_t*)&sBlo[bo];
        }
        #pragma unroll
        for (int tm = 0; tm < 4; ++tm)
            #pragma unroll
            for (int tn = 0; tn < 4; ++tn) {
                acc[tm][tn] = MFMA16(ah[tm], bh[tn], acc[tm][tn]);
                acc[tm][tn] = MFMA16(al[tm], bh[tn], acc[tm][tn]);
                acc[tm][tn] = MFMA16(ah[tm], bl[tn], acc[tm][tn]);
            }
        __syncthreads();
    }

    if (EPI == 0) {
        const int cb = bn * 128 + wn * 64;
        const int mat = cb >> 9;
        const int hh = (cb >> 6) & 7;
        #pragma unroll
        for (int tm = 0; tm < 4; ++tm) {
            #pragma unroll
            for (int r = 0; r < 4; ++r) {
                const int mg = bm * 128 + wm * 64 + tm * 16 + fq * 4 + r;
                const int b = mg >> 11, s = mg & 2047;
                const int bhh = b * NHEAD + hh;
                if (mat < 2) {
                    ushort_t* dhi = (mat == 0) ? oqh : okh;
                    ushort_t* dlo = (mat == 0) ? oql : okl;
                    const size_t base = ((size_t)bhh * S_LEN + s) * DH;
                    #pragma unroll
                    for (int tn = 0; tn < 2; ++tn) {
                        const int d1 = tn * 16 + fr;
                        const float v1 = acc[tm][tn][r], v2 = acc[tm][tn + 2][r];
                        const float2 t = rtab[s * 32 + d1];
                        const float r1 = v1 * t.x - v2 * t.y;
                        const float r2 = v1 * t.y + v2 * t.x;
                        ushort_t h1 = f2bf(r1), h2 = f2bf(r2);
                        dhi[base + d1]      = h1;
                        dlo[base + d1]      = f2bf(r1 - bf2f(h1));
                        dhi[base + d1 + 32] = h2;
                        dlo[base + d1 + 32] = f2bf(r2 - bf2f(h2));
                    }
                } else {
                    #pragma unroll
                    for (int tn = 0; tn < 4; ++tn) {
                        const int d = tn * 16 + fr;
                        const size_t off = ((size_t)bhh * DH + d) * S_LEN + s;
                        ovh[off] = f2bf(acc[tm][tn][r]);
                    }
                }
            }
        }
    } else {
        #pragma unroll
        for (int tm = 0; tm < 4; ++tm) {
            #pragma unroll
            for (int tn = 0; tn < 4; ++tn) {
                const int cb = bn * 128 + wn * 64 + tn * 16;
                #pragma unroll
                for (int r = 0; r < 4; ++r) {
                    const int mg = bm * 128 + wm * 64 + tm * 16 + fq * 4 + r;
                    const float val = acc[tm][tn][r];
                    const size_t off = (size_t)mg * N + cb + fr;
                    if (EPI == 1) {
                        C[off] = Cin[off] + val;
                    } else {
                        const float g = gelu_f(val);
                        const ushort_t hi = f2bf(g);
                        Chi[off] = hi;
                        Clo[off] = f2bf(g - bf2f(hi));
                    }
                }
            }
        }
    }
}

// ---------------- MFMA causal flash attention --------------------------------
__global__ __launch_bounds__(256) void attn_k(const ushort_t* __restrict__ qhi,
                                              const ushort_t* __restrict__ qlo,
                                              const ushort_t* __restrict__ khi,
                                              const ushort_t* __restrict__ klo,
                                              const ushort_t* __restrict__ vthi,
                                              ushort_t* __restrict__ Ohi,
                                              ushort_t* __restrict__ Olo) {
    __shared__ __align__(16) ushort_t sKh[4096], sKl[4096];
    __shared__ __align__(16) ushort_t sVh[4096], sPh[4096];
    const int tid = threadIdx.x, lane = tid & 63, w = tid >> 6;
    const int fr = lane & 15, fq = lane >> 4;
    const int qt = 31 - blockIdx.x, bh = blockIdx.y;

    short8_t qfh[2], qfl[2];
    {
        const size_t base = ((size_t)bh * S_LEN + qt * 64 + w * 16 + fr) * DH + fq * 8;
        qfh[0] = *(const short8_t*)(qhi + base);
        qfh[1] = *(const short8_t*)(qhi + base + 32);
        qfl[0] = *(const short8_t*)(qlo + base);
        qfl[1] = *(const short8_t*)(qlo + base + 32);
    }

    float m_r[4], l_r[4];
    float4_t oacc[4] = {};
    #pragma unroll
    for (int r = 0; r < 4; ++r) { m_r[r] = -INFINITY; l_r[r] = 0.0f; }

    for (int kt = 0; kt <= qt; ++kt) {
        __syncthreads();
        const size_t ko = ((size_t)bh * S_LEN + kt * 64) * DH;
        stage_tile(khi + ko, 64, sKh, w, lane);
        stage_tile(klo + ko, 64, sKl, w, lane);
        const size_t vo = (size_t)bh * DH * S_LEN + kt * 64;
        stage_tile(vthi + vo, S_LEN, sVh, w, lane);
        __syncthreads();

        float4_t sacc[4] = {};
        #pragma unroll
        for (int kk = 0; kk < 2; ++kk) {
            #pragma unroll
            for (int n = 0; n < 4; ++n) {
                const int bb = kk * 2048 + (n * 16 + fr) * 32 + fq * 8;
                short8_t kh = *(const short8_t*)&sKh[bb];
                short8_t kl = *(const short8_t*)&sKl[bb];
                sacc[n] = MFMA16(qfh[kk], kh, sacc[n]);
                sacc[n] = MFMA16(qfl[kk], kh, sacc[n]);
                sacc[n] = MFMA16(qfh[kk], kl, sacc[n]);
            }
        }

        const bool diag = (kt == qt);
        #pragma unroll
        for (int r = 0; r < 4; ++r) {
            const int rowl = fq * 4 + r;
            float sv[4], mx = -INFINITY;
            #pragma unroll
            for (int n = 0; n < 4; ++n) {
                float x = sacc[n][r] * 0.125f;
                if (diag && (n * 16 + fr) > (w * 16 + rowl)) x = -1e30f;
                sv[n] = x;
                mx = fmaxf(mx, x);
            }
            mx = fmaxf(mx, __shfl_xor(mx, 1));
            mx = fmaxf(mx, __shfl_xor(mx, 2));
            mx = fmaxf(mx, __shfl_xor(mx, 4));
            mx = fmaxf(mx, __shfl_xor(mx, 8));
            const float mn = fmaxf(m_r[r], mx);
            const float al = expf(m_r[r] - mn);
            m_r[r] = mn;
            float ls = 0.0f;
            #pragma unroll
            for (int n = 0; n < 4; ++n) {
                const float p = expf(sv[n] - mn);
                const int idx = (n >> 1) * 2048 + (w * 16 + rowl) * 32 + (n & 1) * 16 + fr;
                sPh[idx] = f2bf(p);
                ls += p;
            }
            ls += __shfl_xor(ls, 1);
            ls += __shfl_xor(ls, 2);
            ls += __shfl_xor(ls, 4);
            ls += __shfl_xor(ls, 8);
            l_r[r] = al * l_r[r] + ls;
            #pragma unroll
            for (int n = 0; n < 4; ++n) oacc[n][r] *= al;
        }

        #pragma unroll
        for (int kkj = 0; kkj < 2; ++kkj) {
            short8_t ph = *(const short8_t*)&sPh[kkj * 2048 + (w * 16 + fr) * 32 + fq * 8];
            #pragma unroll
            for (int n = 0; n < 4; ++n) {
                short8_t vh = *(const short8_t*)&sVh[kkj * 2048 + (n * 16 + fr) * 32 + fq * 8];
                oacc[n] = MFMA16(ph, vh, oacc[n]);
            }
        }
    }

    const int b = bh >> 3, hh = bh & 7;
    #pragma unroll
    for (int r = 0; r < 4; ++r) {
        const float inv_l = 1.0f / l_r[r];
        const int s = qt * 64 + w * 16 + fq * 4 + r;
        const size_t base = ((size_t)b * S_LEN + s) * DMODEL + hh * DH;
        #pragma unroll
        for (int n = 0; n < 4; ++n) {
            const float y = oacc[n][r] * inv_l;
            const ushort_t h = f2bf(y);
            Ohi[base + n * 16 + fr] = h;
            Olo[base + n * 16 + fr] = f2bf(y - bf2f(h));
        }
    }
}

// ---------------- head: logits -> sigmoid -> probs (+loss accum) ------------
__global__ __launch_bounds__(256) void head_k(const float* __restrict__ x,
                                              const float* __restrict__ w,
                                              const float* __restrict__ b,
                                              float* __restrict__ probs,
                                              float* __restrict__ loss_out) {
    const int tid = threadIdx.x;
    const int lane = tid & 63;
    const size_t row = (size_t)blockIdx.x * 4 + (tid >> 6);
    const float* xr = x + row * DMODEL;
    float acc = 0.0f;
    #pragma unroll
    for (int i = 0; i < 8; ++i) acc += xr[lane + i * 64] * w[lane + i * 64];
    #pragma unroll
    for (int off = 32; off; off >>= 1) acc += __shfl_down(acc, off);
    if (lane == 0) {
        float p = 1.0f / (1.0f + expf(-(acc + b[0])));
        probs[row] = p;
        atomicAdd(loss_out, p * 0.25f);
    }
}

// ---------------- chunk id scan, parallel (binary lifting) -------------------
// succ[t] (next chunk start) is parallel-computable from nxt[] (suffix-min of
// flag positions). Chunk starts = orbit of 0 under succ (strictly increasing),
// ids[t] = max m : succ^m(0) <= t, answered via 10-level binary lifting.
// All values <= S+1 fit in ushort; saturation at S never accepted in queries
// since queries require landing <= t <= S-1.
__global__ __launch_bounds__(256) void chunk_k(const float* __restrict__ probs,
                                               int* __restrict__ ids,
                                               float* __restrict__ avg_out) {
    __shared__ ushort_t nxA[2052], nxB[2052];
    __shared__ ushort_t lift[10][2052];
    __shared__ int anyf;
    const int b = blockIdx.x, tid = threadIdx.x;
    const float* pr = probs + (size_t)b * S_LEN;
    if (tid == 0) anyf = 0;
    __syncthreads();
    int loc = 0;
    for (int t = tid; t < S_LEN; t += 256) loc |= (pr[t] > 0.5f) ? 1 : 0;
    if (loc) atomicOr(&anyf, 1);
    __syncthreads();
    const int any = anyf;
    // idx over [0..S]: has_end[i] = flags[i-1] (i>=1); fallback: only i==S-1.
    for (int i = tid; i <= S_LEN; i += 256) {
        const bool he = any ? (i >= 1 && pr[i - 1] > 0.5f) : (i == S_LEN - 1);
        nxA[i] = he ? (ushort_t)i : (ushort_t)(S_LEN + 1);
    }
    __syncthreads();
    // suffix-min over 2049 elements: 12 Hillis-Steele rounds, ping-pong.
    ushort_t* src = nxA;
    ushort_t* dst = nxB;
    for (int d = 1; d <= 2048; d <<= 1) {
        for (int i = tid; i <= S_LEN; i += 256) {
            ushort_t v = src[i];
            if (i + d <= S_LEN) { ushort_t u2 = src[i + d]; v = u2 < v ? u2 : v; }
            dst[i] = v;
        }
        __syncthreads();
        ushort_t* tmp = src; src = dst; dst = tmp;
    }
    // src == nxt[]. Build lift[0] = succ.
    for (int t = tid; t < S_LEN; t += 256) {
        int cap = t + 16; if (cap > S_LEN) cap = S_LEN;
        int e = src[t + 1];
        if (e > cap) e = cap;
        if (e - t < 3) { e = t + 3; if (e > S_LEN) e = S_LEN; }
        lift[0][t] = (ushort_t)e;
    }
    if (tid == 0) lift[0][S_LEN] = (ushort_t)S_LEN;   // saturate at S
    __syncthreads();
    for (int j = 1; j < 10; ++j) {
        for (int t = tid; t <= S_LEN; t += 256)
            lift[j][t] = lift[j - 1][lift[j - 1][t]];
        __syncthreads();
    }
    // query: ids[t] = number of succ-steps from 0 staying <= t.
    for (int t = tid; t < S_LEN; t += 256) {
        int pos = 0, cid = 0;
        #pragma unroll
        for (int j = 9; j >= 0; --j) {
            const int p2 = lift[j][pos];
            if (p2 <= t) { pos = p2; cid += (1 << j); }
        }
        ids[(size_t)b * S_LEN + t] = cid;
        if (t == S_LEN - 1) atomicAdd(avg_out, 512.0f / (float)(cid + 1));
    }
}

// ---------------- masks ------------------------------------------------------
__global__ __launch_bounds__(256) void masks_k(const int* __restrict__ ids,
                                               float* __restrict__ mask) {
    const int bq = blockIdx.x;
    const int b = bq >> 11;
    const int myid = ids[bq];
    const int* idr = ids + (size_t)b * S_LEN;
    float* mr = mask + (size_t)bq * S_LEN;
    for (int k = threadIdx.x; k < S_LEN; k += 256)
        mr[k] = (idr[k] == myid) ? 1.0f : 0.0f;
}

extern "C" void kernel_launch(void* const* d_in, const int* in_sizes, int n_in,
                              void* d_out, int out_size, void* d_ws, size_t ws_size,
                              hipStream_t stream) {
    (void)in_sizes; (void)n_in; (void)out_size; (void)ws_size;
    const float* x      = (const float*)d_in[0];
    const int*   x_ids  = (const int*)d_in[1];
    const float* ln1    = (const float*)d_in[2];
    const float* Wq     = (const float*)d_in[3];
    const float* Wk     = (const float*)d_in[4];
    const float* Wv     = (const float*)d_in[5];
    const float* Wo     = (const float*)d_in[6];
    const float* ln2    = (const float*)d_in[7];
    const float* W1     = (const float*)d_in[8];
    const float* W2     = (const float*)d_in[9];
    const float* head_w = (const float*)d_in[10];
    const float* head_b = (const float*)d_in[11];

    float* out = (float*)d_out;
    ushort_t* u = (ushort_t*)d_ws;
    ushort_t* qh   = u;                 // [32 bh][2048 s][64 d] roped q hi
    ushort_t* ql   = u + 4194304;
    ushort_t* kh   = u + 8388608;       // roped k
    ushort_t* kl   = u + 12582912;
    ushort_t* vth  = u + 16777216;      // v transposed hi [32 bh][64 d][2048 s]
    ushort_t* ohi  = u + 25165824;      // attn out [8192][512]
    ushort_t* olo  = u + 29360128;
    ushort_t* hhi  = u + 33554432;      // rmsnorm out [8192][512]
    ushort_t* hlo  = u + 37748736;
    ushort_t* ffhi = u;                 // [8192][2048]; overlays q..k (dead after attn)
    ushort_t* fflo = u + 16777216;      // overlays vt..o (dead after Wo gemm)
    float*    probs = (float*)(u + 41943040);
    int*      ids   = (int*)(u + 41943040 + 16384);
    ushort_t* wbuf     = (ushort_t*)(out + 4202512);   // 16B-aligned
    ushort_t* qkvT_hi  = wbuf;                         // [1536][512]
    ushort_t* qkvT_lo  = wbuf + 786432;
    ushort_t* woT_hi   = wbuf + 1572864;               // [512][512]
    ushort_t* woT_lo   = wbuf + 1835008;
    ushort_t* w1T_hi   = wbuf + 2097152;               // [2048][512]
    ushort_t* w1T_lo   = wbuf + 3145728;
    ushort_t* w2T_hi   = wbuf + 4194304;               // [512][2048]
    ushort_t* w2T_lo   = wbuf + 5242880;
    float2*   rope_tab = (float2*)(wbuf + 6291456);    // [2048][32] (cos,sin)
    float* xbuf = out;

    copy_init_k<<<4096, 256, 0, stream>>>(x, x_ids, out);
    rope_tab_k<<<256, 256, 0, stream>>>(rope_tab);

    for (int l = 0; l < 2; ++l) {
        const float* Wq_l = Wq + (size_t)l * DMODEL * DMODEL;
        const float* Wk_l = Wk + (size_t)l * DMODEL * DMODEL;
        const float* Wv_l = Wv + (size_t)l * DMODEL * DMODEL;
        const float* Wo_l = Wo + (size_t)l * DMODEL * DMODEL;
        const float* W1_l = W1 + (size_t)l * DMODEL * FDIM;
        const float* W2_l = W2 + (size_t)l * FDIM * DMODEL;

        tsplit_k<<<dim3(16, 16), 256, 0, stream>>>(Wq_l, qkvT_hi,          qkvT_lo,          512, 512);
        tsplit_k<<<dim3(16, 16), 256, 0, stream>>>(Wk_l, qkvT_hi + 262144, qkvT_lo + 262144, 512, 512);
        tsplit_k<<<dim3(16, 16), 256, 0, stream>>>(Wv_l, qkvT_hi + 524288, qkvT_lo + 524288, 512, 512);
        tsplit_k<<<dim3(16, 16), 256, 0, stream>>>(Wo_l, woT_hi, woT_lo, 512, 512);
        tsplit_k<<<dim3(64, 16), 256, 0, stream>>>(W1_l, w1T_hi, w1T_lo, 512, 2048);
        tsplit_k<<<dim3(16, 64), 256, 0, stream>>>(W2_l, w2T_hi, w2T_lo, 2048, 512);

        rmsnorm_split_k<<<8192, 256, 0, stream>>>(xbuf, ln1 + l * DMODEL, hhi, hlo);
        gemm_s<0><<<dim3(12, 64), 256, 0, stream>>>(hhi, hlo, qkvT_hi, qkvT_lo, 512, 1536,
                                                    nullptr, nullptr, nullptr, nullptr,
                                                    qh, ql, kh, kl, vth, rope_tab);
        attn_k<<<dim3(32, 32), 256, 0, stream>>>(qh, ql, kh, kl, vth, ohi, olo);
        gemm_s<1><<<dim3(4, 64), 256, 0, stream>>>(ohi, olo, woT_hi, woT_lo, 512, 512,
                                                   xbuf, xbuf, nullptr, nullptr,
                                                   nullptr, nullptr, nullptr, nullptr, nullptr, nullptr);
        rmsnorm_split_k<<<8192, 256, 0, stream>>>(xbuf, ln2 + l * DMODEL, hhi, hlo);
        gemm_s<2><<<dim3(16, 64), 256, 0, stream>>>(hhi, hlo, w1T_hi, w1T_lo, 512, 2048,
                                                    nullptr, nullptr, ffhi, fflo,
                                                    nullptr, nullptr, nullptr, nullptr, nullptr, nullptr);
        gemm_s<1><<<dim3(4, 64), 256, 0, stream>>>(ffhi, fflo, w2T_hi, w2T_lo, 2048, 512,
                                                   xbuf, xbuf, nullptr, nullptr,
                                                   nullptr, nullptr, nullptr, nullptr, nullptr, nullptr);
    }

    head_k<<<2048, 256, 0, stream>>>(xbuf, head_w, head_b, probs, out + 20979713);
    chunk_k<<<4, 256, 0, stream>>>(probs, ids, out + 4202496);
    masks_k<<<8192, 256, 0, stream>>>(ids, out + 4202497);
}

// Round 6
// 989.311 us; speedup vs baseline: 3.0747x; 1.1961x over previous
//
#include <hip/hip_runtime.h>
#include <math.h>

#define S_LEN 2048
#define DMODEL 512
#define NHEAD 8
#define DH 64
#define FDIM 2048

typedef unsigned short ushort_t;
typedef __attribute__((ext_vector_type(8))) short short8_t;   // 8 bf16 = 4 VGPRs
typedef __attribute__((ext_vector_type(4))) float float4_t;   // MFMA acc

#define MFMA16(a, b, c) __builtin_amdgcn_mfma_f32_16x16x32_bf16(a, b, c, 0, 0, 0)

// ---- output layout (floats) ----
// x_t: [0, 4194304)  x_ids: [4194304, 4202496)  avg: 4202496
// masks: [4202497, 20979713)  loss: 20979713
// masks region doubles as weight-split + rope-table scratch (dead until masks_k).

__device__ __forceinline__ ushort_t f2bf(float x) {            // RNE fp32->bf16
    unsigned u = __float_as_uint(x);
    return (ushort_t)((u + 0x7fffu + ((u >> 16) & 1u)) >> 16);
}
__device__ __forceinline__ float bf2f(ushort_t h) {
    return __uint_as_float((unsigned)h << 16);
}
__device__ __forceinline__ float gelu_f(float x) {
    return 0.5f * x * (1.0f + erff(x * 0.70710678118654752440f));
}
__device__ __forceinline__ void gl_lds16(const void* g, void* l) {
    __builtin_amdgcn_global_load_lds(
        (const __attribute__((address_space(1))) void*)g,
        (__attribute__((address_space(3))) void*)l, 16, 0, 0);
}

// stage a 64x64 bf16 tile (row stride rs ushorts) into LDS [kk][64][32] (4096 ushorts).
__device__ __forceinline__ void stage_tile(const ushort_t* __restrict__ g, int rs,
                                           ushort_t* __restrict__ s, int w, int lane) {
    #pragma unroll
    for (int j = 0; j < 2; ++j) {
        const int c = (w * 2 + j) * 64 + lane;
        const int kk = c >> 8, row = (c >> 2) & 63, q = c & 3;
        gl_lds16(g + (size_t)row * rs + kk * 32 + q * 8, s + c * 8);
    }
}

// ---------------- copy x -> out, ids -> out, zero scalar slots --------------
__global__ void copy_init_k(const float* __restrict__ x, const int* __restrict__ x_ids,
                            float* __restrict__ out) {
    size_t i = (size_t)blockIdx.x * blockDim.x + threadIdx.x;
    float4* o4 = (float4*)out;
    o4[i] = ((const float4*)x)[i];
    if (i < 2048) {
        int4 id4 = ((const int4*)x_ids)[i];
        o4[1048576 + i] = make_float4((float)id4.x, (float)id4.y, (float)id4.z, (float)id4.w);
    }
    if (i == 0) { out[4202496] = 0.0f; out[20979713] = 0.0f; }
}

// ---------------- RoPE cos/sin table: tab[s*32+f] = (cos, sin) --------------
__global__ __launch_bounds__(256) void rope_tab_k(float2* __restrict__ tab) {
    const int i = blockIdx.x * 256 + threadIdx.x;   // 65536
    const int s = i >> 5, f = i & 31;
    float inv = powf(10000.0f, -(float)f * (1.0f / 32.0f));
    float sn, cs;
    sincosf((float)s * inv, &sn, &cs);
    tab[i] = make_float2(cs, sn);
}

// ---------------- ALL weights transpose + split, one dispatch ----------------
// Per layer (3072 blocks): [0,768) Wq/Wk/Wv, [768,1024) Wo, [1024,2048) W1,
// [2048,3072) W2. Layer stride in wbuf = 6291456 ushorts.
__global__ __launch_bounds__(256) void tsplit_all_k(const float* __restrict__ Wq,
                                                    const float* __restrict__ Wk,
                                                    const float* __restrict__ Wv,
                                                    const float* __restrict__ Wo,
                                                    const float* __restrict__ W1,
                                                    const float* __restrict__ W2,
                                                    ushort_t* __restrict__ wbuf) {
    __shared__ float T[32][33];
    const int bid = blockIdx.x;
    const int l = bid / 3072;
    const int r = bid % 3072;
    ushort_t* lb = wbuf + (size_t)l * 6291456;
    const float* W; ushort_t* Thi; ushort_t* Tlo; int K, N, ntn, rr;
    if (r < 768) {
        const int which = r >> 8; rr = r & 255;
        W = (which == 0 ? Wq : which == 1 ? Wk : Wv) + (size_t)l * 262144;
        Thi = lb + which * 262144; Tlo = lb + 786432 + which * 262144;
        K = 512; N = 512; ntn = 16;
    } else if (r < 1024) {
        rr = r - 768; W = Wo + (size_t)l * 262144;
        Thi = lb + 1572864; Tlo = lb + 1835008; K = 512; N = 512; ntn = 16;
    } else if (r < 2048) {
        rr = r - 1024; W = W1 + (size_t)l * 1048576;
        Thi = lb + 2097152; Tlo = lb + 3145728; K = 512; N = 2048; ntn = 64;
    } else {
        rr = r - 2048; W = W2 + (size_t)l * 1048576;
        Thi = lb + 4194304; Tlo = lb + 5242880; K = 2048; N = 512; ntn = 16;
    }
    const int n0 = (rr % ntn) * 32, k0 = (rr / ntn) * 32;
    const int tx = threadIdx.x & 31, ty = threadIdx.x >> 5;
    #pragma unroll
    for (int i = 0; i < 4; ++i)
        T[ty + 8 * i][tx] = W[(size_t)(k0 + ty + 8 * i) * N + n0 + tx];
    __syncthreads();
    #pragma unroll
    for (int i = 0; i < 4; ++i) {
        const int n = ty + 8 * i;
        float x = T[tx][n];
        ushort_t hi = f2bf(x);
        Thi[(size_t)(n0 + n) * K + k0 + tx] = hi;
        Tlo[(size_t)(n0 + n) * K + k0 + tx] = f2bf(x - bf2f(hi));
    }
}

// ---------------- RMSNorm -> hi/lo bf16 split --------------------------------
__global__ __launch_bounds__(256) void rmsnorm_split_k(const float* __restrict__ x,
                                                       const float* __restrict__ w,
                                                       ushort_t* __restrict__ hhi,
                                                       ushort_t* __restrict__ hlo) {
    __shared__ float red[4];
    const int tid = threadIdx.x;
    const size_t row = blockIdx.x;
    const float* xr = x + row * DMODEL;
    float2 v = *(const float2*)(xr + tid * 2);
    float ss = v.x * v.x + v.y * v.y;
    #pragma unroll
    for (int off = 32; off; off >>= 1) ss += __shfl_down(ss, off);
    if ((tid & 63) == 0) red[tid >> 6] = ss;
    __syncthreads();
    float tot = red[0] + red[1] + red[2] + red[3];
    float rs = 1.0f / sqrtf(tot * (1.0f / 512.0f) + 1e-6f);
    float2 wv = *(const float2*)(w + tid * 2);
    float y0 = v.x * rs * wv.x, y1 = v.y * rs * wv.y;
    ushort_t h0 = f2bf(y0), h1 = f2bf(y1);
    ushort_t l0 = f2bf(y0 - bf2f(h0)), l1 = f2bf(y1 - bf2f(h1));
    *(unsigned*)(hhi + row * DMODEL + tid * 2) = ((unsigned)h1 << 16) | h0;
    *(unsigned*)(hlo + row * DMODEL + tid * 2) = ((unsigned)l1 << 16) | l0;
}

// ---------------- bf16x3 split MFMA GEMM ------------------------------------
// A [M][K], B [N][K] hi/lo bf16. 128 x TN tile, BK=32, 4 waves.
// TN=128: waves 2x2, wave=64x64 (4x4 tiles). TN=64: waves 4x1, wave=32x64
// (2x4 tiles) -> 2x more blocks for small-N GEMMs (occupancy).
// EPI 0 (TN=128): fused QKV: RoPE q/k (q pre-scaled by 1/8) -> split bf16;
//                 v -> hi bf16 transposed [bh][d][S].
// EPI 1: C = Cin + acc.  EPI 2: gelu -> split bf16.
template<int EPI, int TN>
__global__ __launch_bounds__(256) void gemm_s(const ushort_t* __restrict__ Ahi,
                                              const ushort_t* __restrict__ Alo,
                                              const ushort_t* __restrict__ Bhi,
                                              const ushort_t* __restrict__ Blo,
                                              int K, int N,
                                              float* __restrict__ C,
                                              const float* __restrict__ Cin,
                                              ushort_t* __restrict__ Chi,
                                              ushort_t* __restrict__ Clo,
                                              ushort_t* __restrict__ oqh,
                                              ushort_t* __restrict__ oql,
                                              ushort_t* __restrict__ okh,
                                              ushort_t* __restrict__ okl,
                                              ushort_t* __restrict__ ovh,
                                              const float2* __restrict__ rtab) {
    constexpr int MT = (TN == 128) ? 4 : 2;        // m-tiles per wave
    __shared__ ushort_t sAhi[4096], sAlo[4096];
    __shared__ ushort_t sBhi[TN * 32], sBlo[TN * 32];
    const int tid = threadIdx.x;
    const int lane = tid & 63, w = tid >> 6;
    const int wm = (TN == 128) ? (w >> 1) : w;
    const int wn = (TN == 128) ? (w & 1) : 0;
    const int bm = blockIdx.y, bn = blockIdx.x;
    const int sm = lane >> 2;
    const int sk = (lane & 3) * 8;
    const int fr = lane & 15;
    const int fq = lane >> 4;
    const int fk = fq * 8;

    float4_t acc[MT][4] = {};

    for (int kt = 0; kt < K; kt += 32) {
        #pragma unroll
        for (int j = 0; j < 2; ++j) {              // A: 8 chunks x 16 rows
            const int chunk = w * 2 + j;
            const int mr = chunk * 16 + sm;
            const size_t ga = (size_t)(bm * 128 + mr) * K + kt + sk;
            gl_lds16(Ahi + ga, &sAhi[chunk * 512]);
            gl_lds16(Alo + ga, &sAlo[chunk * 512]);
        }
        #pragma unroll
        for (int j = 0; j < TN / 64; ++j) {        // B: TN/16 chunks
            const int chunk = w * (TN / 64) + j;
            const int mr = chunk * 16 + sm;
            const size_t gb = (size_t)(bn * TN + mr) * K + kt + sk;
            gl_lds16(Bhi + gb, &sBhi[chunk * 512]);
            gl_lds16(Blo + gb, &sBlo[chunk * 512]);
        }
        __syncthreads();
        short8_t ah[MT], al[MT], bh[4], bl[4];
        #pragma unroll
        for (int t = 0; t < MT; ++t) {
            const int ao = (wm * (MT * 16) + t * 16 + fr) * 32 + fk;
            ah[t] = *(const short8_t*)&sAhi[ao];
            al[t] = *(const short8_t*)&sAlo[ao];
        }
        #pragma unroll
        for (int t = 0; t < 4; ++t) {
            const int bo = (wn * 64 + t * 16 + fr) * 32 + fk;
            bh[t] = *(const short8_t*)&sBhi[bo];
            bl[t] = *(const short8_t*)&sBlo[bo];
        }
        #pragma unroll
        for (int tm = 0; tm < MT; ++tm)
            #pragma unroll
            for (int tn = 0; tn < 4; ++tn) {
                acc[tm][tn] = MFMA16(ah[tm], bh[tn], acc[tm][tn]);
                acc[tm][tn] = MFMA16(al[tm], bh[tn], acc[tm][tn]);
                acc[tm][tn] = MFMA16(ah[tm], bl[tn], acc[tm][tn]);
            }
        __syncthreads();
    }

    // epilogue: C/D layout col = lane&15, row = (lane>>4)*4 + reg  [m89/m91]
    if (EPI == 0) {
        const int cb = bn * 128 + wn * 64;         // one head per wave-half
        const int mat = cb >> 9;                   // 0=q 1=k 2=v
        const int hh = (cb >> 6) & 7;
        #pragma unroll
        for (int tm = 0; tm < MT; ++tm) {
            #pragma unroll
            for (int r = 0; r < 4; ++r) {
                const int mg = bm * 128 + wm * (MT * 16) + tm * 16 + fq * 4 + r;
                const int b = mg >> 11, s = mg & 2047;
                const int bhh = b * NHEAD + hh;
                if (mat < 2) {
                    ushort_t* dhi = (mat == 0) ? oqh : okh;
                    ushort_t* dlo = (mat == 0) ? oql : okl;
                    const size_t base = ((size_t)bhh * S_LEN + s) * DH;
                    #pragma unroll
                    for (int tn = 0; tn < 2; ++tn) {
                        const int d1 = tn * 16 + fr;
                        const float v1 = acc[tm][tn][r], v2 = acc[tm][tn + 2][r];
                        const float2 t = rtab[s * 32 + d1];
                        float r1 = v1 * t.x - v2 * t.y;
                        float r2 = v1 * t.y + v2 * t.x;
                        if (mat == 0) { r1 *= 0.125f; r2 *= 0.125f; } // fold 1/sqrt(Dh)
                        ushort_t h1 = f2bf(r1), h2 = f2bf(r2);
                        dhi[base + d1]      = h1;
                        dlo[base + d1]      = f2bf(r1 - bf2f(h1));
                        dhi[base + d1 + 32] = h2;
                        dlo[base + d1 + 32] = f2bf(r2 - bf2f(h2));
                    }
                } else {
                    #pragma unroll
                    for (int tn = 0; tn < 4; ++tn) {
                        const int d = tn * 16 + fr;
                        const size_t off = ((size_t)bhh * DH + d) * S_LEN + s;
                        ovh[off] = f2bf(acc[tm][tn][r]);
                    }
                }
            }
        }
    } else {
        #pragma unroll
        for (int tm = 0; tm < MT; ++tm) {
            #pragma unroll
            for (int tn = 0; tn < 4; ++tn) {
                const int cb = bn * TN + wn * 64 + tn * 16;
                #pragma unroll
                for (int r = 0; r < 4; ++r) {
                    const int mg = bm * 128 + wm * (MT * 16) + tm * 16 + fq * 4 + r;
                    const float val = acc[tm][tn][r];
                    const size_t off = (size_t)mg * N + cb + fr;
                    if (EPI == 1) {
                        C[off] = Cin[off] + val;
                    } else {
                        const float g = gelu_f(val);
                        const ushort_t hi = f2bf(g);
                        Chi[off] = hi;
                        Clo[off] = f2bf(g - bf2f(hi));
                    }
                }
            }
        }
    }
}

// ---------------- MFMA causal flash attention --------------------------------
// 1-D grid 1024: bh = blockIdx&31 (fastest -> XCD = bh&7 pins each head's K/V
// into one XCD's L2, ~3 MB working set < 4 MB), qt = 31 - (blockIdx>>5)
// (heavy blocks first). q pre-scaled by 1/8 in QKV epilogue. Diag tile's mask
// handled in a separate final iteration (main loop mask-free). __expf.
__global__ __launch_bounds__(256) void attn_k(const ushort_t* __restrict__ qhi,
                                              const ushort_t* __restrict__ qlo,
                                              const ushort_t* __restrict__ khi,
                                              const ushort_t* __restrict__ klo,
                                              const ushort_t* __restrict__ vthi,
                                              ushort_t* __restrict__ Ohi,
                                              ushort_t* __restrict__ Olo) {
    __shared__ __align__(16) ushort_t sKh[4096], sKl[4096];
    __shared__ __align__(16) ushort_t sVh[4096], sPh[4096];
    const int tid = threadIdx.x, lane = tid & 63, w = tid >> 6;
    const int fr = lane & 15, fq = lane >> 4;
    const int bidx = blockIdx.x;
    const int bh = bidx & 31;
    const int qt = 31 - (bidx >> 5);

    short8_t qfh[2], qfl[2];
    {
        const size_t base = ((size_t)bh * S_LEN + qt * 64 + w * 16 + fr) * DH + fq * 8;
        qfh[0] = *(const short8_t*)(qhi + base);
        qfh[1] = *(const short8_t*)(qhi + base + 32);
        qfl[0] = *(const short8_t*)(qlo + base);
        qfl[1] = *(const short8_t*)(qlo + base + 32);
    }

    float m_r[4], l_r[4];
    float4_t oacc[4] = {};
    #pragma unroll
    for (int r = 0; r < 4; ++r) { m_r[r] = -INFINITY; l_r[r] = 0.0f; }

    auto step = [&](const int kt, const bool diag) {
        __syncthreads();   // prior iteration's frag reads done
        const size_t ko = ((size_t)bh * S_LEN + kt * 64) * DH;
        stage_tile(khi + ko, 64, sKh, w, lane);
        stage_tile(klo + ko, 64, sKl, w, lane);
        const size_t vo = (size_t)bh * DH * S_LEN + kt * 64;
        stage_tile(vthi + vo, S_LEN, sVh, w, lane);
        __syncthreads();   // vmcnt drained: K/V visible

        float4_t sacc[4] = {};
        #pragma unroll
        for (int kk = 0; kk < 2; ++kk) {
            #pragma unroll
            for (int n = 0; n < 4; ++n) {
                const int bb = kk * 2048 + (n * 16 + fr) * 32 + fq * 8;
                short8_t kh2 = *(const short8_t*)&sKh[bb];
                short8_t kl2 = *(const short8_t*)&sKl[bb];
                sacc[n] = MFMA16(qfh[kk], kh2, sacc[n]);
                sacc[n] = MFMA16(qfl[kk], kh2, sacc[n]);
                sacc[n] = MFMA16(qfh[kk], kl2, sacc[n]);
            }
        }

        #pragma unroll
        for (int r = 0; r < 4; ++r) {
            const int rowl = fq * 4 + r;
            float sv[4], mx = -INFINITY;
            #pragma unroll
            for (int n = 0; n < 4; ++n) {
                float x = sacc[n][r];
                if (diag && (n * 16 + fr) > (w * 16 + rowl)) x = -1e30f;
                sv[n] = x;
                mx = fmaxf(mx, x);
            }
            mx = fmaxf(mx, __shfl_xor(mx, 1));
            mx = fmaxf(mx, __shfl_xor(mx, 2));
            mx = fmaxf(mx, __shfl_xor(mx, 4));
            mx = fmaxf(mx, __shfl_xor(mx, 8));
            const float mn = fmaxf(m_r[r], mx);
            const float alp = __expf(m_r[r] - mn);
            m_r[r] = mn;
            float ls = 0.0f;
            #pragma unroll
            for (int n = 0; n < 4; ++n) {
                const float p = __expf(sv[n] - mn);
                const int idx = (n >> 1) * 2048 + (w * 16 + rowl) * 32 + (n & 1) * 16 + fr;
                sPh[idx] = f2bf(p);
                ls += p;
            }
            ls += __shfl_xor(ls, 1);
            ls += __shfl_xor(ls, 2);
            ls += __shfl_xor(ls, 4);
            ls += __shfl_xor(ls, 8);
            l_r[r] = alp * l_r[r] + ls;
            #pragma unroll
            for (int n = 0; n < 4; ++n) oacc[n][r] *= alp;
        }
        // P rows wave-private: no barrier between P write and PV reads.

        #pragma unroll
        for (int kkj = 0; kkj < 2; ++kkj) {
            short8_t ph = *(const short8_t*)&sPh[kkj * 2048 + (w * 16 + fr) * 32 + fq * 8];
            #pragma unroll
            for (int n = 0; n < 4; ++n) {
                short8_t vh = *(const short8_t*)&sVh[kkj * 2048 + (n * 16 + fr) * 32 + fq * 8];
                oacc[n] = MFMA16(ph, vh, oacc[n]);
            }
        }
    };

    for (int kt = 0; kt < qt; ++kt) step(kt, false);
    step(qt, true);

    const int b = bh >> 3, hh = bh & 7;
    #pragma unroll
    for (int r = 0; r < 4; ++r) {
        const float inv_l = 1.0f / l_r[r];
        const int s = qt * 64 + w * 16 + fq * 4 + r;
        const size_t base = ((size_t)b * S_LEN + s) * DMODEL + hh * DH;
        #pragma unroll
        for (int n = 0; n < 4; ++n) {
            const float y = oacc[n][r] * inv_l;
            const ushort_t h = f2bf(y);
            Ohi[base + n * 16 + fr] = h;
            Olo[base + n * 16 + fr] = f2bf(y - bf2f(h));
        }
    }
}

// ---------------- head: logits -> sigmoid -> probs (+loss accum) ------------
__global__ __launch_bounds__(256) void head_k(const float* __restrict__ x,
                                              const float* __restrict__ w,
                                              const float* __restrict__ b,
                                              float* __restrict__ probs,
                                              float* __restrict__ loss_out) {
    const int tid = threadIdx.x;
    const int lane = tid & 63;
    const size_t row = (size_t)blockIdx.x * 4 + (tid >> 6);
    const float* xr = x + row * DMODEL;
    float acc = 0.0f;
    #pragma unroll
    for (int i = 0; i < 8; ++i) acc += xr[lane + i * 64] * w[lane + i * 64];
    #pragma unroll
    for (int off = 32; off; off >>= 1) acc += __shfl_down(acc, off);
    if (lane == 0) {
        float p = 1.0f / (1.0f + expf(-(acc + b[0])));
        probs[row] = p;
        atomicAdd(loss_out, p * 0.25f);
    }
}

// ---------------- chunk id scan, parallel (binary lifting) -------------------
__global__ __launch_bounds__(256) void chunk_k(const float* __restrict__ probs,
                                               int* __restrict__ ids,
                                               float* __restrict__ avg_out) {
    __shared__ ushort_t nxA[2052], nxB[2052];
    __shared__ ushort_t lift[10][2052];
    __shared__ int anyf;
    const int b = blockIdx.x, tid = threadIdx.x;
    const float* pr = probs + (size_t)b * S_LEN;
    if (tid == 0) anyf = 0;
    __syncthreads();
    int loc = 0;
    for (int t = tid; t < S_LEN; t += 256) loc |= (pr[t] > 0.5f) ? 1 : 0;
    if (loc) atomicOr(&anyf, 1);
    __syncthreads();
    const int any = anyf;
    for (int i = tid; i <= S_LEN; i += 256) {
        const bool he = any ? (i >= 1 && pr[i - 1] > 0.5f) : (i == S_LEN - 1);
        nxA[i] = he ? (ushort_t)i : (ushort_t)(S_LEN + 1);
    }
    __syncthreads();
    ushort_t* src = nxA;
    ushort_t* dst = nxB;
    for (int d = 1; d <= 2048; d <<= 1) {
        for (int i = tid; i <= S_LEN; i += 256) {
            ushort_t v = src[i];
            if (i + d <= S_LEN) { ushort_t u2 = src[i + d]; v = u2 < v ? u2 : v; }
            dst[i] = v;
        }
        __syncthreads();
        ushort_t* tmp = src; src = dst; dst = tmp;
    }
    for (int t = tid; t < S_LEN; t += 256) {
        int cap = t + 16; if (cap > S_LEN) cap = S_LEN;
        int e = src[t + 1];
        if (e > cap) e = cap;
        if (e - t < 3) { e = t + 3; if (e > S_LEN) e = S_LEN; }
        lift[0][t] = (ushort_t)e;
    }
    if (tid == 0) lift[0][S_LEN] = (ushort_t)S_LEN;
    __syncthreads();
    for (int j = 1; j < 10; ++j) {
        for (int t = tid; t <= S_LEN; t += 256)
            lift[j][t] = lift[j - 1][lift[j - 1][t]];
        __syncthreads();
    }
    for (int t = tid; t < S_LEN; t += 256) {
        int pos = 0, cid = 0;
        #pragma unroll
        for (int j = 9; j >= 0; --j) {
            const int p2 = lift[j][pos];
            if (p2 <= t) { pos = p2; cid += (1 << j); }
        }
        ids[(size_t)b * S_LEN + t] = cid;
        if (t == S_LEN - 1) atomicAdd(avg_out, 512.0f / (float)(cid + 1));
    }
}

// ---------------- masks ------------------------------------------------------
__global__ __launch_bounds__(256) void masks_k(const int* __restrict__ ids,
                                               float* __restrict__ mask) {
    const int bq = blockIdx.x;
    const int b = bq >> 11;
    const int myid = ids[bq];
    const int* idr = ids + (size_t)b * S_LEN;
    float* mr = mask + (size_t)bq * S_LEN;
    for (int k = threadIdx.x; k < S_LEN; k += 256)
        mr[k] = (idr[k] == myid) ? 1.0f : 0.0f;
}

extern "C" void kernel_launch(void* const* d_in, const int* in_sizes, int n_in,
                              void* d_out, int out_size, void* d_ws, size_t ws_size,
                              hipStream_t stream) {
    (void)in_sizes; (void)n_in; (void)out_size; (void)ws_size;
    const float* x      = (const float*)d_in[0];
    const int*   x_ids  = (const int*)d_in[1];
    const float* ln1    = (const float*)d_in[2];
    const float* Wq     = (const float*)d_in[3];
    const float* Wk     = (const float*)d_in[4];
    const float* Wv     = (const float*)d_in[5];
    const float* Wo     = (const float*)d_in[6];
    const float* ln2    = (const float*)d_in[7];
    const float* W1     = (const float*)d_in[8];
    const float* W2     = (const float*)d_in[9];
    const float* head_w = (const float*)d_in[10];
    const float* head_b = (const float*)d_in[11];

    float* out = (float*)d_out;
    ushort_t* u = (ushort_t*)d_ws;
    ushort_t* qh   = u;                 // [32 bh][2048 s][64 d] roped q (x 1/8) hi
    ushort_t* ql   = u + 4194304;
    ushort_t* kh   = u + 8388608;       // roped k
    ushort_t* kl   = u + 12582912;
    ushort_t* vth  = u + 16777216;      // v transposed hi [32 bh][64 d][2048 s]
    ushort_t* ohi  = u + 25165824;      // attn out [8192][512]
    ushort_t* olo  = u + 29360128;
    ushort_t* hhi  = u + 33554432;      // rmsnorm out [8192][512]
    ushort_t* hlo  = u + 37748736;
    ushort_t* ffhi = u;                 // [8192][2048]; overlays q..k (dead after attn)
    ushort_t* fflo = u + 16777216;      // overlays vt..o (dead after Wo gemm)
    float*    probs = (float*)(u + 41943040);
    int*      ids   = (int*)(u + 41943040 + 16384);
    // weight-split (both layers) + rope table in out's mask region:
    ushort_t* wbuf     = (ushort_t*)(out + 4202512);   // 16B-aligned
    // per-layer offsets inside wbuf (layer stride 6291456 ushorts):
    //   qkvT_hi 0 / qkvT_lo 786432 / woT_hi 1572864 / woT_lo 1835008 /
    //   w1T_hi 2097152 / w1T_lo 3145728 / w2T_hi 4194304 / w2T_lo 5242880
    float2*   rope_tab = (float2*)(wbuf + 12582912);   // [2048][32] (cos,sin)
    float* xbuf = out;

    copy_init_k<<<4096, 256, 0, stream>>>(x, x_ids, out);
    rope_tab_k<<<256, 256, 0, stream>>>(rope_tab);
    tsplit_all_k<<<6144, 256, 0, stream>>>(Wq, Wk, Wv, Wo, W1, W2, wbuf);

    for (int l = 0; l < 2; ++l) {
        ushort_t* lb = wbuf + (size_t)l * 6291456;
        ushort_t* qkvT_hi = lb;
        ushort_t* qkvT_lo = lb + 786432;
        ushort_t* woT_hi  = lb + 1572864;
        ushort_t* woT_lo  = lb + 1835008;
        ushort_t* w1T_hi  = lb + 2097152;
        ushort_t* w1T_lo  = lb + 3145728;
        ushort_t* w2T_hi  = lb + 4194304;
        ushort_t* w2T_lo  = lb + 5242880;

        rmsnorm_split_k<<<8192, 256, 0, stream>>>(xbuf, ln1 + l * DMODEL, hhi, hlo);
        gemm_s<0, 128><<<dim3(12, 64), 256, 0, stream>>>(hhi, hlo, qkvT_hi, qkvT_lo, 512, 1536,
                                                         nullptr, nullptr, nullptr, nullptr,
                                                         qh, ql, kh, kl, vth, rope_tab);
        attn_k<<<1024, 256, 0, stream>>>(qh, ql, kh, kl, vth, ohi, olo);
        gemm_s<1, 64><<<dim3(8, 64), 256, 0, stream>>>(ohi, olo, woT_hi, woT_lo, 512, 512,
                                                       xbuf, xbuf, nullptr, nullptr,
                                                       nullptr, nullptr, nullptr, nullptr, nullptr, nullptr);
        rmsnorm_split_k<<<8192, 256, 0, stream>>>(xbuf, ln2 + l * DMODEL, hhi, hlo);
        gemm_s<2, 128><<<dim3(16, 64), 256, 0, stream>>>(hhi, hlo, w1T_hi, w1T_lo, 512, 2048,
                                                         nullptr, nullptr, ffhi, fflo,
                                                         nullptr, nullptr, nullptr, nullptr, nullptr, nullptr);
        gemm_s<1, 64><<<dim3(8, 64), 256, 0, stream>>>(ffhi, fflo, w2T_hi, w2T_lo, 2048, 512,
                                                       xbuf, xbuf, nullptr, nullptr,
                                                       nullptr, nullptr, nullptr, nullptr, nullptr, nullptr);
    }

    head_k<<<2048, 256, 0, stream>>>(xbuf, head_w, head_b, probs, out + 20979713);
    chunk_k<<<4, 256, 0, stream>>>(probs, ids, out + 4202496);
    masks_k<<<8192, 256, 0, stream>>>(ids, out + 4202497);
}

// Round 7
// 883.277 us; speedup vs baseline: 3.4438x; 1.1200x over previous
//
#include <hip/hip_runtime.h>
#include <math.h>

#define S_LEN 2048
#define DMODEL 512
#define NHEAD 8
#define DH 64
#define FDIM 2048

typedef unsigned short ushort_t;
typedef __attribute__((ext_vector_type(8))) short short8_t;   // 8 bf16 = 4 VGPRs
typedef __attribute__((ext_vector_type(4))) float float4_t;   // MFMA acc

#define MFMA16(a, b, c) __builtin_amdgcn_mfma_f32_16x16x32_bf16(a, b, c, 0, 0, 0)

// ---- output layout (floats) ----
// x_t: [0, 4194304)  x_ids: [4194304, 4202496)  avg: 4202496
// masks: [4202497, 20979713)  loss: 20979713
// masks region doubles as weight-split + rope-table scratch (dead until masks_k).

__device__ __forceinline__ ushort_t f2bf(float x) {            // RNE fp32->bf16
    unsigned u = __float_as_uint(x);
    return (ushort_t)((u + 0x7fffu + ((u >> 16) & 1u)) >> 16);
}
__device__ __forceinline__ float bf2f(ushort_t h) {
    return __uint_as_float((unsigned)h << 16);
}
__device__ __forceinline__ float gelu_f(float x) {
    return 0.5f * x * (1.0f + erff(x * 0.70710678118654752440f));
}
__device__ __forceinline__ void gl_lds16(const void* g, void* l) {
    __builtin_amdgcn_global_load_lds(
        (const __attribute__((address_space(1))) void*)g,
        (__attribute__((address_space(3))) void*)l, 16, 0, 0);
}

// stage a 64x64 bf16 tile (row stride rs ushorts) into LDS [kk][64][32] (4096 ushorts).
__device__ __forceinline__ void stage_tile(const ushort_t* __restrict__ g, int rs,
                                           ushort_t* __restrict__ s, int w, int lane) {
    #pragma unroll
    for (int j = 0; j < 2; ++j) {
        const int c = (w * 2 + j) * 64 + lane;
        const int kk = c >> 8, row = (c >> 2) & 63, q = c & 3;
        gl_lds16(g + (size_t)row * rs + kk * 32 + q * 8, s + c * 8);
    }
}

// ---------------- copy x -> out, ids -> out, zero scalar slots --------------
__global__ void copy_init_k(const float* __restrict__ x, const int* __restrict__ x_ids,
                            float* __restrict__ out) {
    size_t i = (size_t)blockIdx.x * blockDim.x + threadIdx.x;
    float4* o4 = (float4*)out;
    o4[i] = ((const float4*)x)[i];
    if (i < 2048) {
        int4 id4 = ((const int4*)x_ids)[i];
        o4[1048576 + i] = make_float4((float)id4.x, (float)id4.y, (float)id4.z, (float)id4.w);
    }
    if (i == 0) { out[4202496] = 0.0f; out[20979713] = 0.0f; }
}

// ---------------- RoPE cos/sin table: tab[s*32+f] = (cos, sin) --------------
__global__ __launch_bounds__(256) void rope_tab_k(float2* __restrict__ tab) {
    const int i = blockIdx.x * 256 + threadIdx.x;   // 65536
    const int s = i >> 5, f = i & 31;
    float inv = powf(10000.0f, -(float)f * (1.0f / 32.0f));
    float sn, cs;
    sincosf((float)s * inv, &sn, &cs);
    tab[i] = make_float2(cs, sn);
}

// ---------------- ALL weights transpose + split, one dispatch ----------------
// Per layer (3072 blocks): [0,768) Wq/Wk/Wv, [768,1024) Wo, [1024,2048) W1,
// [2048,3072) W2. Layer stride in wbuf = 6291456 ushorts.
__global__ __launch_bounds__(256) void tsplit_all_k(const float* __restrict__ Wq,
                                                    const float* __restrict__ Wk,
                                                    const float* __restrict__ Wv,
                                                    const float* __restrict__ Wo,
                                                    const float* __restrict__ W1,
                                                    const float* __restrict__ W2,
                                                    ushort_t* __restrict__ wbuf) {
    __shared__ float T[32][33];
    const int bid = blockIdx.x;
    const int l = bid / 3072;
    const int r = bid % 3072;
    ushort_t* lb = wbuf + (size_t)l * 6291456;
    const float* W; ushort_t* Thi; ushort_t* Tlo; int K, N, ntn, rr;
    if (r < 768) {
        const int which = r >> 8; rr = r & 255;
        W = (which == 0 ? Wq : which == 1 ? Wk : Wv) + (size_t)l * 262144;
        Thi = lb + which * 262144; Tlo = lb + 786432 + which * 262144;
        K = 512; N = 512; ntn = 16;
    } else if (r < 1024) {
        rr = r - 768; W = Wo + (size_t)l * 262144;
        Thi = lb + 1572864; Tlo = lb + 1835008; K = 512; N = 512; ntn = 16;
    } else if (r < 2048) {
        rr = r - 1024; W = W1 + (size_t)l * 1048576;
        Thi = lb + 2097152; Tlo = lb + 3145728; K = 512; N = 2048; ntn = 64;
    } else {
        rr = r - 2048; W = W2 + (size_t)l * 1048576;
        Thi = lb + 4194304; Tlo = lb + 5242880; K = 2048; N = 512; ntn = 16;
    }
    const int n0 = (rr % ntn) * 32, k0 = (rr / ntn) * 32;
    const int tx = threadIdx.x & 31, ty = threadIdx.x >> 5;
    #pragma unroll
    for (int i = 0; i < 4; ++i)
        T[ty + 8 * i][tx] = W[(size_t)(k0 + ty + 8 * i) * N + n0 + tx];
    __syncthreads();
    #pragma unroll
    for (int i = 0; i < 4; ++i) {
        const int n = ty + 8 * i;
        float x = T[tx][n];
        ushort_t hi = f2bf(x);
        Thi[(size_t)(n0 + n) * K + k0 + tx] = hi;
        Tlo[(size_t)(n0 + n) * K + k0 + tx] = f2bf(x - bf2f(hi));
    }
}

// ---------------- RMSNorm -> hi/lo bf16 split --------------------------------
__global__ __launch_bounds__(256) void rmsnorm_split_k(const float* __restrict__ x,
                                                       const float* __restrict__ w,
                                                       ushort_t* __restrict__ hhi,
                                                       ushort_t* __restrict__ hlo) {
    __shared__ float red[4];
    const int tid = threadIdx.x;
    const size_t row = blockIdx.x;
    const float* xr = x + row * DMODEL;
    float2 v = *(const float2*)(xr + tid * 2);
    float ss = v.x * v.x + v.y * v.y;
    #pragma unroll
    for (int off = 32; off; off >>= 1) ss += __shfl_down(ss, off);
    if ((tid & 63) == 0) red[tid >> 6] = ss;
    __syncthreads();
    float tot = red[0] + red[1] + red[2] + red[3];
    float rs = 1.0f / sqrtf(tot * (1.0f / 512.0f) + 1e-6f);
    float2 wv = *(const float2*)(w + tid * 2);
    float y0 = v.x * rs * wv.x, y1 = v.y * rs * wv.y;
    ushort_t h0 = f2bf(y0), h1 = f2bf(y1);
    ushort_t l0 = f2bf(y0 - bf2f(h0)), l1 = f2bf(y1 - bf2f(h1));
    *(unsigned*)(hhi + row * DMODEL + tid * 2) = ((unsigned)h1 << 16) | h0;
    *(unsigned*)(hlo + row * DMODEL + tid * 2) = ((unsigned)l1 << 16) | l0;
}

// ---------------- bf16x3 split MFMA GEMM ------------------------------------
// A [M][K], B [N][K] hi/lo bf16. 128 x TN tile, BK=32, 4 waves.
// TN=128: waves 2x2, wave=64x64 (4x4 tiles). TN=64: waves 4x1, wave=32x64
// (2x4 tiles) -> 2x more blocks for small-N GEMMs (occupancy).
// EPI 0 (TN=128): fused QKV: RoPE q/k (q pre-scaled by 1/8) -> split bf16;
//                 v -> hi bf16 transposed [bh][d][S].
// EPI 1: C = Cin + acc.  EPI 2: gelu -> split bf16.
template<int EPI, int TN>
__global__ __launch_bounds__(256) void gemm_s(const ushort_t* __restrict__ Ahi,
                                              const ushort_t* __restrict__ Alo,
                                              const ushort_t* __restrict__ Bhi,
                                              const ushort_t* __restrict__ Blo,
                                              int K, int N,
                                              float* __restrict__ C,
                                              const float* __restrict__ Cin,
                                              ushort_t* __restrict__ Chi,
                                              ushort_t* __restrict__ Clo,
                                              ushort_t* __restrict__ oqh,
                                              ushort_t* __restrict__ oql,
                                              ushort_t* __restrict__ okh,
                                              ushort_t* __restrict__ okl,
                                              ushort_t* __restrict__ ovh,
                                              const float2* __restrict__ rtab) {
    constexpr int MT = (TN == 128) ? 4 : 2;        // m-tiles per wave
    __shared__ ushort_t sAhi[4096], sAlo[4096];
    __shared__ ushort_t sBhi[TN * 32], sBlo[TN * 32];
    const int tid = threadIdx.x;
    const int lane = tid & 63, w = tid >> 6;
    const int wm = (TN == 128) ? (w >> 1) : w;
    const int wn = (TN == 128) ? (w & 1) : 0;
    const int bm = blockIdx.y, bn = blockIdx.x;
    const int sm = lane >> 2;
    const int sk = (lane & 3) * 8;
    const int fr = lane & 15;
    const int fq = lane >> 4;
    const int fk = fq * 8;

    float4_t acc[MT][4] = {};

    for (int kt = 0; kt < K; kt += 32) {
        #pragma unroll
        for (int j = 0; j < 2; ++j) {              // A: 8 chunks x 16 rows
            const int chunk = w * 2 + j;
            const int mr = chunk * 16 + sm;
            const size_t ga = (size_t)(bm * 128 + mr) * K + kt + sk;
            gl_lds16(Ahi + ga, &sAhi[chunk * 512]);
            gl_lds16(Alo + ga, &sAlo[chunk * 512]);
        }
        #pragma unroll
        for (int j = 0; j < TN / 64; ++j) {        // B: TN/16 chunks
            const int chunk = w * (TN / 64) + j;
            const int mr = chunk * 16 + sm;
            const size_t gb = (size_t)(bn * TN + mr) * K + kt + sk;
            gl_lds16(Bhi + gb, &sBhi[chunk * 512]);
            gl_lds16(Blo + gb, &sBlo[chunk * 512]);
        }
        __syncthreads();
        short8_t ah[MT], al[MT], bh[4], bl[4];
        #pragma unroll
        for (int t = 0; t < MT; ++t) {
            const int ao = (wm * (MT * 16) + t * 16 + fr) * 32 + fk;
            ah[t] = *(const short8_t*)&sAhi[ao];
            al[t] = *(const short8_t*)&sAlo[ao];
        }
        #pragma unroll
        for (int t = 0; t < 4; ++t) {
            const int bo = (wn * 64 + t * 16 + fr) * 32 + fk;
            bh[t] = *(const short8_t*)&sBhi[bo];
            bl[t] = *(const short8_t*)&sBlo[bo];
        }
        #pragma unroll
        for (int tm = 0; tm < MT; ++tm)
            #pragma unroll
            for (int tn = 0; tn < 4; ++tn) {
                acc[tm][tn] = MFMA16(ah[tm], bh[tn], acc[tm][tn]);
                acc[tm][tn] = MFMA16(al[tm], bh[tn], acc[tm][tn]);
                acc[tm][tn] = MFMA16(ah[tm], bl[tn], acc[tm][tn]);
            }
        __syncthreads();
    }

    // epilogue: C/D layout col = lane&15, row = (lane>>4)*4 + reg  [m89/m91]
    if (EPI == 0) {
        const int cb = bn * 128 + wn * 64;         // one head per wave-half
        const int mat = cb >> 9;                   // 0=q 1=k 2=v
        const int hh = (cb >> 6) & 7;
        #pragma unroll
        for (int tm = 0; tm < MT; ++tm) {
            #pragma unroll
            for (int r = 0; r < 4; ++r) {
                const int mg = bm * 128 + wm * (MT * 16) + tm * 16 + fq * 4 + r;
                const int b = mg >> 11, s = mg & 2047;
                const int bhh = b * NHEAD + hh;
                if (mat < 2) {
                    ushort_t* dhi = (mat == 0) ? oqh : okh;
                    ushort_t* dlo = (mat == 0) ? oql : okl;
                    const size_t base = ((size_t)bhh * S_LEN + s) * DH;
                    #pragma unroll
                    for (int tn = 0; tn < 2; ++tn) {
                        const int d1 = tn * 16 + fr;
                        const float v1 = acc[tm][tn][r], v2 = acc[tm][tn + 2][r];
                        const float2 t = rtab[s * 32 + d1];
                        float r1 = v1 * t.x - v2 * t.y;
                        float r2 = v1 * t.y + v2 * t.x;
                        if (mat == 0) { r1 *= 0.125f; r2 *= 0.125f; } // fold 1/sqrt(Dh)
                        ushort_t h1 = f2bf(r1), h2 = f2bf(r2);
                        dhi[base + d1]      = h1;
                        dlo[base + d1]      = f2bf(r1 - bf2f(h1));
                        dhi[base + d1 + 32] = h2;
                        dlo[base + d1 + 32] = f2bf(r2 - bf2f(h2));
                    }
                } else {
                    #pragma unroll
                    for (int tn = 0; tn < 4; ++tn) {
                        const int d = tn * 16 + fr;
                        const size_t off = ((size_t)bhh * DH + d) * S_LEN + s;
                        ovh[off] = f2bf(acc[tm][tn][r]);
                    }
                }
            }
        }
    } else {
        #pragma unroll
        for (int tm = 0; tm < MT; ++tm) {
            #pragma unroll
            for (int tn = 0; tn < 4; ++tn) {
                const int cb = bn * TN + wn * 64 + tn * 16;
                #pragma unroll
                for (int r = 0; r < 4; ++r) {
                    const int mg = bm * 128 + wm * (MT * 16) + tm * 16 + fq * 4 + r;
                    const float val = acc[tm][tn][r];
                    const size_t off = (size_t)mg * N + cb + fr;
                    if (EPI == 1) {
                        C[off] = Cin[off] + val;
                    } else {
                        const float g = gelu_f(val);
                        const ushort_t hi = f2bf(g);
                        Chi[off] = hi;
                        Clo[off] = f2bf(g - bf2f(hi));
                    }
                }
            }
        }
    }
}

// ---------------- MFMA causal flash attention --------------------------------
// 1-D grid 1024: bh = blockIdx&31 (fastest -> XCD = bh&7 pins each head's K/V
// into one XCD's L2), qt = 31 - (blockIdx>>5) (heavy blocks first).
__global__ __launch_bounds__(256) void attn_k(const ushort_t* __restrict__ qhi,
                                              const ushort_t* __restrict__ qlo,
                                              const ushort_t* __restrict__ khi,
                                              const ushort_t* __restrict__ klo,
                                              const ushort_t* __restrict__ vthi,
                                              ushort_t* __restrict__ Ohi,
                                              ushort_t* __restrict__ Olo) {
    __shared__ __align__(16) ushort_t sKh[4096], sKl[4096];
    __shared__ __align__(16) ushort_t sVh[4096], sPh[4096];
    const int tid = threadIdx.x, lane = tid & 63, w = tid >> 6;
    const int fr = lane & 15, fq = lane >> 4;
    const int bidx = blockIdx.x;
    const int bh = bidx & 31;
    const int qt = 31 - (bidx >> 5);

    short8_t qfh[2], qfl[2];
    {
        const size_t base = ((size_t)bh * S_LEN + qt * 64 + w * 16 + fr) * DH + fq * 8;
        qfh[0] = *(const short8_t*)(qhi + base);
        qfh[1] = *(const short8_t*)(qhi + base + 32);
        qfl[0] = *(const short8_t*)(qlo + base);
        qfl[1] = *(const short8_t*)(qlo + base + 32);
    }

    float m_r[4], l_r[4];
    float4_t oacc[4] = {};
    #pragma unroll
    for (int r = 0; r < 4; ++r) { m_r[r] = -INFINITY; l_r[r] = 0.0f; }

    auto step = [&](const int kt, const bool diag) {
        __syncthreads();   // prior iteration's frag reads done
        const size_t ko = ((size_t)bh * S_LEN + kt * 64) * DH;
        stage_tile(khi + ko, 64, sKh, w, lane);
        stage_tile(klo + ko, 64, sKl, w, lane);
        const size_t vo = (size_t)bh * DH * S_LEN + kt * 64;
        stage_tile(vthi + vo, S_LEN, sVh, w, lane);
        __syncthreads();   // vmcnt drained: K/V visible

        float4_t sacc[4] = {};
        #pragma unroll
        for (int kk = 0; kk < 2; ++kk) {
            #pragma unroll
            for (int n = 0; n < 4; ++n) {
                const int bb = kk * 2048 + (n * 16 + fr) * 32 + fq * 8;
                short8_t kh2 = *(const short8_t*)&sKh[bb];
                short8_t kl2 = *(const short8_t*)&sKl[bb];
                sacc[n] = MFMA16(qfh[kk], kh2, sacc[n]);
                sacc[n] = MFMA16(qfl[kk], kh2, sacc[n]);
                sacc[n] = MFMA16(qfh[kk], kl2, sacc[n]);
            }
        }

        #pragma unroll
        for (int r = 0; r < 4; ++r) {
            const int rowl = fq * 4 + r;
            float sv[4], mx = -INFINITY;
            #pragma unroll
            for (int n = 0; n < 4; ++n) {
                float x = sacc[n][r];
                if (diag && (n * 16 + fr) > (w * 16 + rowl)) x = -1e30f;
                sv[n] = x;
                mx = fmaxf(mx, x);
            }
            mx = fmaxf(mx, __shfl_xor(mx, 1));
            mx = fmaxf(mx, __shfl_xor(mx, 2));
            mx = fmaxf(mx, __shfl_xor(mx, 4));
            mx = fmaxf(mx, __shfl_xor(mx, 8));
            const float mn = fmaxf(m_r[r], mx);
            const float alp = __expf(m_r[r] - mn);
            m_r[r] = mn;
            float ls = 0.0f;
            #pragma unroll
            for (int n = 0; n < 4; ++n) {
                const float p = __expf(sv[n] - mn);
                const int idx = (n >> 1) * 2048 + (w * 16 + rowl) * 32 + (n & 1) * 16 + fr;
                sPh[idx] = f2bf(p);
                ls += p;
            }
            ls += __shfl_xor(ls, 1);
            ls += __shfl_xor(ls, 2);
            ls += __shfl_xor(ls, 4);
            ls += __shfl_xor(ls, 8);
            l_r[r] = alp * l_r[r] + ls;
            #pragma unroll
            for (int n = 0; n < 4; ++n) oacc[n][r] *= alp;
        }
        // P rows wave-private: no barrier between P write and PV reads.

        #pragma unroll
        for (int kkj = 0; kkj < 2; ++kkj) {
            short8_t ph = *(const short8_t*)&sPh[kkj * 2048 + (w * 16 + fr) * 32 + fq * 8];
            #pragma unroll
            for (int n = 0; n < 4; ++n) {
                short8_t vh = *(const short8_t*)&sVh[kkj * 2048 + (n * 16 + fr) * 32 + fq * 8];
                oacc[n] = MFMA16(ph, vh, oacc[n]);
            }
        }
    };

    for (int kt = 0; kt < qt; ++kt) step(kt, false);
    step(qt, true);

    const int b = bh >> 3, hh = bh & 7;
    #pragma unroll
    for (int r = 0; r < 4; ++r) {
        const float inv_l = 1.0f / l_r[r];
        const int s = qt * 64 + w * 16 + fq * 4 + r;
        const size_t base = ((size_t)b * S_LEN + s) * DMODEL + hh * DH;
        #pragma unroll
        for (int n = 0; n < 4; ++n) {
            const float y = oacc[n][r] * inv_l;
            const ushort_t h = f2bf(y);
            Ohi[base + n * 16 + fr] = h;
            Olo[base + n * 16 + fr] = f2bf(y - bf2f(h));
        }
    }
}

// ---------------- head: logits -> sigmoid -> probs (no atomics) -------------
__global__ __launch_bounds__(256) void head_k(const float* __restrict__ x,
                                              const float* __restrict__ w,
                                              const float* __restrict__ b,
                                              float* __restrict__ probs) {
    const int tid = threadIdx.x;
    const int lane = tid & 63;
    const size_t row = (size_t)blockIdx.x * 4 + (tid >> 6);
    const float* xr = x + row * DMODEL;
    float acc = 0.0f;
    #pragma unroll
    for (int i = 0; i < 8; ++i) acc += xr[lane + i * 64] * w[lane + i * 64];
    #pragma unroll
    for (int off = 32; off; off >>= 1) acc += __shfl_down(acc, off);
    if (lane == 0)
        probs[row] = 1.0f / (1.0f + expf(-(acc + b[0])));
}

// ---------------- chunk id scan (binary lifting) + loss reduction ------------
// Loss: mean over B of sum over S of probs -> each block (one batch) reduces
// its row and does ONE atomicAdd (4 total, vs 8192 single-address atomics).
__global__ __launch_bounds__(256) void chunk_k(const float* __restrict__ probs,
                                               int* __restrict__ ids,
                                               float* __restrict__ avg_out,
                                               float* __restrict__ loss_out) {
    __shared__ ushort_t nxA[2052], nxB[2052];
    __shared__ ushort_t lift[10][2052];
    __shared__ float lred[4];
    __shared__ int anyf;
    const int b = blockIdx.x, tid = threadIdx.x;
    const float* pr = probs + (size_t)b * S_LEN;
    if (tid == 0) anyf = 0;
    __syncthreads();
    int loc = 0;
    float lsum = 0.0f;
    for (int t = tid; t < S_LEN; t += 256) {
        const float p = pr[t];
        loc |= (p > 0.5f) ? 1 : 0;
        lsum += p;
    }
    if (loc) atomicOr(&anyf, 1);
    #pragma unroll
    for (int off = 32; off; off >>= 1) lsum += __shfl_down(lsum, off);
    if ((tid & 63) == 0) lred[tid >> 6] = lsum;
    __syncthreads();
    if (tid == 0)
        atomicAdd(loss_out, (lred[0] + lred[1] + lred[2] + lred[3]) * 0.25f);
    const int any = anyf;
    for (int i = tid; i <= S_LEN; i += 256) {
        const bool he = any ? (i >= 1 && pr[i - 1] > 0.5f) : (i == S_LEN - 1);
        nxA[i] = he ? (ushort_t)i : (ushort_t)(S_LEN + 1);
    }
    __syncthreads();
    ushort_t* src = nxA;
    ushort_t* dst = nxB;
    for (int d = 1; d <= 2048; d <<= 1) {
        for (int i = tid; i <= S_LEN; i += 256) {
            ushort_t v = src[i];
            if (i + d <= S_LEN) { ushort_t u2 = src[i + d]; v = u2 < v ? u2 : v; }
            dst[i] = v;
        }
        __syncthreads();
        ushort_t* tmp = src; src = dst; dst = tmp;
    }
    for (int t = tid; t < S_LEN; t += 256) {
        int cap = t + 16; if (cap > S_LEN) cap = S_LEN;
        int e = src[t + 1];
        if (e > cap) e = cap;
        if (e - t < 3) { e = t + 3; if (e > S_LEN) e = S_LEN; }
        lift[0][t] = (ushort_t)e;
    }
    if (tid == 0) lift[0][S_LEN] = (ushort_t)S_LEN;
    __syncthreads();
    for (int j = 1; j < 10; ++j) {
        for (int t = tid; t <= S_LEN; t += 256)
            lift[j][t] = lift[j - 1][lift[j - 1][t]];
        __syncthreads();
    }
    for (int t = tid; t < S_LEN; t += 256) {
        int pos = 0, cid = 0;
        #pragma unroll
        for (int j = 9; j >= 0; --j) {
            const int p2 = lift[j][pos];
            if (p2 <= t) { pos = p2; cid += (1 << j); }
        }
        ids[(size_t)b * S_LEN + t] = cid;
        if (t == S_LEN - 1) atomicAdd(avg_out, 512.0f / (float)(cid + 1));
    }
}

// ---------------- masks ------------------------------------------------------
__global__ __launch_bounds__(256) void masks_k(const int* __restrict__ ids,
                                               float* __restrict__ mask) {
    const int bq = blockIdx.x;
    const int b = bq >> 11;
    const int myid = ids[bq];
    const int* idr = ids + (size_t)b * S_LEN;
    float* mr = mask + (size_t)bq * S_LEN;
    for (int k = threadIdx.x; k < S_LEN; k += 256)
        mr[k] = (idr[k] == myid) ? 1.0f : 0.0f;
}

extern "C" void kernel_launch(void* const* d_in, const int* in_sizes, int n_in,
                              void* d_out, int out_size, void* d_ws, size_t ws_size,
                              hipStream_t stream) {
    (void)in_sizes; (void)n_in; (void)out_size; (void)ws_size;
    const float* x      = (const float*)d_in[0];
    const int*   x_ids  = (const int*)d_in[1];
    const float* ln1    = (const float*)d_in[2];
    const float* Wq     = (const float*)d_in[3];
    const float* Wk     = (const float*)d_in[4];
    const float* Wv     = (const float*)d_in[5];
    const float* Wo     = (const float*)d_in[6];
    const float* ln2    = (const float*)d_in[7];
    const float* W1     = (const float*)d_in[8];
    const float* W2     = (const float*)d_in[9];
    const float* head_w = (const float*)d_in[10];
    const float* head_b = (const float*)d_in[11];

    float* out = (float*)d_out;
    ushort_t* u = (ushort_t*)d_ws;
    ushort_t* qh   = u;                 // [32 bh][2048 s][64 d] roped q (x 1/8) hi
    ushort_t* ql   = u + 4194304;
    ushort_t* kh   = u + 8388608;       // roped k
    ushort_t* kl   = u + 12582912;
    ushort_t* vth  = u + 16777216;      // v transposed hi [32 bh][64 d][2048 s]
    ushort_t* ohi  = u + 25165824;      // attn out [8192][512]
    ushort_t* olo  = u + 29360128;
    ushort_t* hhi  = u + 33554432;      // rmsnorm out [8192][512]
    ushort_t* hlo  = u + 37748736;
    ushort_t* ffhi = u;                 // [8192][2048]; overlays q..k (dead after attn)
    ushort_t* fflo = u + 16777216;      // overlays vt..o (dead after Wo gemm)
    float*    probs = (float*)(u + 41943040);
    int*      ids   = (int*)(u + 41943040 + 16384);
    // weight-split (both layers) + rope table in out's mask region:
    ushort_t* wbuf     = (ushort_t*)(out + 4202512);   // 16B-aligned
    float2*   rope_tab = (float2*)(wbuf + 12582912);   // [2048][32] (cos,sin)
    float* xbuf = out;

    copy_init_k<<<4096, 256, 0, stream>>>(x, x_ids, out);
    rope_tab_k<<<256, 256, 0, stream>>>(rope_tab);
    tsplit_all_k<<<6144, 256, 0, stream>>>(Wq, Wk, Wv, Wo, W1, W2, wbuf);

    for (int l = 0; l < 2; ++l) {
        ushort_t* lb = wbuf + (size_t)l * 6291456;
        ushort_t* qkvT_hi = lb;
        ushort_t* qkvT_lo = lb + 786432;
        ushort_t* woT_hi  = lb + 1572864;
        ushort_t* woT_lo  = lb + 1835008;
        ushort_t* w1T_hi  = lb + 2097152;
        ushort_t* w1T_lo  = lb + 3145728;
        ushort_t* w2T_hi  = lb + 4194304;
        ushort_t* w2T_lo  = lb + 5242880;

        rmsnorm_split_k<<<8192, 256, 0, stream>>>(xbuf, ln1 + l * DMODEL, hhi, hlo);
        gemm_s<0, 128><<<dim3(12, 64), 256, 0, stream>>>(hhi, hlo, qkvT_hi, qkvT_lo, 512, 1536,
                                                         nullptr, nullptr, nullptr, nullptr,
                                                         qh, ql, kh, kl, vth, rope_tab);
        attn_k<<<1024, 256, 0, stream>>>(qh, ql, kh, kl, vth, ohi, olo);
        gemm_s<1, 64><<<dim3(8, 64), 256, 0, stream>>>(ohi, olo, woT_hi, woT_lo, 512, 512,
                                                       xbuf, xbuf, nullptr, nullptr,
                                                       nullptr, nullptr, nullptr, nullptr, nullptr, nullptr);
        rmsnorm_split_k<<<8192, 256, 0, stream>>>(xbuf, ln2 + l * DMODEL, hhi, hlo);
        gemm_s<2, 128><<<dim3(16, 64), 256, 0, stream>>>(hhi, hlo, w1T_hi, w1T_lo, 512, 2048,
                                                         nullptr, nullptr, ffhi, fflo,
                                                         nullptr, nullptr, nullptr, nullptr, nullptr, nullptr);
        gemm_s<1, 64><<<dim3(8, 64), 256, 0, stream>>>(ffhi, fflo, w2T_hi, w2T_lo, 2048, 512,
                                                       xbuf, xbuf, nullptr, nullptr,
                                                       nullptr, nullptr, nullptr, nullptr, nullptr, nullptr);
    }

    head_k<<<2048, 256, 0, stream>>>(xbuf, head_w, head_b, probs);
    chunk_k<<<4, 256, 0, stream>>>(probs, ids, out + 4202496, out + 20979713);
    masks_k<<<8192, 256, 0, stream>>>(ids, out + 4202497);
}

// Round 8
// 863.477 us; speedup vs baseline: 3.5228x; 1.0229x over previous
//
#include <hip/hip_runtime.h>
#include <math.h>

#define S_LEN 2048
#define DMODEL 512
#define NHEAD 8
#define DH 64
#define FDIM 2048

typedef unsigned short ushort_t;
typedef __attribute__((ext_vector_type(8))) short short8_t;   // 8 bf16 = 4 VGPRs
typedef __attribute__((ext_vector_type(4))) float float4_t;   // MFMA acc

#define MFMA16(a, b, c) __builtin_amdgcn_mfma_f32_16x16x32_bf16(a, b, c, 0, 0, 0)

// ---- output layout (floats) ----
// x_t: [0, 4194304)  x_ids: [4194304, 4202496)  avg: 4202496
// masks: [4202497, 20979713)  loss: 20979713
// masks region doubles as weight-split + rope-table scratch (dead until masks_k).

// LDS bank-conflict swizzle: logical 16B quad q of row r stored at physical
// quad q ^ ((r>>1)&3). Makes b128 fragment reads (64B row stride) 2-way
// (free, m136) instead of 8-way (2.94x). Bits 1-2 of the row are invariant
// across all uses (tiles are 16-row aligned), so writer/reader agree.

__device__ __forceinline__ ushort_t f2bf(float x) {            // RNE fp32->bf16
    unsigned u = __float_as_uint(x);
    return (ushort_t)((u + 0x7fffu + ((u >> 16) & 1u)) >> 16);
}
__device__ __forceinline__ float bf2f(ushort_t h) {
    return __uint_as_float((unsigned)h << 16);
}
__device__ __forceinline__ float gelu_f(float x) {
    return 0.5f * x * (1.0f + erff(x * 0.70710678118654752440f));
}
__device__ __forceinline__ void gl_lds16(const void* g, void* l) {
    __builtin_amdgcn_global_load_lds(
        (const __attribute__((address_space(1))) void*)g,
        (__attribute__((address_space(3))) void*)l, 16, 0, 0);
}

// stage a 64x64 bf16 tile (row stride rs ushorts) into LDS [kk][64][32] with
// quad swizzle. LDS dest stays lane-linear (gl_lds16 requirement); the global
// source quad is permuted per lane instead.
__device__ __forceinline__ void stage_tile(const ushort_t* __restrict__ g, int rs,
                                           ushort_t* __restrict__ s, int w, int lane) {
    #pragma unroll
    for (int j = 0; j < 2; ++j) {
        const int c = (w * 2 + j) * 64 + lane;
        const int kk = c >> 8, row = (c >> 2) & 63, q = c & 3;
        const int qs = q ^ ((row >> 1) & 3);
        gl_lds16(g + (size_t)row * rs + kk * 32 + qs * 8, s + c * 8);
    }
}

// ---------------- copy x -> out, ids -> out, zero scalar slots --------------
__global__ void copy_init_k(const float* __restrict__ x, const int* __restrict__ x_ids,
                            float* __restrict__ out) {
    size_t i = (size_t)blockIdx.x * blockDim.x + threadIdx.x;
    float4* o4 = (float4*)out;
    o4[i] = ((const float4*)x)[i];
    if (i < 2048) {
        int4 id4 = ((const int4*)x_ids)[i];
        o4[1048576 + i] = make_float4((float)id4.x, (float)id4.y, (float)id4.z, (float)id4.w);
    }
    if (i == 0) { out[4202496] = 0.0f; out[20979713] = 0.0f; }
}

// ---------------- RoPE cos/sin table: tab[s*32+f] = (cos, sin) --------------
__global__ __launch_bounds__(256) void rope_tab_k(float2* __restrict__ tab) {
    const int i = blockIdx.x * 256 + threadIdx.x;   // 65536
    const int s = i >> 5, f = i & 31;
    float inv = powf(10000.0f, -(float)f * (1.0f / 32.0f));
    float sn, cs;
    sincosf((float)s * inv, &sn, &cs);
    tab[i] = make_float2(cs, sn);
}

// ---------------- ALL weights transpose + split, one dispatch ----------------
__global__ __launch_bounds__(256) void tsplit_all_k(const float* __restrict__ Wq,
                                                    const float* __restrict__ Wk,
                                                    const float* __restrict__ Wv,
                                                    const float* __restrict__ Wo,
                                                    const float* __restrict__ W1,
                                                    const float* __restrict__ W2,
                                                    ushort_t* __restrict__ wbuf) {
    __shared__ float T[32][33];
    const int bid = blockIdx.x;
    const int l = bid / 3072;
    const int r = bid % 3072;
    ushort_t* lb = wbuf + (size_t)l * 6291456;
    const float* W; ushort_t* Thi; ushort_t* Tlo; int K, N, ntn, rr;
    if (r < 768) {
        const int which = r >> 8; rr = r & 255;
        W = (which == 0 ? Wq : which == 1 ? Wk : Wv) + (size_t)l * 262144;
        Thi = lb + which * 262144; Tlo = lb + 786432 + which * 262144;
        K = 512; N = 512; ntn = 16;
    } else if (r < 1024) {
        rr = r - 768; W = Wo + (size_t)l * 262144;
        Thi = lb + 1572864; Tlo = lb + 1835008; K = 512; N = 512; ntn = 16;
    } else if (r < 2048) {
        rr = r - 1024; W = W1 + (size_t)l * 1048576;
        Thi = lb + 2097152; Tlo = lb + 3145728; K = 512; N = 2048; ntn = 64;
    } else {
        rr = r - 2048; W = W2 + (size_t)l * 1048576;
        Thi = lb + 4194304; Tlo = lb + 5242880; K = 2048; N = 512; ntn = 16;
    }
    const int n0 = (rr % ntn) * 32, k0 = (rr / ntn) * 32;
    const int tx = threadIdx.x & 31, ty = threadIdx.x >> 5;
    #pragma unroll
    for (int i = 0; i < 4; ++i)
        T[ty + 8 * i][tx] = W[(size_t)(k0 + ty + 8 * i) * N + n0 + tx];
    __syncthreads();
    #pragma unroll
    for (int i = 0; i < 4; ++i) {
        const int n = ty + 8 * i;
        float x = T[tx][n];
        ushort_t hi = f2bf(x);
        Thi[(size_t)(n0 + n) * K + k0 + tx] = hi;
        Tlo[(size_t)(n0 + n) * K + k0 + tx] = f2bf(x - bf2f(hi));
    }
}

// ---------------- RMSNorm -> hi/lo bf16 split --------------------------------
__global__ __launch_bounds__(256) void rmsnorm_split_k(const float* __restrict__ x,
                                                       const float* __restrict__ w,
                                                       ushort_t* __restrict__ hhi,
                                                       ushort_t* __restrict__ hlo) {
    __shared__ float red[4];
    const int tid = threadIdx.x;
    const size_t row = blockIdx.x;
    const float* xr = x + row * DMODEL;
    float2 v = *(const float2*)(xr + tid * 2);
    float ss = v.x * v.x + v.y * v.y;
    #pragma unroll
    for (int off = 32; off; off >>= 1) ss += __shfl_down(ss, off);
    if ((tid & 63) == 0) red[tid >> 6] = ss;
    __syncthreads();
    float tot = red[0] + red[1] + red[2] + red[3];
    float rs = 1.0f / sqrtf(tot * (1.0f / 512.0f) + 1e-6f);
    float2 wv = *(const float2*)(w + tid * 2);
    float y0 = v.x * rs * wv.x, y1 = v.y * rs * wv.y;
    ushort_t h0 = f2bf(y0), h1 = f2bf(y1);
    ushort_t l0 = f2bf(y0 - bf2f(h0)), l1 = f2bf(y1 - bf2f(h1));
    *(unsigned*)(hhi + row * DMODEL + tid * 2) = ((unsigned)h1 << 16) | h0;
    *(unsigned*)(hlo + row * DMODEL + tid * 2) = ((unsigned)l1 << 16) | l0;
}

// ---------------- bf16x3 split MFMA GEMM (swizzled LDS) ----------------------
template<int EPI, int TN>
__global__ __launch_bounds__(256) void gemm_s(const ushort_t* __restrict__ Ahi,
                                              const ushort_t* __restrict__ Alo,
                                              const ushort_t* __restrict__ Bhi,
                                              const ushort_t* __restrict__ Blo,
                                              int K, int N,
                                              float* __restrict__ C,
                                              const float* __restrict__ Cin,
                                              ushort_t* __restrict__ Chi,
                                              ushort_t* __restrict__ Clo,
                                              ushort_t* __restrict__ oqh,
                                              ushort_t* __restrict__ oql,
                                              ushort_t* __restrict__ okh,
                                              ushort_t* __restrict__ okl,
                                              ushort_t* __restrict__ ovh,
                                              const float2* __restrict__ rtab) {
    constexpr int MT = (TN == 128) ? 4 : 2;        // m-tiles per wave
    __shared__ ushort_t sAhi[4096], sAlo[4096];
    __shared__ ushort_t sBhi[TN * 32], sBlo[TN * 32];
    const int tid = threadIdx.x;
    const int lane = tid & 63, w = tid >> 6;
    const int wm = (TN == 128) ? (w >> 1) : w;
    const int wn = (TN == 128) ? (w & 1) : 0;
    const int bm = blockIdx.y, bn = blockIdx.x;
    const int sm = lane >> 2;                       // staging row in 16-chunk
    const int sk = ((lane & 3) ^ ((sm >> 1) & 3)) * 8;  // swizzled global quad
    const int fr = lane & 15;
    const int fq = lane >> 4;
    const int fko = (fq ^ ((fr >> 1) & 3)) * 8;     // swizzled frag k-offset

    float4_t acc[MT][4] = {};

    for (int kt = 0; kt < K; kt += 32) {
        #pragma unroll
        for (int j = 0; j < 2; ++j) {              // A: 8 chunks x 16 rows
            const int chunk = w * 2 + j;
            const int mr = chunk * 16 + sm;
            const size_t ga = (size_t)(bm * 128 + mr) * K + kt + sk;
            gl_lds16(Ahi + ga, &sAhi[chunk * 512]);
            gl_lds16(Alo + ga, &sAlo[chunk * 512]);
        }
        #pragma unroll
        for (int j = 0; j < TN / 64; ++j) {        // B: TN/16 chunks
            const int chunk = w * (TN / 64) + j;
            const int mr = chunk * 16 + sm;
            const size_t gb = (size_t)(bn * TN + mr) * K + kt + sk;
            gl_lds16(Bhi + gb, &sBhi[chunk * 512]);
            gl_lds16(Blo + gb, &sBlo[chunk * 512]);
        }
        __syncthreads();
        short8_t ah[MT], al[MT], bh[4], bl[4];
        #pragma unroll
        for (int t = 0; t < MT; ++t) {
            const int ao = (wm * (MT * 16) + t * 16 + fr) * 32 + fko;
            ah[t] = *(const short8_t*)&sAhi[ao];
            al[t] = *(const short8_t*)&sAlo[ao];
        }
        #pragma unroll
        for (int t = 0; t < 4; ++t) {
            const int bo = (wn * 64 + t * 16 + fr) * 32 + fko;
            bh[t] = *(const short8_t*)&sBhi[bo];
            bl[t] = *(const short8_t*)&sBlo[bo];
        }
        #pragma unroll
        for (int tm = 0; tm < MT; ++tm)
            #pragma unroll
            for (int tn = 0; tn < 4; ++tn) {
                acc[tm][tn] = MFMA16(ah[tm], bh[tn], acc[tm][tn]);
                acc[tm][tn] = MFMA16(al[tm], bh[tn], acc[tm][tn]);
                acc[tm][tn] = MFMA16(ah[tm], bl[tn], acc[tm][tn]);
            }
        __syncthreads();
    }

    // epilogue: C/D layout col = lane&15, row = (lane>>4)*4 + reg  [m89/m91]
    if (EPI == 0) {
        const int cb = bn * 128 + wn * 64;         // one head per wave-half
        const int mat = cb >> 9;                   // 0=q 1=k 2=v
        const int hh = (cb >> 6) & 7;
        #pragma unroll
        for (int tm = 0; tm < MT; ++tm) {
            #pragma unroll
            for (int r = 0; r < 4; ++r) {
                const int mg = bm * 128 + wm * (MT * 16) + tm * 16 + fq * 4 + r;
                const int b = mg >> 11, s = mg & 2047;
                const int bhh = b * NHEAD + hh;
                if (mat < 2) {
                    ushort_t* dhi = (mat == 0) ? oqh : okh;
                    ushort_t* dlo = (mat == 0) ? oql : okl;
                    const size_t base = ((size_t)bhh * S_LEN + s) * DH;
                    #pragma unroll
                    for (int tn = 0; tn < 2; ++tn) {
                        const int d1 = tn * 16 + fr;
                        const float v1 = acc[tm][tn][r], v2 = acc[tm][tn + 2][r];
                        const float2 t = rtab[s * 32 + d1];
                        float r1 = v1 * t.x - v2 * t.y;
                        float r2 = v1 * t.y + v2 * t.x;
                        if (mat == 0) { r1 *= 0.125f; r2 *= 0.125f; } // fold 1/sqrt(Dh)
                        ushort_t h1 = f2bf(r1), h2 = f2bf(r2);
                        dhi[base + d1]      = h1;
                        dlo[base + d1]      = f2bf(r1 - bf2f(h1));
                        dhi[base + d1 + 32] = h2;
                        dlo[base + d1 + 32] = f2bf(r2 - bf2f(h2));
                    }
                } else {
                    #pragma unroll
                    for (int tn = 0; tn < 4; ++tn) {
                        const int d = tn * 16 + fr;
                        const size_t off = ((size_t)bhh * DH + d) * S_LEN + s;
                        ovh[off] = f2bf(acc[tm][tn][r]);
                    }
                }
            }
        }
    } else {
        #pragma unroll
        for (int tm = 0; tm < MT; ++tm) {
            #pragma unroll
            for (int tn = 0; tn < 4; ++tn) {
                const int cb = bn * TN + wn * 64 + tn * 16;
                #pragma unroll
                for (int r = 0; r < 4; ++r) {
                    const int mg = bm * 128 + wm * (MT * 16) + tm * 16 + fq * 4 + r;
                    const float val = acc[tm][tn][r];
                    const size_t off = (size_t)mg * N + cb + fr;
                    if (EPI == 1) {
                        C[off] = Cin[off] + val;
                    } else {
                        const float g = gelu_f(val);
                        const ushort_t hi = f2bf(g);
                        Chi[off] = hi;
                        Clo[off] = f2bf(g - bf2f(hi));
                    }
                }
            }
        }
    }
}

// ---------------- MFMA causal flash attention (swizzled LDS) -----------------
// 1-D grid 1024: bh = blockIdx&31 (XCD-pinned K/V), qt = 31 - (blockIdx>>5).
__global__ __launch_bounds__(256) void attn_k(const ushort_t* __restrict__ qhi,
                                              const ushort_t* __restrict__ qlo,
                                              const ushort_t* __restrict__ khi,
                                              const ushort_t* __restrict__ klo,
                                              const ushort_t* __restrict__ vthi,
                                              ushort_t* __restrict__ Ohi,
                                              ushort_t* __restrict__ Olo) {
    __shared__ __align__(16) ushort_t sKh[4096], sKl[4096];
    __shared__ __align__(16) ushort_t sVh[4096], sPh[4096];
    const int tid = threadIdx.x, lane = tid & 63, w = tid >> 6;
    const int fr = lane & 15, fq = lane >> 4;
    const int fko = (fq ^ ((fr >> 1) & 3)) * 8;     // swizzled frag k-offset
    const int bidx = blockIdx.x;
    const int bh = bidx & 31;
    const int qt = 31 - (bidx >> 5);

    short8_t qfh[2], qfl[2];
    {
        const size_t base = ((size_t)bh * S_LEN + qt * 64 + w * 16 + fr) * DH + fq * 8;
        qfh[0] = *(const short8_t*)(qhi + base);
        qfh[1] = *(const short8_t*)(qhi + base + 32);
        qfl[0] = *(const short8_t*)(qlo + base);
        qfl[1] = *(const short8_t*)(qlo + base + 32);
    }

    float m_r[4], l_r[4];
    float4_t oacc[4] = {};
    #pragma unroll
    for (int r = 0; r < 4; ++r) { m_r[r] = -INFINITY; l_r[r] = 0.0f; }

    auto step = [&](const int kt, const bool diag) {
        __syncthreads();   // prior iteration's frag reads done
        const size_t ko = ((size_t)bh * S_LEN + kt * 64) * DH;
        stage_tile(khi + ko, 64, sKh, w, lane);
        stage_tile(klo + ko, 64, sKl, w, lane);
        const size_t vo = (size_t)bh * DH * S_LEN + kt * 64;
        stage_tile(vthi + vo, S_LEN, sVh, w, lane);
        __syncthreads();   // vmcnt drained: K/V visible

        float4_t sacc[4] = {};
        #pragma unroll
        for (int kk = 0; kk < 2; ++kk) {
            #pragma unroll
            for (int n = 0; n < 4; ++n) {
                const int bb = kk * 2048 + (n * 16 + fr) * 32 + fko;
                short8_t kh2 = *(const short8_t*)&sKh[bb];
                short8_t kl2 = *(const short8_t*)&sKl[bb];
                sacc[n] = MFMA16(qfh[kk], kh2, sacc[n]);
                sacc[n] = MFMA16(qfl[kk], kh2, sacc[n]);
                sacc[n] = MFMA16(qfh[kk], kl2, sacc[n]);
            }
        }

        #pragma unroll
        for (int r = 0; r < 4; ++r) {
            const int rowl = fq * 4 + r;
            const int qrow = w * 16 + rowl;
            const int psw = (qrow >> 1) & 3;       // P write swizzle
            float sv[4], mx = -INFINITY;
            #pragma unroll
            for (int n = 0; n < 4; ++n) {
                float x = sacc[n][r];
                if (diag && (n * 16 + fr) > qrow - w * 16 + w * 16) {} // (kept below)
                sv[n] = x;
            }
            #pragma unroll
            for (int n = 0; n < 4; ++n) {
                if (diag && (n * 16 + fr) > qrow) sv[n] = -1e30f;
                mx = fmaxf(mx, sv[n]);
            }
            mx = fmaxf(mx, __shfl_xor(mx, 1));
            mx = fmaxf(mx, __shfl_xor(mx, 2));
            mx = fmaxf(mx, __shfl_xor(mx, 4));
            mx = fmaxf(mx, __shfl_xor(mx, 8));
            const float mn = fmaxf(m_r[r], mx);
            const float alp = __expf(m_r[r] - mn);
            m_r[r] = mn;
            float ls = 0.0f;
            #pragma unroll
            for (int n = 0; n < 4; ++n) {
                const float p = __expf(sv[n] - mn);
                const int c0 = (n & 1) * 16 + fr;
                const int idx = (n >> 1) * 2048 + qrow * 32 + ((c0 >> 3) ^ psw) * 8 + (c0 & 7);
                sPh[idx] = f2bf(p);
                ls += p;
            }
            ls += __shfl_xor(ls, 1);
            ls += __shfl_xor(ls, 2);
            ls += __shfl_xor(ls, 4);
            ls += __shfl_xor(ls, 8);
            l_r[r] = alp * l_r[r] + ls;
            #pragma unroll
            for (int n = 0; n < 4; ++n) oacc[n][r] *= alp;
        }
        // P rows wave-private: no barrier between P write and PV reads.

        #pragma unroll
        for (int kkj = 0; kkj < 2; ++kkj) {
            short8_t ph = *(const short8_t*)&sPh[kkj * 2048 + (w * 16 + fr) * 32 + fko];
            #pragma unroll
            for (int n = 0; n < 4; ++n) {
                short8_t vh = *(const short8_t*)&sVh[kkj * 2048 + (n * 16 + fr) * 32 + fko];
                oacc[n] = MFMA16(ph, vh, oacc[n]);
            }
        }
    };

    for (int kt = 0; kt < qt; ++kt) step(kt, false);
    step(qt, true);

    const int b = bh >> 3, hh = bh & 7;
    #pragma unroll
    for (int r = 0; r < 4; ++r) {
        const float inv_l = 1.0f / l_r[r];
        const int s = qt * 64 + w * 16 + fq * 4 + r;
        const size_t base = ((size_t)b * S_LEN + s) * DMODEL + hh * DH;
        #pragma unroll
        for (int n = 0; n < 4; ++n) {
            const float y = oacc[n][r] * inv_l;
            const ushort_t h = f2bf(y);
            Ohi[base + n * 16 + fr] = h;
            Olo[base + n * 16 + fr] = f2bf(y - bf2f(h));
        }
    }
}

// ---------------- head: logits -> sigmoid -> probs (no atomics) -------------
__global__ __launch_bounds__(256) void head_k(const float* __restrict__ x,
                                              const float* __restrict__ w,
                                              const float* __restrict__ b,
                                              float* __restrict__ probs) {
    const int tid = threadIdx.x;
    const int lane = tid & 63;
    const size_t row = (size_t)blockIdx.x * 4 + (tid >> 6);
    const float* xr = x + row * DMODEL;
    float acc = 0.0f;
    #pragma unroll
    for (int i = 0; i < 8; ++i) acc += xr[lane + i * 64] * w[lane + i * 64];
    #pragma unroll
    for (int off = 32; off; off >>= 1) acc += __shfl_down(acc, off);
    if (lane == 0)
        probs[row] = 1.0f / (1.0f + expf(-(acc + b[0])));
}

// ---------------- chunk id scan (binary lifting) + loss reduction ------------
__global__ __launch_bounds__(256) void chunk_k(const float* __restrict__ probs,
                                               int* __restrict__ ids,
                                               float* __restrict__ avg_out,
                                               float* __restrict__ loss_out) {
    __shared__ ushort_t nxA[2052], nxB[2052];
    __shared__ ushort_t lift[10][2052];
    __shared__ float lred[4];
    __shared__ int anyf;
    const int b = blockIdx.x, tid = threadIdx.x;
    const float* pr = probs + (size_t)b * S_LEN;
    if (tid == 0) anyf = 0;
    __syncthreads();
    int loc = 0;
    float lsum = 0.0f;
    for (int t = tid; t < S_LEN; t += 256) {
        const float p = pr[t];
        loc |= (p > 0.5f) ? 1 : 0;
        lsum += p;
    }
    if (loc) atomicOr(&anyf, 1);
    #pragma unroll
    for (int off = 32; off; off >>= 1) lsum += __shfl_down(lsum, off);
    if ((tid & 63) == 0) lred[tid >> 6] = lsum;
    __syncthreads();
    if (tid == 0)
        atomicAdd(loss_out, (lred[0] + lred[1] + lred[2] + lred[3]) * 0.25f);
    const int any = anyf;
    for (int i = tid; i <= S_LEN; i += 256) {
        const bool he = any ? (i >= 1 && pr[i - 1] > 0.5f) : (i == S_LEN - 1);
        nxA[i] = he ? (ushort_t)i : (ushort_t)(S_LEN + 1);
    }
    __syncthreads();
    ushort_t* src = nxA;
    ushort_t* dst = nxB;
    for (int d = 1; d <= 2048; d <<= 1) {
        for (int i = tid; i <= S_LEN; i += 256) {
            ushort_t v = src[i];
            if (i + d <= S_LEN) { ushort_t u2 = src[i + d]; v = u2 < v ? u2 : v; }
            dst[i] = v;
        }
        __syncthreads();
        ushort_t* tmp = src; src = dst; dst = tmp;
    }
    for (int t = tid; t < S_LEN; t += 256) {
        int cap = t + 16; if (cap > S_LEN) cap = S_LEN;
        int e = src[t + 1];
        if (e > cap) e = cap;
        if (e - t < 3) { e = t + 3; if (e > S_LEN) e = S_LEN; }
        lift[0][t] = (ushort_t)e;
    }
    if (tid == 0) lift[0][S_LEN] = (ushort_t)S_LEN;
    __syncthreads();
    for (int j = 1; j < 10; ++j) {
        for (int t = tid; t <= S_LEN; t += 256)
            lift[j][t] = lift[j - 1][lift[j - 1][t]];
        __syncthreads();
    }
    for (int t = tid; t < S_LEN; t += 256) {
        int pos = 0, cid = 0;
        #pragma unroll
        for (int j = 9; j >= 0; --j) {
            const int p2 = lift[j][pos];
            if (p2 <= t) { pos = p2; cid += (1 << j); }
        }
        ids[(size_t)b * S_LEN + t] = cid;
        if (t == S_LEN - 1) atomicAdd(avg_out, 512.0f / (float)(cid + 1));
    }
}

// ---------------- masks ------------------------------------------------------
__global__ __launch_bounds__(256) void masks_k(const int* __restrict__ ids,
                                               float* __restrict__ mask) {
    const int bq = blockIdx.x;
    const int b = bq >> 11;
    const int myid = ids[bq];
    const int* idr = ids + (size_t)b * S_LEN;
    float* mr = mask + (size_t)bq * S_LEN;
    for (int k = threadIdx.x; k < S_LEN; k += 256)
        mr[k] = (idr[k] == myid) ? 1.0f : 0.0f;
}

extern "C" void kernel_launch(void* const* d_in, const int* in_sizes, int n_in,
                              void* d_out, int out_size, void* d_ws, size_t ws_size,
                              hipStream_t stream) {
    (void)in_sizes; (void)n_in; (void)out_size; (void)ws_size;
    const float* x      = (const float*)d_in[0];
    const int*   x_ids  = (const int*)d_in[1];
    const float* ln1    = (const float*)d_in[2];
    const float* Wq     = (const float*)d_in[3];
    const float* Wk     = (const float*)d_in[4];
    const float* Wv     = (const float*)d_in[5];
    const float* Wo     = (const float*)d_in[6];
    const float* ln2    = (const float*)d_in[7];
    const float* W1     = (const float*)d_in[8];
    const float* W2     = (const float*)d_in[9];
    const float* head_w = (const float*)d_in[10];
    const float* head_b = (const float*)d_in[11];

    float* out = (float*)d_out;
    ushort_t* u = (ushort_t*)d_ws;
    ushort_t* qh   = u;                 // [32 bh][2048 s][64 d] roped q (x 1/8) hi
    ushort_t* ql   = u + 4194304;
    ushort_t* kh   = u + 8388608;       // roped k
    ushort_t* kl   = u + 12582912;
    ushort_t* vth  = u + 16777216;      // v transposed hi [32 bh][64 d][2048 s]
    ushort_t* ohi  = u + 25165824;      // attn out [8192][512]
    ushort_t* olo  = u + 29360128;
    ushort_t* hhi  = u + 33554432;      // rmsnorm out [8192][512]
    ushort_t* hlo  = u + 37748736;
    ushort_t* ffhi = u;                 // [8192][2048]; overlays q..k (dead after attn)
    ushort_t* fflo = u + 16777216;      // overlays vt..o (dead after Wo gemm)
    float*    probs = (float*)(u + 41943040);
    int*      ids   = (int*)(u + 41943040 + 16384);
    // weight-split (both layers) + rope table in out's mask region:
    ushort_t* wbuf     = (ushort_t*)(out + 4202512);   // 16B-aligned
    float2*   rope_tab = (float2*)(wbuf + 12582912);   // [2048][32] (cos,sin)
    float* xbuf = out;

    copy_init_k<<<4096, 256, 0, stream>>>(x, x_ids, out);
    rope_tab_k<<<256, 256, 0, stream>>>(rope_tab);
    tsplit_all_k<<<6144, 256, 0, stream>>>(Wq, Wk, Wv, Wo, W1, W2, wbuf);

    for (int l = 0; l < 2; ++l) {
        ushort_t* lb = wbuf + (size_t)l * 6291456;
        ushort_t* qkvT_hi = lb;
        ushort_t* qkvT_lo = lb + 786432;
        ushort_t* woT_hi  = lb + 1572864;
        ushort_t* woT_lo  = lb + 1835008;
        ushort_t* w1T_hi  = lb + 2097152;
        ushort_t* w1T_lo  = lb + 3145728;
        ushort_t* w2T_hi  = lb + 4194304;
        ushort_t* w2T_lo  = lb + 5242880;

        rmsnorm_split_k<<<8192, 256, 0, stream>>>(xbuf, ln1 + l * DMODEL, hhi, hlo);
        gemm_s<0, 128><<<dim3(12, 64), 256, 0, stream>>>(hhi, hlo, qkvT_hi, qkvT_lo, 512, 1536,
                                                         nullptr, nullptr, nullptr, nullptr,
                                                         qh, ql, kh, kl, vth, rope_tab);
        attn_k<<<1024, 256, 0, stream>>>(qh, ql, kh, kl, vth, ohi, olo);
        gemm_s<1, 64><<<dim3(8, 64), 256, 0, stream>>>(ohi, olo, woT_hi, woT_lo, 512, 512,
                                                       xbuf, xbuf, nullptr, nullptr,
                                                       nullptr, nullptr, nullptr, nullptr, nullptr, nullptr);
        rmsnorm_split_k<<<8192, 256, 0, stream>>>(xbuf, ln2 + l * DMODEL, hhi, hlo);
        gemm_s<2, 128><<<dim3(16, 64), 256, 0, stream>>>(hhi, hlo, w1T_hi, w1T_lo, 512, 2048,
                                                         nullptr, nullptr, ffhi, fflo,
                                                         nullptr, nullptr, nullptr, nullptr, nullptr, nullptr);
        gemm_s<1, 64><<<dim3(8, 64), 256, 0, stream>>>(ffhi, fflo, w2T_hi, w2T_lo, 2048, 512,
                                                       xbuf, xbuf, nullptr, nullptr,
                                                       nullptr, nullptr, nullptr, nullptr, nullptr, nullptr);
    }

    head_k<<<2048, 256, 0, stream>>>(xbuf, head_w, head_b, probs);
    chunk_k<<<4, 256, 0, stream>>>(probs, ids, out + 4202496, out + 20979713);
    masks_k<<<8192, 256, 0, stream>>>(ids, out + 4202497);
}